// Round 4
// baseline (520.773 us; speedup 1.0000x reference)
//
#include <hip/hip_runtime.h>

#define SEQ  2048
#define EMB  256
#define NH   8
#define HD   32
#define NB   4
#define KTOP 204
#define IDXP 208   // padded row stride for index list
#define JPW  51    // keys per wave in sparse_attn (4*51 = 204)

typedef unsigned long long ull;
typedef unsigned short u16;

__device__ __forceinline__ unsigned f2ord(float f) {
  unsigned u = __float_as_uint(f);
  return (u & 0x80000000u) ? ~u : (u | 0x80000000u);
}

// ---------------------------------------------------------------------------
// fp32 GEMM, 64x64 tile, 4x4/thread: C = scale*A@B^T + bias. QKV fused via z.
// ---------------------------------------------------------------------------
__global__ __launch_bounds__(256) void gemm_qkv(
    const float* __restrict__ x,
    const float* __restrict__ Wq, const float* __restrict__ bq,
    const float* __restrict__ Wk, const float* __restrict__ bk,
    const float* __restrict__ Wv, const float* __restrict__ bv,
    float* __restrict__ qo, float* __restrict__ ko, float* __restrict__ vo)
{
  const float* B  = (blockIdx.z == 0) ? Wq : (blockIdx.z == 1) ? Wk : Wv;
  const float* bi_ = (blockIdx.z == 0) ? bq : (blockIdx.z == 1) ? bk : bv;
  float* C = (blockIdx.z == 0) ? qo : (blockIdx.z == 1) ? ko : vo;

  __shared__ float As[16][68];
  __shared__ float Bs[16][68];
  const int tid = threadIdx.x;
  const int m0 = blockIdx.x * 64, n0 = blockIdx.y * 64;
  const int lm = tid >> 2;
  const int lk = (tid & 3) << 2;
  const int mt = tid >> 4;
  const int nt = tid & 15;
  float acc[4][4] = {{0.f}};
  for (int k0 = 0; k0 < EMB; k0 += 16) {
    float4 av = *(const float4*)(x + (size_t)(m0 + lm) * EMB + k0 + lk);
    float4 bv4 = *(const float4*)(B + (size_t)(n0 + lm) * EMB + k0 + lk);
    __syncthreads();
    As[lk+0][lm] = av.x; As[lk+1][lm] = av.y; As[lk+2][lm] = av.z; As[lk+3][lm] = av.w;
    Bs[lk+0][lm] = bv4.x; Bs[lk+1][lm] = bv4.y; Bs[lk+2][lm] = bv4.z; Bs[lk+3][lm] = bv4.w;
    __syncthreads();
#pragma unroll
    for (int kk = 0; kk < 16; ++kk) {
      float4 a4 = *(const float4*)&As[kk][mt << 2];
      float4 b4 = *(const float4*)&Bs[kk][nt << 2];
      acc[0][0] += a4.x*b4.x; acc[0][1] += a4.x*b4.y; acc[0][2] += a4.x*b4.z; acc[0][3] += a4.x*b4.w;
      acc[1][0] += a4.y*b4.x; acc[1][1] += a4.y*b4.y; acc[1][2] += a4.y*b4.z; acc[1][3] += a4.y*b4.w;
      acc[2][0] += a4.z*b4.x; acc[2][1] += a4.z*b4.y; acc[2][2] += a4.z*b4.z; acc[2][3] += a4.z*b4.w;
      acc[3][0] += a4.w*b4.x; acc[3][1] += a4.w*b4.y; acc[3][2] += a4.w*b4.z; acc[3][3] += a4.w*b4.w;
    }
  }
  float4 bi = *(const float4*)(bi_ + n0 + (nt << 2));
#pragma unroll
  for (int r = 0; r < 4; ++r) {
    float4 o;
    o.x = acc[r][0] + bi.x;
    o.y = acc[r][1] + bi.y;
    o.z = acc[r][2] + bi.z;
    o.w = acc[r][3] + bi.w;
    *(float4*)(C + (size_t)(m0 + (mt << 2) + r) * EMB + n0 + (nt << 2)) = o;
  }
}

// ---------------------------------------------------------------------------
// fp32 GEMM, 64x64 tile — single A@B^T + bias (out projection).
// ---------------------------------------------------------------------------
__global__ __launch_bounds__(256) void gemm_abT(
    const float* __restrict__ A, const float* __restrict__ B,
    const float* __restrict__ bias, float* __restrict__ C)
{
  __shared__ float As[16][68];
  __shared__ float Bs[16][68];
  const int tid = threadIdx.x;
  const int m0 = blockIdx.x * 64, n0 = blockIdx.y * 64;
  const int lm = tid >> 2;
  const int lk = (tid & 3) << 2;
  const int mt = tid >> 4;
  const int nt = tid & 15;
  float acc[4][4] = {{0.f}};
  for (int k0 = 0; k0 < EMB; k0 += 16) {
    float4 av = *(const float4*)(A + (size_t)(m0 + lm) * EMB + k0 + lk);
    float4 bv = *(const float4*)(B + (size_t)(n0 + lm) * EMB + k0 + lk);
    __syncthreads();
    As[lk+0][lm] = av.x; As[lk+1][lm] = av.y; As[lk+2][lm] = av.z; As[lk+3][lm] = av.w;
    Bs[lk+0][lm] = bv.x; Bs[lk+1][lm] = bv.y; Bs[lk+2][lm] = bv.z; Bs[lk+3][lm] = bv.w;
    __syncthreads();
#pragma unroll
    for (int kk = 0; kk < 16; ++kk) {
      float4 a4 = *(const float4*)&As[kk][mt << 2];
      float4 b4 = *(const float4*)&Bs[kk][nt << 2];
      acc[0][0] += a4.x*b4.x; acc[0][1] += a4.x*b4.y; acc[0][2] += a4.x*b4.z; acc[0][3] += a4.x*b4.w;
      acc[1][0] += a4.y*b4.x; acc[1][1] += a4.y*b4.y; acc[1][2] += a4.y*b4.z; acc[1][3] += a4.y*b4.w;
      acc[2][0] += a4.z*b4.x; acc[2][1] += a4.z*b4.y; acc[2][2] += a4.z*b4.z; acc[2][3] += a4.z*b4.w;
      acc[3][0] += a4.w*b4.x; acc[3][1] += a4.w*b4.y; acc[3][2] += a4.w*b4.z; acc[3][3] += a4.w*b4.w;
    }
  }
  float4 bi = *(const float4*)(bias + n0 + (nt << 2));
#pragma unroll
  for (int r = 0; r < 4; ++r) {
    float4 o;
    o.x = acc[r][0] + bi.x;
    o.y = acc[r][1] + bi.y;
    o.z = acc[r][2] + bi.z;
    o.w = acc[r][3] + bi.w;
    *(float4*)(C + (size_t)(m0 + (mt << 2) + r) * EMB + n0 + (nt << 2)) = o;
  }
}

// ---------------------------------------------------------------------------
// fp32 GEMM, 128x128 tile, 8x8/thread — scores = x @ x^T / 16 per batch.
// ---------------------------------------------------------------------------
__global__ __launch_bounds__(256) void gemm128_abT(
    const float* __restrict__ A, const float* __restrict__ B,
    float* __restrict__ C, int ldc,
    long bsA, long bsB, long bsC, float scale)
{
  __shared__ float As[16][132];
  __shared__ float Bs[16][132];
  const int tid = threadIdx.x;
  const int m0 = blockIdx.x * 128, n0 = blockIdx.y * 128;
  const float* Ab = A + (size_t)blockIdx.z * bsA;
  const float* Bb = B + (size_t)blockIdx.z * bsB;
  float* Cb = C + (size_t)blockIdx.z * bsC;
  const int lm = tid >> 1;          // 0..127
  const int lk = (tid & 1) << 3;    // 0 or 8
  const int mt = tid >> 4;          // 0..15
  const int nt = tid & 15;          // 0..15
  float acc[8][8] = {{0.f}};
  for (int k0 = 0; k0 < EMB; k0 += 16) {
    float4 a0 = *(const float4*)(Ab + (size_t)(m0 + lm) * EMB + k0 + lk);
    float4 a1 = *(const float4*)(Ab + (size_t)(m0 + lm) * EMB + k0 + lk + 4);
    float4 b0 = *(const float4*)(Bb + (size_t)(n0 + lm) * EMB + k0 + lk);
    float4 b1 = *(const float4*)(Bb + (size_t)(n0 + lm) * EMB + k0 + lk + 4);
    __syncthreads();
    As[lk+0][lm]=a0.x; As[lk+1][lm]=a0.y; As[lk+2][lm]=a0.z; As[lk+3][lm]=a0.w;
    As[lk+4][lm]=a1.x; As[lk+5][lm]=a1.y; As[lk+6][lm]=a1.z; As[lk+7][lm]=a1.w;
    Bs[lk+0][lm]=b0.x; Bs[lk+1][lm]=b0.y; Bs[lk+2][lm]=b0.z; Bs[lk+3][lm]=b0.w;
    Bs[lk+4][lm]=b1.x; Bs[lk+5][lm]=b1.y; Bs[lk+6][lm]=b1.z; Bs[lk+7][lm]=b1.w;
    __syncthreads();
#pragma unroll
    for (int kk = 0; kk < 16; ++kk) {
      float4 aA = *(const float4*)&As[kk][mt * 8];
      float4 aB = *(const float4*)&As[kk][mt * 8 + 4];
      float4 bA = *(const float4*)&Bs[kk][nt * 8];
      float4 bB = *(const float4*)&Bs[kk][nt * 8 + 4];
      float am[8] = {aA.x,aA.y,aA.z,aA.w,aB.x,aB.y,aB.z,aB.w};
      float bn[8] = {bA.x,bA.y,bA.z,bA.w,bB.x,bB.y,bB.z,bB.w};
#pragma unroll
      for (int i = 0; i < 8; ++i)
#pragma unroll
        for (int j = 0; j < 8; ++j)
          acc[i][j] += am[i] * bn[j];
    }
  }
#pragma unroll
  for (int r = 0; r < 8; ++r) {
    float4 o0, o1;
    o0.x = acc[r][0]*scale; o0.y = acc[r][1]*scale; o0.z = acc[r][2]*scale; o0.w = acc[r][3]*scale;
    o1.x = acc[r][4]*scale; o1.y = acc[r][5]*scale; o1.z = acc[r][6]*scale; o1.w = acc[r][7]*scale;
    float* cp = Cb + (size_t)(m0 + mt * 8 + r) * ldc + n0 + nt * 8;
    *(float4*)cp = o0;
    *(float4*)(cp + 4) = o1;
  }
}

// ---------------------------------------------------------------------------
// Top-k=204 per row. Binary search on ordinal bits; lowest-index tie-break.
// Emits compacted ASCENDING index list (KTOP u16 per row, stride IDXP).
// ---------------------------------------------------------------------------
__global__ __launch_bounds__(256) void topk_idx(
    const float* __restrict__ scores, u16* __restrict__ idxl)
{
  const int r = blockIdx.x;
  const int tid = threadIdx.x;
  const float* row = scores + (size_t)r * SEQ;
  unsigned key[8];
  {
    float4 f0 = *(const float4*)(row + tid * 8);
    float4 f1 = *(const float4*)(row + tid * 8 + 4);
    key[0]=f2ord(f0.x); key[1]=f2ord(f0.y); key[2]=f2ord(f0.z); key[3]=f2ord(f0.w);
    key[4]=f2ord(f1.x); key[5]=f2ord(f1.y); key[6]=f2ord(f1.z); key[7]=f2ord(f1.w);
  }
  __shared__ int wsum[4];
  __shared__ int total_sh;
  __shared__ int scan_sh[256];
  const int lane = tid & 63, wid = tid >> 6;

  unsigned lo = 0u, hi = 0xFFFFFFFFu;
  while (lo < hi) {
    unsigned mid = (unsigned)((((ull)lo + (ull)hi) + 1ull) >> 1);
    int c = 0;
#pragma unroll
    for (int j = 0; j < 8; ++j) c += (key[j] >= mid) ? 1 : 0;
    for (int off = 32; off > 0; off >>= 1) c += __shfl_down(c, off, 64);
    if (lane == 0) wsum[wid] = c;
    __syncthreads();
    if (tid == 0) total_sh = wsum[0] + wsum[1] + wsum[2] + wsum[3];
    __syncthreads();
    int cnt = total_sh;
    __syncthreads();
    if (cnt >= KTOP) lo = mid; else hi = mid - 1;
  }
  const unsigned V = lo;

  int cgt = 0, ceq = 0;
#pragma unroll
  for (int j = 0; j < 8; ++j) {
    cgt += (key[j] > V) ? 1 : 0;
    ceq += (key[j] == V) ? 1 : 0;
  }
  int cg = cgt;
  for (int off = 32; off > 0; off >>= 1) cg += __shfl_down(cg, off, 64);
  if (lane == 0) wsum[wid] = cg;
  __syncthreads();
  if (tid == 0) total_sh = wsum[0] + wsum[1] + wsum[2] + wsum[3];
  __syncthreads();
  const int MEQ = KTOP - total_sh;

  scan_sh[tid] = ceq;
  __syncthreads();
  for (int off = 1; off < 256; off <<= 1) {
    int v = (tid >= off) ? scan_sh[tid - off] : 0;
    __syncthreads();
    scan_sh[tid] += v;
    __syncthreads();
  }
  int run = scan_sh[tid] - ceq;

  unsigned bits = 0;
#pragma unroll
  for (int j = 0; j < 8; ++j) {
    bool e = (key[j] == V);
    bool sel = (key[j] > V) || (e && (run < MEQ));
    if (e) run++;
    if (sel) bits |= (1u << j);
  }
  int csel = __popc(bits);

  __syncthreads();
  scan_sh[tid] = csel;
  __syncthreads();
  for (int off = 1; off < 256; off <<= 1) {
    int v = (tid >= off) ? scan_sh[tid - off] : 0;
    __syncthreads();
    scan_sh[tid] += v;
    __syncthreads();
  }
  int base = scan_sh[tid] - csel;
  u16* orow = idxl + (size_t)r * IDXP;
#pragma unroll
  for (int j = 0; j < 8; ++j) {
    if ((bits >> j) & 1u) orow[base++] = (u16)(tid * 8 + j);
  }
}

// ---------------------------------------------------------------------------
// Single-pass sparse attention, v3.
//  - XCD batch swizzle: batch = lin&3 so each XCD's L2 holds one batch's K+V.
//  - attn row built densely in LDS (zero + scatter), then streamed out as
//    full-line float4 writes (no partial-line writebacks).
// ---------------------------------------------------------------------------
__global__ __launch_bounds__(256) void sparse_attn(
    const float* __restrict__ qb, const float* __restrict__ kb,
    const float* __restrict__ vb, const u16* __restrict__ idxl,
    float* __restrict__ attn, float* __restrict__ ctxb)
{
  const int lin = blockIdx.x;
  const int b = lin & 3;                                  // XCD-stable batch
  const int q = (lin >> 3) + (((lin >> 2) & 1) << 10);
  const int tid = threadIdx.x;
  const int wv = tid >> 6, ln = tid & 63;
  const int h = ln >> 3, hd8 = ln & 7;
  __shared__ int   ish[IDXP];
  __shared__ float psh[KTOP * 9 + 4];   // [j][h], stride 9
  __shared__ float idsh[NH];
  __shared__ float csh[4][EMB + 8];
  __shared__ float rsh[SEQ];            // dense attn row

  const int row = b * SEQ + q;
  if (tid < KTOP) ish[tid] = (int)idxl[(size_t)row * IDXP + tid];

  // zero dense row in LDS
  float4 z4 = make_float4(0.f, 0.f, 0.f, 0.f);
  *(float4*)&rsh[tid * 8]     = z4;
  *(float4*)&rsh[tid * 8 + 4] = z4;

  // q fragment: lane ln holds q[row][ln*4 .. ln*4+3]
  float4 qv = *(const float4*)(qb + (size_t)row * EMB + ln * 4);

  __syncthreads();

  const float scale = 0.17677669529663687f;  // 1/sqrt(32)
  const float* kbB = kb + (size_t)(b * SEQ) * EMB;
#pragma unroll 3
  for (int t = 0; t < JPW; ++t) {
    int j = wv * JPW + t;
    const float4 kv = *(const float4*)(kbB + (size_t)ish[j] * EMB + ln * 4);
    float p = qv.x*kv.x + qv.y*kv.y + qv.z*kv.z + qv.w*kv.w;
    p += __shfl_xor(p, 4, 64);
    p += __shfl_xor(p, 2, 64);
    p += __shfl_xor(p, 1, 64);
    if (hd8 == 0) psh[j * 9 + h] = __expf(p * scale);
  }
  __syncthreads();

  // per-head denominators
  {
    int h2 = tid >> 5, l = tid & 31;
    float s = 0.f;
    for (int j = l; j < KTOP; j += 32) s += psh[j * 9 + h2];
#pragma unroll
    for (int off = 16; off > 0; off >>= 1) s += __shfl_down(s, off, 32);
    if (l == 0) idsh[h2] = 1.0f / s;
  }
  __syncthreads();

  // normalize in place; head-mean scatter into LDS row
  if (tid < KTOP) {
    float ps = 0.f;
#pragma unroll
    for (int hh = 0; hh < 8; ++hh) {
      float pp = psh[tid * 9 + hh] * idsh[hh];
      psh[tid * 9 + hh] = pp;
      ps += pp;
    }
    rsh[ish[tid]] = ps * 0.125f;
  }
  __syncthreads();

  // stream dense row out (full-line writes only)
  {
    float* arow = attn + (size_t)row * SEQ;
    *(float4*)(arow + tid * 8)     = *(const float4*)&rsh[tid * 8];
    *(float4*)(arow + tid * 8 + 4) = *(const float4*)&rsh[tid * 8 + 4];
  }

  // ctx: wave wv accumulates its 51 keys; lane ln covers dims ln*4..+3
  {
    const float* vbB = vb + (size_t)(b * SEQ) * EMB;
    float4 acc = z4;
#pragma unroll 3
    for (int t = 0; t < JPW; ++t) {
      int j = wv * JPW + t;
      const float4 vv = *(const float4*)(vbB + (size_t)ish[j] * EMB + ln * 4);
      float pp = psh[j * 9 + h];
      acc.x += pp*vv.x; acc.y += pp*vv.y; acc.z += pp*vv.z; acc.w += pp*vv.w;
    }
    *(float4*)&csh[wv][ln * 4] = acc;
  }
  __syncthreads();
  if (tid < 64) {
    float4 o = z4;
#pragma unroll
    for (int g = 0; g < 4; ++g) {
      float4 v = *(const float4*)&csh[g][tid * 4];
      o.x += v.x; o.y += v.y; o.z += v.z; o.w += v.w;
    }
    *(float4*)(ctxb + (size_t)row * EMB + tid * 4) = o;
  }
}

// ---------------------------------------------------------------------------
extern "C" void kernel_launch(void* const* d_in, const int* in_sizes, int n_in,
                              void* d_out, int out_size, void* d_ws, size_t ws_size,
                              hipStream_t stream)
{
  const float* x  = (const float*)d_in[0];
  const float* Wq = (const float*)d_in[1];
  const float* bq = (const float*)d_in[2];
  const float* Wk = (const float*)d_in[3];
  const float* bk = (const float*)d_in[4];
  const float* Wv = (const float*)d_in[5];
  const float* bv = (const float*)d_in[6];
  const float* Wo = (const float*)d_in[7];
  const float* bo = (const float*)d_in[8];

  float* out  = (float*)d_out;
  float* attn = out + (size_t)NB * SEQ * EMB;   // [B,S,S] region of d_out

  float* qbuf = (float*)d_ws;
  float* kbuf = qbuf + (size_t)NB * SEQ * EMB;
  float* vbuf = kbuf + (size_t)NB * SEQ * EMB;
  float* ctxb = vbuf + (size_t)NB * SEQ * EMB;
  u16*  idxl  = (u16*)(ctxb + (size_t)NB * SEQ * EMB);  // B*S*IDXP u16

  const dim3 blk(256);
  const long strideXB = (long)SEQ * EMB;
  const long strideSB = (long)SEQ * SEQ;

  // fused Q/K/V projections: [8192,256] = x @ W^T + b, z selects W
  gemm_qkv<<<dim3(128, 4, 3), blk, 0, stream>>>(x, Wq, bq, Wk, bk, Wv, bv,
                                                qbuf, kbuf, vbuf);

  // scores = x @ x^T / 16, into the attn_weights region of d_out (128-tile)
  gemm128_abT<<<dim3(16, 16, NB), blk, 0, stream>>>(x, x, attn, SEQ,
      strideXB, strideXB, strideSB, 0.0625f);

  // compacted top-k index lists (ascending per row)
  topk_idx<<<dim3(NB * SEQ), blk, 0, stream>>>(attn, idxl);

  // fused sparse attention (XCD batch swizzle, LDS-dense row)
  sparse_attn<<<dim3(SEQ * NB), blk, 0, stream>>>(qbuf, kbuf, vbuf, idxl, attn, ctxb);

  // out = ctx @ Wo^T + bo
  gemm_abT<<<dim3(128, 4, 1), blk, 0, stream>>>(ctxb, Wo, bo, out);
}

// Round 7
// 487.606 us; speedup vs baseline: 1.0680x; 1.0680x over previous
//
#include <hip/hip_runtime.h>

#define SEQ  2048
#define EMB  256
#define NH   8
#define HD   32
#define NB   4
#define KTOP 204
#define IDXP 208   // padded row stride for index list
#define KPW  52    // keys per wave in sparse_attn (4*52 = 208, padded)
#define MBOUND 4e-4f  // top-k margin below which we re-verify in fp32 (>=2x max approx err ~5e-5)

typedef unsigned long long ull;
typedef unsigned short u16;

using frag8 = __attribute__((ext_vector_type(8))) short;   // 8 bf16
using f32x4v = __attribute__((ext_vector_type(4))) float;  // 4 fp32 acc

__device__ __forceinline__ unsigned f2ord(float f) {
  unsigned u = __float_as_uint(f);
  return (u & 0x80000000u) ? ~u : (u | 0x80000000u);
}
__device__ __forceinline__ float ord2f(unsigned o) {
  unsigned u = (o & 0x80000000u) ? (o ^ 0x80000000u) : ~o;
  return __uint_as_float(u);
}
__device__ __forceinline__ u16 f2bf(float f) {
  unsigned u = __float_as_uint(f);
  u += 0x7FFF + ((u >> 16) & 1);     // RTNE
  return (u16)(u >> 16);
}
__device__ __forceinline__ float bf2f(u16 h) {
  return __uint_as_float((unsigned)h << 16);
}
__device__ __forceinline__ float dotbf(float4 q, ushort4 k) {
  return q.x*bf2f(k.x) + q.y*bf2f(k.y) + q.z*bf2f(k.z) + q.w*bf2f(k.w);
}

// ---------------------------------------------------------------------------
// Shared top-k machinery (binary search on ordinal bits, stable lowest-index
// tie-break, compacted ascending index output).
// ---------------------------------------------------------------------------
struct TkS { int wsum[4]; int total; int scan[256]; };

__device__ __forceinline__ int tk_blksum(int v, int tid, TkS& s) {
  const int lane = tid & 63, wid = tid >> 6;
  for (int off = 32; off > 0; off >>= 1) v += __shfl_down(v, off, 64);
  if (lane == 0) s.wsum[wid] = v;
  __syncthreads();
  if (tid == 0) s.total = s.wsum[0] + s.wsum[1] + s.wsum[2] + s.wsum[3];
  __syncthreads();
  int r = s.total;
  __syncthreads();
  return r;
}

__device__ __forceinline__ unsigned tk_kth(const unsigned key[8], int tid, TkS& s) {
  unsigned lo = 0u, hi = 0xFFFFFFFFu;
  while (lo < hi) {
    unsigned mid = (unsigned)((((ull)lo + (ull)hi) + 1ull) >> 1);
    int c = 0;
#pragma unroll
    for (int j = 0; j < 8; ++j) c += (key[j] >= mid) ? 1 : 0;
    int cnt = tk_blksum(c, tid, s);
    if (cnt >= KTOP) lo = mid; else hi = mid - 1;
  }
  return lo;
}

__device__ __forceinline__ void tk_scan_inc(int v, int tid, TkS& s) {
  s.scan[tid] = v;
  __syncthreads();
  for (int off = 1; off < 256; off <<= 1) {
    int t = (tid >= off) ? s.scan[tid - off] : 0;
    __syncthreads();
    s.scan[tid] += t;
    __syncthreads();
  }
}

__device__ __forceinline__ void tk_write(const unsigned key[8], unsigned V, int MEQ,
                                         int tid, u16* orow, TkS& s) {
  int ceq = 0;
#pragma unroll
  for (int j = 0; j < 8; ++j) ceq += (key[j] == V) ? 1 : 0;
  tk_scan_inc(ceq, tid, s);
  int run = s.scan[tid] - ceq;
  unsigned bits = 0;
#pragma unroll
  for (int j = 0; j < 8; ++j) {
    bool e = (key[j] == V);
    bool sel = (key[j] > V) || (e && (run < MEQ));
    if (e) run++;
    if (sel) bits |= (1u << j);
  }
  int csel = __popc(bits);
  __syncthreads();
  tk_scan_inc(csel, tid, s);
  int base = s.scan[tid] - csel;
#pragma unroll
  for (int j = 0; j < 8; ++j)
    if ((bits >> j) & 1u) orow[base++] = (u16)(tid * 8 + j);
}

// ---------------------------------------------------------------------------
// Split x into hi/lo bf16 pair (x = hi + lo to ~2^-17 rel).
// Also zeroes the per-batch fixup flag counters (runs first on the stream).
// ---------------------------------------------------------------------------
__global__ __launch_bounds__(256) void pack_x(
    const float* __restrict__ x, u16* __restrict__ xh, u16* __restrict__ xl,
    int* __restrict__ flagcnt)
{
  if (blockIdx.x == 0 && threadIdx.x < NB) flagcnt[threadIdx.x] = 0;
  const int i = (blockIdx.x * 256 + threadIdx.x) * 8;
  float4 a = *(const float4*)(x + i);
  float4 b = *(const float4*)(x + i + 4);
  float v[8] = {a.x,a.y,a.z,a.w,b.x,b.y,b.z,b.w};
  u16 h[8], l[8];
#pragma unroll
  for (int j = 0; j < 8; ++j) {
    h[j] = f2bf(v[j]);
    l[j] = f2bf(v[j] - bf2f(h[j]));
  }
  uint4 ph, pl;
  ph.x = h[0] | ((unsigned)h[1] << 16); ph.y = h[2] | ((unsigned)h[3] << 16);
  ph.z = h[4] | ((unsigned)h[5] << 16); ph.w = h[6] | ((unsigned)h[7] << 16);
  pl.x = l[0] | ((unsigned)l[1] << 16); pl.y = l[2] | ((unsigned)l[3] << 16);
  pl.z = l[4] | ((unsigned)l[5] << 16); pl.w = l[6] | ((unsigned)l[7] << 16);
  *(uint4*)(xh + i) = ph;
  *(uint4*)(xl + i) = pl;
}

// ---------------------------------------------------------------------------
// scores = x @ x^T / 16 via bf16 MFMA, FULL 2x2 split (hh+hl+lh+ll):
// residual ~9e-6 rms / ~5e-5 max; rows whose top-k margin < MBOUND are
// recomputed exactly by fixup_gemm + topk_fixup.
// ---------------------------------------------------------------------------
__global__ __launch_bounds__(256) void scores_mfma(
    const u16* __restrict__ xh, const u16* __restrict__ xl,
    float* __restrict__ C)
{
  __shared__ u16 Ah[128 * 40], Al[128 * 40], Bh[128 * 40], Bl[128 * 40];
  const int tid = threadIdx.x;
  const int m0 = blockIdx.x * 128, n0 = blockIdx.y * 128;
  const u16* xhB = xh + (size_t)blockIdx.z * SEQ * EMB;
  const u16* xlB = xl + (size_t)blockIdx.z * SEQ * EMB;
  float* Cb = C + (size_t)blockIdx.z * SEQ * SEQ;
  const int wv = tid >> 6, ln = tid & 63;
  const int quad = ln >> 4, r16 = ln & 15;
  const int wm = (wv & 1) * 64, wn = (wv >> 1) * 64;
  const int srow = tid >> 1, shalf = (tid & 1) * 16;

  f32x4v acc[4][4];
#pragma unroll
  for (int i = 0; i < 4; ++i)
#pragma unroll
    for (int j = 0; j < 4; ++j) acc[i][j] = (f32x4v){0.f, 0.f, 0.f, 0.f};

  for (int k0 = 0; k0 < EMB; k0 += 32) {
    __syncthreads();
    {
      size_t ga = (size_t)(m0 + srow) * EMB + k0 + shalf;
      size_t gb = (size_t)(n0 + srow) * EMB + k0 + shalf;
      uint4 ah0 = *(const uint4*)(xhB + ga), ah1 = *(const uint4*)(xhB + ga + 8);
      uint4 al0 = *(const uint4*)(xlB + ga), al1 = *(const uint4*)(xlB + ga + 8);
      uint4 bh0 = *(const uint4*)(xhB + gb), bh1 = *(const uint4*)(xhB + gb + 8);
      uint4 bl0 = *(const uint4*)(xlB + gb), bl1 = *(const uint4*)(xlB + gb + 8);
      int o = srow * 40 + shalf;
      *(uint4*)&Ah[o] = ah0; *(uint4*)&Ah[o + 8] = ah1;
      *(uint4*)&Al[o] = al0; *(uint4*)&Al[o + 8] = al1;
      *(uint4*)&Bh[o] = bh0; *(uint4*)&Bh[o + 8] = bh1;
      *(uint4*)&Bl[o] = bl0; *(uint4*)&Bl[o + 8] = bl1;
    }
    __syncthreads();
    frag8 fbh[4], fbl[4];
#pragma unroll
    for (int nt = 0; nt < 4; ++nt) {
      int ob = (wn + nt * 16 + r16) * 40 + quad * 8;
      fbh[nt] = *(const frag8*)&Bh[ob];
      fbl[nt] = *(const frag8*)&Bl[ob];
    }
#pragma unroll
    for (int mt = 0; mt < 4; ++mt) {
      int oa = (wm + mt * 16 + r16) * 40 + quad * 8;
      frag8 fah = *(const frag8*)&Ah[oa];
      frag8 fal = *(const frag8*)&Al[oa];
#pragma unroll
      for (int nt = 0; nt < 4; ++nt) {
        acc[mt][nt] = __builtin_amdgcn_mfma_f32_16x16x32_bf16(fah, fbh[nt], acc[mt][nt], 0, 0, 0);
        acc[mt][nt] = __builtin_amdgcn_mfma_f32_16x16x32_bf16(fah, fbl[nt], acc[mt][nt], 0, 0, 0);
        acc[mt][nt] = __builtin_amdgcn_mfma_f32_16x16x32_bf16(fal, fbh[nt], acc[mt][nt], 0, 0, 0);
        acc[mt][nt] = __builtin_amdgcn_mfma_f32_16x16x32_bf16(fal, fbl[nt], acc[mt][nt], 0, 0, 0);
      }
    }
  }
  // C/D layout: col = lane&15, row = quad*4 + reg  [m89/m91]
#pragma unroll
  for (int mt = 0; mt < 4; ++mt)
#pragma unroll
    for (int nt = 0; nt < 4; ++nt) {
      int cg = n0 + wn + nt * 16 + r16;
      int rb = m0 + wm + mt * 16 + quad * 4;
#pragma unroll
      for (int r = 0; r < 4; ++r)
        Cb[(size_t)(rb + r) * SEQ + cg] = acc[mt][nt][r] * 0.0625f;
    }
}

// ---------------------------------------------------------------------------
// fp32 GEMM, 64x64 tile, 4x4/thread: QKV fused via z. Q out fp32; K/V bf16.
// ---------------------------------------------------------------------------
__global__ __launch_bounds__(256) void gemm_qkv(
    const float* __restrict__ x,
    const float* __restrict__ Wq, const float* __restrict__ bq,
    const float* __restrict__ Wk, const float* __restrict__ bk,
    const float* __restrict__ Wv, const float* __restrict__ bv,
    float* __restrict__ qo, u16* __restrict__ ko, u16* __restrict__ vo)
{
  const float* B  = (blockIdx.z == 0) ? Wq : (blockIdx.z == 1) ? Wk : Wv;
  const float* bi_ = (blockIdx.z == 0) ? bq : (blockIdx.z == 1) ? bk : bv;

  __shared__ float As[16][68];
  __shared__ float Bs[16][68];
  const int tid = threadIdx.x;
  const int m0 = blockIdx.x * 64, n0 = blockIdx.y * 64;
  const int lm = tid >> 2;
  const int lk = (tid & 3) << 2;
  const int mt = tid >> 4;
  const int nt = tid & 15;
  float acc[4][4] = {{0.f}};
  for (int k0 = 0; k0 < EMB; k0 += 16) {
    float4 av = *(const float4*)(x + (size_t)(m0 + lm) * EMB + k0 + lk);
    float4 bv4 = *(const float4*)(B + (size_t)(n0 + lm) * EMB + k0 + lk);
    __syncthreads();
    As[lk+0][lm] = av.x; As[lk+1][lm] = av.y; As[lk+2][lm] = av.z; As[lk+3][lm] = av.w;
    Bs[lk+0][lm] = bv4.x; Bs[lk+1][lm] = bv4.y; Bs[lk+2][lm] = bv4.z; Bs[lk+3][lm] = bv4.w;
    __syncthreads();
#pragma unroll
    for (int kk = 0; kk < 16; ++kk) {
      float4 a4 = *(const float4*)&As[kk][mt << 2];
      float4 b4 = *(const float4*)&Bs[kk][nt << 2];
      acc[0][0] += a4.x*b4.x; acc[0][1] += a4.x*b4.y; acc[0][2] += a4.x*b4.z; acc[0][3] += a4.x*b4.w;
      acc[1][0] += a4.y*b4.x; acc[1][1] += a4.y*b4.y; acc[1][2] += a4.y*b4.z; acc[1][3] += a4.y*b4.w;
      acc[2][0] += a4.z*b4.x; acc[2][1] += a4.z*b4.y; acc[2][2] += a4.z*b4.z; acc[2][3] += a4.z*b4.w;
      acc[3][0] += a4.w*b4.x; acc[3][1] += a4.w*b4.y; acc[3][2] += a4.w*b4.z; acc[3][3] += a4.w*b4.w;
    }
  }
  float4 bi = *(const float4*)(bi_ + n0 + (nt << 2));
  if (blockIdx.z == 0) {
#pragma unroll
    for (int r = 0; r < 4; ++r) {
      float4 o;
      o.x = acc[r][0] + bi.x; o.y = acc[r][1] + bi.y;
      o.z = acc[r][2] + bi.z; o.w = acc[r][3] + bi.w;
      *(float4*)(qo + (size_t)(m0 + (mt << 2) + r) * EMB + n0 + (nt << 2)) = o;
    }
  } else {
    u16* C = (blockIdx.z == 1) ? ko : vo;
#pragma unroll
    for (int r = 0; r < 4; ++r) {
      ushort4 o;
      o.x = f2bf(acc[r][0] + bi.x); o.y = f2bf(acc[r][1] + bi.y);
      o.z = f2bf(acc[r][2] + bi.z); o.w = f2bf(acc[r][3] + bi.w);
      *(ushort4*)(C + (size_t)(m0 + (mt << 2) + r) * EMB + n0 + (nt << 2)) = o;
    }
  }
}

// ---------------------------------------------------------------------------
// fp32 GEMM, 64x64 tile — out projection.
// ---------------------------------------------------------------------------
__global__ __launch_bounds__(256) void gemm_abT(
    const float* __restrict__ A, const float* __restrict__ B,
    const float* __restrict__ bias, float* __restrict__ C)
{
  __shared__ float As[16][68];
  __shared__ float Bs[16][68];
  const int tid = threadIdx.x;
  const int m0 = blockIdx.x * 64, n0 = blockIdx.y * 64;
  const int lm = tid >> 2;
  const int lk = (tid & 3) << 2;
  const int mt = tid >> 4;
  const int nt = tid & 15;
  float acc[4][4] = {{0.f}};
  for (int k0 = 0; k0 < EMB; k0 += 16) {
    float4 av = *(const float4*)(A + (size_t)(m0 + lm) * EMB + k0 + lk);
    float4 bv = *(const float4*)(B + (size_t)(n0 + lm) * EMB + k0 + lk);
    __syncthreads();
    As[lk+0][lm] = av.x; As[lk+1][lm] = av.y; As[lk+2][lm] = av.z; As[lk+3][lm] = av.w;
    Bs[lk+0][lm] = bv.x; Bs[lk+1][lm] = bv.y; Bs[lk+2][lm] = bv.z; Bs[lk+3][lm] = bv.w;
    __syncthreads();
#pragma unroll
    for (int kk = 0; kk < 16; ++kk) {
      float4 a4 = *(const float4*)&As[kk][mt << 2];
      float4 b4 = *(const float4*)&Bs[kk][nt << 2];
      acc[0][0] += a4.x*b4.x; acc[0][1] += a4.x*b4.y; acc[0][2] += a4.x*b4.z; acc[0][3] += a4.x*b4.w;
      acc[1][0] += a4.y*b4.x; acc[1][1] += a4.y*b4.y; acc[1][2] += a4.y*b4.z; acc[1][3] += a4.y*b4.w;
      acc[2][0] += a4.z*b4.x; acc[2][1] += a4.z*b4.y; acc[2][2] += a4.z*b4.z; acc[2][3] += a4.z*b4.w;
      acc[3][0] += a4.w*b4.x; acc[3][1] += a4.w*b4.y; acc[3][2] += a4.w*b4.z; acc[3][3] += a4.w*b4.w;
    }
  }
  float4 bi = *(const float4*)(bias + n0 + (nt << 2));
#pragma unroll
  for (int r = 0; r < 4; ++r) {
    float4 o;
    o.x = acc[r][0] + bi.x; o.y = acc[r][1] + bi.y;
    o.z = acc[r][2] + bi.z; o.w = acc[r][3] + bi.w;
    *(float4*)(C + (size_t)(m0 + (mt << 2) + r) * EMB + n0 + (nt << 2)) = o;
  }
}

// ---------------------------------------------------------------------------
// Top-k per row on approx scores, with margin flagging into per-batch lists.
// ---------------------------------------------------------------------------
__global__ __launch_bounds__(256) void topk_idx(
    const float* __restrict__ scores, u16* __restrict__ idxl,
    int* __restrict__ flagcnt, int* __restrict__ flaglist)
{
  __shared__ TkS s;
  const int r = blockIdx.x;
  const int tid = threadIdx.x;
  const float* row = scores + (size_t)r * SEQ;
  unsigned key[8];
  {
    float4 f0 = *(const float4*)(row + tid * 8);
    float4 f1 = *(const float4*)(row + tid * 8 + 4);
    key[0]=f2ord(f0.x); key[1]=f2ord(f0.y); key[2]=f2ord(f0.z); key[3]=f2ord(f0.w);
    key[4]=f2ord(f1.x); key[5]=f2ord(f1.y); key[6]=f2ord(f1.z); key[7]=f2ord(f1.w);
  }
  const unsigned V = tk_kth(key, tid, s);

  int cgt = 0, ceq = 0;
#pragma unroll
  for (int j = 0; j < 8; ++j) {
    cgt += (key[j] > V) ? 1 : 0;
    ceq += (key[j] == V) ? 1 : 0;
  }
  const int GT = tk_blksum(cgt, tid, s);
  const int EQ = tk_blksum(ceq, tid, s);
  const int MEQ = KTOP - GT;

  // margin: next ordinal value strictly below V
  {
    unsigned mk = 0;
#pragma unroll
    for (int j = 0; j < 8; ++j)
      if (key[j] < V && key[j] > mk) mk = key[j];
    for (int off = 32; off > 0; off >>= 1) {
      unsigned o = (unsigned)__shfl_down((int)mk, off, 64);
      if (o > mk) mk = o;
    }
    const int lane = tid & 63, wid = tid >> 6;
    if (lane == 0) s.wsum[wid] = (int)mk;
    __syncthreads();
    if (tid == 0) {
      unsigned m2 = (unsigned)s.wsum[0];
      for (int w = 1; w < 4; ++w)
        if ((unsigned)s.wsum[w] > m2) m2 = (unsigned)s.wsum[w];
      bool flag = (EQ > MEQ) || !(ord2f(V) - ord2f(m2) >= MBOUND);
      if (flag) {
        int bb = r >> 11;
        int p = atomicAdd(&flagcnt[bb], 1);
        flaglist[bb * SEQ + p] = r & (SEQ - 1);
      }
    }
    __syncthreads();
  }

  tk_write(key, V, MEQ, tid, idxl + (size_t)r * IDXP, s);
}

// ---------------------------------------------------------------------------
// Fixup stage A: exact fp32 scores for flagged rows (gathered-A 64x64 GEMM),
// written in place over the approx scores in the attn region.
// grid = (32 key-tiles, groups of 64 flagged rows, NB batches).
// ---------------------------------------------------------------------------
__global__ __launch_bounds__(256) void fixup_gemm(
    const float* __restrict__ x, const int* __restrict__ flagcnt,
    const int* __restrict__ flaglist, float* __restrict__ attn)
{
  const int b = blockIdx.z;
  const int n = flagcnt[b];
  const int g0 = blockIdx.y * 64;
  if (g0 >= n) return;
  __shared__ float As[16][68];
  __shared__ float Bs[16][68];
  __shared__ int rowsh[64];
  const int tid = threadIdx.x;
  const int n0 = blockIdx.x * 64;   // key tile
  if (tid < 64) {
    int gi = g0 + tid;
    rowsh[tid] = (gi < n) ? flaglist[b * SEQ + gi] : -1;
  }
  __syncthreads();
  const float* xb = x + (size_t)b * SEQ * EMB;
  const int lm = tid >> 2;
  const int lk = (tid & 3) << 2;
  const int mt = tid >> 4;
  const int nt = tid & 15;
  const int arow = rowsh[lm];
  const int arowL = (arow < 0) ? 0 : arow;
  float acc[4][4] = {{0.f}};
  for (int k0 = 0; k0 < EMB; k0 += 16) {
    float4 av = *(const float4*)(xb + (size_t)arowL * EMB + k0 + lk);
    float4 bv = *(const float4*)(xb + (size_t)(n0 + lm) * EMB + k0 + lk);
    __syncthreads();
    As[lk+0][lm] = av.x; As[lk+1][lm] = av.y; As[lk+2][lm] = av.z; As[lk+3][lm] = av.w;
    Bs[lk+0][lm] = bv.x; Bs[lk+1][lm] = bv.y; Bs[lk+2][lm] = bv.z; Bs[lk+3][lm] = bv.w;
    __syncthreads();
#pragma unroll
    for (int kk = 0; kk < 16; ++kk) {
      float4 a4 = *(const float4*)&As[kk][mt << 2];
      float4 b4 = *(const float4*)&Bs[kk][nt << 2];
      acc[0][0] += a4.x*b4.x; acc[0][1] += a4.x*b4.y; acc[0][2] += a4.x*b4.z; acc[0][3] += a4.x*b4.w;
      acc[1][0] += a4.y*b4.x; acc[1][1] += a4.y*b4.y; acc[1][2] += a4.y*b4.z; acc[1][3] += a4.y*b4.w;
      acc[2][0] += a4.z*b4.x; acc[2][1] += a4.z*b4.y; acc[2][2] += a4.z*b4.z; acc[2][3] += a4.z*b4.w;
      acc[3][0] += a4.w*b4.x; acc[3][1] += a4.w*b4.y; acc[3][2] += a4.w*b4.z; acc[3][3] += a4.w*b4.w;
    }
  }
  float* attnB = attn + (size_t)b * SEQ * SEQ;
#pragma unroll
  for (int r = 0; r < 4; ++r) {
    int rr = rowsh[(mt << 2) + r];
    if (rr >= 0) {
      float4 o;
      o.x = acc[r][0] * 0.0625f; o.y = acc[r][1] * 0.0625f;
      o.z = acc[r][2] * 0.0625f; o.w = acc[r][3] * 0.0625f;
      *(float4*)(attnB + (size_t)rr * SEQ + n0 + (nt << 2)) = o;
    }
  }
}

// ---------------------------------------------------------------------------
// Fixup stage B: redo top-k on the (now exact) flagged rows.
// grid = (SEQ, NB); blocks beyond the flag count exit immediately.
// ---------------------------------------------------------------------------
__global__ __launch_bounds__(256) void topk_fixup(
    const float* __restrict__ attn, const int* __restrict__ flagcnt,
    const int* __restrict__ flaglist, u16* __restrict__ idxl)
{
  const int b = blockIdx.y;
  if ((int)blockIdx.x >= flagcnt[b]) return;
  const int r = b * SEQ + flaglist[b * SEQ + blockIdx.x];
  __shared__ TkS s;
  const int tid = threadIdx.x;
  const float* row = attn + (size_t)r * SEQ;
  unsigned key[8];
  {
    float4 f0 = *(const float4*)(row + tid * 8);
    float4 f1 = *(const float4*)(row + tid * 8 + 4);
    key[0]=f2ord(f0.x); key[1]=f2ord(f0.y); key[2]=f2ord(f0.z); key[3]=f2ord(f0.w);
    key[4]=f2ord(f1.x); key[5]=f2ord(f1.y); key[6]=f2ord(f1.z); key[7]=f2ord(f1.w);
  }
  const unsigned V = tk_kth(key, tid, s);
  int cgt = 0;
#pragma unroll
  for (int j = 0; j < 8; ++j) cgt += (key[j] > V) ? 1 : 0;
  const int GT = tk_blksum(cgt, tid, s);
  tk_write(key, V, KTOP - GT, tid, idxl + (size_t)r * IDXP, s);
}

// ---------------------------------------------------------------------------
// Single-pass sparse attention (v4): bf16 K/V gathers, 4-way batched index
// reads, LDS-dense attn row, XCD batch swizzle.
// ---------------------------------------------------------------------------
__global__ __launch_bounds__(256) void sparse_attn(
    const float* __restrict__ qb, const u16* __restrict__ kbh,
    const u16* __restrict__ vbh, const u16* __restrict__ idxl,
    float* __restrict__ attn, float* __restrict__ ctxb)
{
  const int lin = blockIdx.x;
  const int b = lin & 3;                                  // XCD-stable batch
  const int q = (lin >> 3) + (((lin >> 2) & 1) << 10);
  const int tid = threadIdx.x;
  const int wv = tid >> 6, ln = tid & 63;
  const int h = ln >> 3, hd8 = ln & 7;
  __shared__ int   ish[IDXP];
  __shared__ float psh[IDXP * 9 + 4];   // [j][h], stride 9
  __shared__ float idsh[NH];
  __shared__ float csh[4][EMB + 8];
  __shared__ float rsh[SEQ];            // dense attn row

  const int row = b * SEQ + q;
  if (tid < KTOP)      ish[tid] = (int)idxl[(size_t)row * IDXP + tid];
  else if (tid < IDXP) ish[tid] = 0;    // pad keys -> gather row 0, prob 0
  if (tid < 32) psh[(KTOP + (tid >> 3)) * 9 + (tid & 7)] = 0.f;  // pad probs

  float4 z4 = make_float4(0.f, 0.f, 0.f, 0.f);
  *(float4*)&rsh[tid * 4]        = z4;
  *(float4*)&rsh[1024 + tid * 4] = z4;

  // q fragment: lane ln holds q[row][ln*4 .. ln*4+3]
  float4 qv = *(const float4*)(qb + (size_t)row * EMB + ln * 4);

  __syncthreads();

  const float scale = 0.17677669529663687f;  // 1/sqrt(32)
  const u16* kbB = kbh + (size_t)(b * SEQ) * EMB;
  const int jb = wv * KPW;
#pragma unroll 2
  for (int t = 0; t < KPW; t += 4) {
    const int j = jb + t;
    int i0 = ish[j], i1 = ish[j+1], i2 = ish[j+2], i3 = ish[j+3];
    ushort4 k0 = *(const ushort4*)(kbB + (size_t)i0 * EMB + ln * 4);
    ushort4 k1 = *(const ushort4*)(kbB + (size_t)i1 * EMB + ln * 4);
    ushort4 k2 = *(const ushort4*)(kbB + (size_t)i2 * EMB + ln * 4);
    ushort4 k3 = *(const ushort4*)(kbB + (size_t)i3 * EMB + ln * 4);
    float p0 = dotbf(qv, k0), p1 = dotbf(qv, k1), p2 = dotbf(qv, k2), p3 = dotbf(qv, k3);
    p0 += __shfl_xor(p0, 4, 64); p1 += __shfl_xor(p1, 4, 64);
    p2 += __shfl_xor(p2, 4, 64); p3 += __shfl_xor(p3, 4, 64);
    p0 += __shfl_xor(p0, 2, 64); p1 += __shfl_xor(p1, 2, 64);
    p2 += __shfl_xor(p2, 2, 64); p3 += __shfl_xor(p3, 2, 64);
    p0 += __shfl_xor(p0, 1, 64); p1 += __shfl_xor(p1, 1, 64);
    p2 += __shfl_xor(p2, 1, 64); p3 += __shfl_xor(p3, 1, 64);
    if (hd8 == 0) {
      if (j + 0 < KTOP) psh[(j+0) * 9 + h] = __expf(p0 * scale);
      if (j + 1 < KTOP) psh[(j+1) * 9 + h] = __expf(p1 * scale);
      if (j + 2 < KTOP) psh[(j+2) * 9 + h] = __expf(p2 * scale);
      if (j + 3 < KTOP) psh[(j+3) * 9 + h] = __expf(p3 * scale);
    }
  }
  __syncthreads();

  // per-head denominators
  {
    int h2 = tid >> 5, l = tid & 31;
    float sden = 0.f;
    for (int j = l; j < KTOP; j += 32) sden += psh[j * 9 + h2];
#pragma unroll
    for (int off = 16; off > 0; off >>= 1) sden += __shfl_down(sden, off, 32);
    if (l == 0) idsh[h2] = 1.0f / sden;
  }
  __syncthreads();

  // normalize in place; head-mean scatter into LDS row
  if (tid < KTOP) {
    float ps = 0.f;
#pragma unroll
    for (int hh = 0; hh < 8; ++hh) {
      float pp = psh[tid * 9 + hh] * idsh[hh];
      psh[tid * 9 + hh] = pp;
      ps += pp;
    }
    rsh[ish[tid]] = ps * 0.125f;
  }
  __syncthreads();

  // stream dense row out (full-line, conflict-free)
  {
    float* arow = attn + (size_t)row * SEQ;
    *(float4*)(arow + tid * 4)        = *(const float4*)&rsh[tid * 4];
    *(float4*)(arow + 1024 + tid * 4) = *(const float4*)&rsh[1024 + tid * 4];
  }

  // ctx: wave wv accumulates its 52 keys (pads have p=0)
  {
    const u16* vbB = vbh + (size_t)(b * SEQ) * EMB;
    float4 acc = z4;
#pragma unroll 2
    for (int t = 0; t < KPW; t += 4) {
      const int j = jb + t;
      int i0 = ish[j], i1 = ish[j+1], i2 = ish[j+2], i3 = ish[j+3];
      ushort4 v0 = *(const ushort4*)(vbB + (size_t)i0 * EMB + ln * 4);
      ushort4 v1 = *(const ushort4*)(vbB + (size_t)i1 * EMB + ln * 4);
      ushort4 v2 = *(const ushort4*)(vbB + (size_t)i2 * EMB + ln * 4);
      ushort4 v3 = *(const ushort4*)(vbB + (size_t)i3 * EMB + ln * 4);
      float p0 = psh[(j+0) * 9 + h], p1 = psh[(j+1) * 9 + h];
      float p2 = psh[(j+2) * 9 + h], p3 = psh[(j+3) * 9 + h];
      acc.x += p0*bf2f(v0.x) + p1*bf2f(v1.x) + p2*bf2f(v2.x) + p3*bf2f(v3.x);
      acc.y += p0*bf2f(v0.y) + p1*bf2f(v1.y) + p2*bf2f(v2.y) + p3*bf2f(v3.y);
      acc.z += p0*bf2f(v0.z) + p1*bf2f(v1.z) + p2*bf2f(v2.z) + p3*bf2f(v3.z);
      acc.w += p0*bf2f(v0.w) + p1*bf2f(v1.w) + p2*bf2f(v2.w) + p3*bf2f(v3.w);
    }
    *(float4*)&csh[wv][ln * 4] = acc;
  }
  __syncthreads();
  if (tid < 64) {
    float4 o = z4;
#pragma unroll
    for (int g = 0; g < 4; ++g) {
      float4 v = *(const float4*)&csh[g][tid * 4];
      o.x += v.x; o.y += v.y; o.z += v.z; o.w += v.w;
    }
    *(float4*)(ctxb + (size_t)row * EMB + tid * 4) = o;
  }
}

// ---------------------------------------------------------------------------
extern "C" void kernel_launch(void* const* d_in, const int* in_sizes, int n_in,
                              void* d_out, int out_size, void* d_ws, size_t ws_size,
                              hipStream_t stream)
{
  const float* x  = (const float*)d_in[0];
  const float* Wq = (const float*)d_in[1];
  const float* bq = (const float*)d_in[2];
  const float* Wk = (const float*)d_in[3];
  const float* bk = (const float*)d_in[4];
  const float* Wv = (const float*)d_in[5];
  const float* bv = (const float*)d_in[6];
  const float* Wo = (const float*)d_in[7];
  const float* bo = (const float*)d_in[8];

  float* out  = (float*)d_out;
  float* attn = out + (size_t)NB * SEQ * EMB;   // [B,S,S] region of d_out

  const size_t NSE = (size_t)NB * SEQ * EMB;    // 2097152
  float* qbuf = (float*)d_ws;
  float* ctxb = qbuf + NSE;
  u16*  xh   = (u16*)(ctxb + NSE);
  u16*  xl   = xh + NSE;
  u16*  kbh  = xl + NSE;
  u16*  vbh  = kbh + NSE;
  u16*  idxl = vbh + NSE;                       // NB*SEQ*IDXP u16
  int*  flagcnt  = (int*)(idxl + (size_t)NB * SEQ * IDXP);  // [NB]
  int*  flaglist = flagcnt + NB;                // NB * SEQ ints

  const dim3 blk(256);

  // hi/lo bf16 split of x (+ flag counter reset)
  pack_x<<<dim3(NSE / (256 * 8)), blk, 0, stream>>>(x, xh, xl, flagcnt);

  // fused Q/K/V projections (Q fp32, K/V bf16)
  gemm_qkv<<<dim3(128, 4, 3), blk, 0, stream>>>(x, Wq, bq, Wk, bk, Wv, bv,
                                                qbuf, kbh, vbh);

  // scores = x @ x^T / 16 via full split-bf16 MFMA (hh+hl+lh+ll)
  scores_mfma<<<dim3(16, 16, NB), blk, 0, stream>>>(xh, xl, attn);

  // top-k with margin flagging (per-batch lists)
  topk_idx<<<dim3(NB * SEQ), blk, 0, stream>>>(attn, idxl, flagcnt, flaglist);

  // exact fp32 scores for flagged rows, then re-run their top-k
  fixup_gemm<<<dim3(32, 32, NB), blk, 0, stream>>>(x, flagcnt, flaglist, attn);
  topk_fixup<<<dim3(SEQ, NB), blk, 0, stream>>>(attn, flagcnt, flaglist, idxl);

  // fused sparse attention
  sparse_attn<<<dim3(SEQ * NB), blk, 0, stream>>>(qbuf, kbh, vbh, idxl, attn, ctxb);

  // out = ctx @ Wo^T + bo
  gemm_abT<<<dim3(128, 4, 1), blk, 0, stream>>>(ctxb, Wo, bo, out);
}

// Round 8
// 413.923 us; speedup vs baseline: 1.2581x; 1.1780x over previous
//
#include <hip/hip_runtime.h>

#define SEQ  2048
#define EMB  256
#define NH   8
#define HD   32
#define NB   4
#define KTOP 204
#define IDXP 208
#define KPW  52       // keys per wave (4*52 = 208, padded)
#define MBOUND 4e-4f  // top-k margin for fp32 re-verify

typedef unsigned long long ull;
typedef unsigned short u16;

using frag8  = __attribute__((ext_vector_type(8))) short;  // 8 bf16
using f32x4v = __attribute__((ext_vector_type(4))) float;
typedef _Float16 f16;
typedef _Float16 f16x2 __attribute__((ext_vector_type(2)));

union U4 { uint4 u; f16x2 h[4]; };
union HU { f16 h; u16 u; };

#if defined(__has_builtin)
#if __has_builtin(__builtin_amdgcn_fdot2)
#define FDOT2(a,b,c) __builtin_amdgcn_fdot2(a, b, c, false)
#endif
#endif
#ifndef FDOT2
__device__ __forceinline__ float fdot2_sw(f16x2 a, f16x2 b, float c) {
  return c + (float)a[0]*(float)b[0] + (float)a[1]*(float)b[1];
}
#define FDOT2(a,b,c) fdot2_sw(a,b,c)
#endif

__device__ __forceinline__ unsigned f2ord(float f) {
  unsigned u = __float_as_uint(f);
  return (u & 0x80000000u) ? ~u : (u | 0x80000000u);
}
__device__ __forceinline__ float ord2f(unsigned o) {
  unsigned u = (o & 0x80000000u) ? (o ^ 0x80000000u) : ~o;
  return __uint_as_float(u);
}
__device__ __forceinline__ u16 f2bf(float f) {
  unsigned u = __float_as_uint(f);
  u += 0x7FFF + ((u >> 16) & 1);     // RTNE
  return (u16)(u >> 16);
}
__device__ __forceinline__ float bf2f(u16 h) {
  return __uint_as_float((unsigned)h << 16);
}

// ---------------------------------------------------------------------------
// Top-k machinery (binary search on ordinal bits, lowest-index tie-break).
// ---------------------------------------------------------------------------
struct TkS { int wsum[4]; int total; int scan[256]; };

__device__ __forceinline__ int tk_blksum(int v, int tid, TkS& s) {
  const int lane = tid & 63, wid = tid >> 6;
  for (int off = 32; off > 0; off >>= 1) v += __shfl_down(v, off, 64);
  if (lane == 0) s.wsum[wid] = v;
  __syncthreads();
  if (tid == 0) s.total = s.wsum[0] + s.wsum[1] + s.wsum[2] + s.wsum[3];
  __syncthreads();
  int r = s.total;
  __syncthreads();
  return r;
}

__device__ __forceinline__ unsigned tk_kth(const unsigned key[8], int tid, TkS& s) {
  unsigned lo = 0u, hi = 0xFFFFFFFFu;
  while (lo < hi) {
    unsigned mid = (unsigned)((((ull)lo + (ull)hi) + 1ull) >> 1);
    int c = 0;
#pragma unroll
    for (int j = 0; j < 8; ++j) c += (key[j] >= mid) ? 1 : 0;
    int cnt = tk_blksum(c, tid, s);
    if (cnt >= KTOP) lo = mid; else hi = mid - 1;
  }
  return lo;
}

__device__ __forceinline__ void tk_scan_inc(int v, int tid, TkS& s) {
  s.scan[tid] = v;
  __syncthreads();
  for (int off = 1; off < 256; off <<= 1) {
    int t = (tid >= off) ? s.scan[tid - off] : 0;
    __syncthreads();
    s.scan[tid] += t;
    __syncthreads();
  }
}

__device__ __forceinline__ void tk_write(const unsigned key[8], unsigned V, int MEQ,
                                         int tid, u16* orow, TkS& s) {
  int ceq = 0;
#pragma unroll
  for (int j = 0; j < 8; ++j) ceq += (key[j] == V) ? 1 : 0;
  tk_scan_inc(ceq, tid, s);
  int run = s.scan[tid] - ceq;
  unsigned bits = 0;
#pragma unroll
  for (int j = 0; j < 8; ++j) {
    bool e = (key[j] == V);
    bool sel = (key[j] > V) || (e && (run < MEQ));
    if (e) run++;
    if (sel) bits |= (1u << j);
  }
  int csel = __popc(bits);
  __syncthreads();
  tk_scan_inc(csel, tid, s);
  int base = s.scan[tid] - csel;
#pragma unroll
  for (int j = 0; j < 8; ++j)
    if ((bits >> j) & 1u) orow[base++] = (u16)(tid * 8 + j);
}

// ---------------------------------------------------------------------------
// Split fp32 -> bf16 hi/lo pair. flagcnt (nullable) zeroed by block 0.
// ---------------------------------------------------------------------------
__global__ __launch_bounds__(256) void pack_x(
    const float* __restrict__ x, u16* __restrict__ xh, u16* __restrict__ xl,
    int* __restrict__ flagcnt)
{
  if (flagcnt && blockIdx.x == 0 && threadIdx.x < NB) flagcnt[threadIdx.x] = 0;
  const int i = (blockIdx.x * 256 + threadIdx.x) * 8;
  float4 a = *(const float4*)(x + i);
  float4 b = *(const float4*)(x + i + 4);
  float v[8] = {a.x,a.y,a.z,a.w,b.x,b.y,b.z,b.w};
  u16 h[8], l[8];
#pragma unroll
  for (int j = 0; j < 8; ++j) {
    h[j] = f2bf(v[j]);
    l[j] = f2bf(v[j] - bf2f(h[j]));
  }
  uint4 ph, pl;
  ph.x = h[0] | ((unsigned)h[1] << 16); ph.y = h[2] | ((unsigned)h[3] << 16);
  ph.z = h[4] | ((unsigned)h[5] << 16); ph.w = h[6] | ((unsigned)h[7] << 16);
  pl.x = l[0] | ((unsigned)l[1] << 16); pl.y = l[2] | ((unsigned)l[3] << 16);
  pl.z = l[4] | ((unsigned)l[5] << 16); pl.w = l[6] | ((unsigned)l[7] << 16);
  *(uint4*)(xh + i) = ph;
  *(uint4*)(xl + i) = pl;
}

// ---------------------------------------------------------------------------
// Pack the 4 weight matrices into bf16 hi/lo pairs: wpk[m*2]=hi, [m*2+1]=lo.
// ---------------------------------------------------------------------------
__global__ __launch_bounds__(256) void pack_w(
    const float* __restrict__ W0, const float* __restrict__ W1,
    const float* __restrict__ W2, const float* __restrict__ W3,
    u16* __restrict__ wpk)
{
  const int m = blockIdx.y;
  const float* W = (m == 0) ? W0 : (m == 1) ? W1 : (m == 2) ? W2 : W3;
  const int i = (blockIdx.x * 256 + threadIdx.x) * 8;
  float4 a = *(const float4*)(W + i);
  float4 b = *(const float4*)(W + i + 4);
  float v[8] = {a.x,a.y,a.z,a.w,b.x,b.y,b.z,b.w};
  u16 h[8], l[8];
#pragma unroll
  for (int j = 0; j < 8; ++j) {
    h[j] = f2bf(v[j]);
    l[j] = f2bf(v[j] - bf2f(h[j]));
  }
  uint4 ph, pl;
  ph.x = h[0] | ((unsigned)h[1] << 16); ph.y = h[2] | ((unsigned)h[3] << 16);
  ph.z = h[4] | ((unsigned)h[5] << 16); ph.w = h[6] | ((unsigned)h[7] << 16);
  pl.x = l[0] | ((unsigned)l[1] << 16); pl.y = l[2] | ((unsigned)l[3] << 16);
  pl.z = l[4] | ((unsigned)l[5] << 16); pl.w = l[6] | ((unsigned)l[7] << 16);
  u16* dh = wpk + (size_t)m * 2 * 65536;
  *(uint4*)(dh + i) = ph;
  *(uint4*)(dh + 65536 + i) = pl;
}

// ---------------------------------------------------------------------------
// scores = x @ x^T / 16 via bf16 MFMA, FULL 2x2 split (hh+hl+lh+ll).
// ---------------------------------------------------------------------------
__global__ __launch_bounds__(256) void scores_mfma(
    const u16* __restrict__ xh, const u16* __restrict__ xl,
    float* __restrict__ C)
{
  __shared__ u16 Ah[128 * 40], Al[128 * 40], Bh[128 * 40], Bl[128 * 40];
  const int tid = threadIdx.x;
  const int m0 = blockIdx.x * 128, n0 = blockIdx.y * 128;
  const u16* xhB = xh + (size_t)blockIdx.z * SEQ * EMB;
  const u16* xlB = xl + (size_t)blockIdx.z * SEQ * EMB;
  float* Cb = C + (size_t)blockIdx.z * SEQ * SEQ;
  const int wv = tid >> 6, ln = tid & 63;
  const int quad = ln >> 4, r16 = ln & 15;
  const int wm = (wv & 1) * 64, wn = (wv >> 1) * 64;
  const int srow = tid >> 1, shalf = (tid & 1) * 16;

  f32x4v acc[4][4];
#pragma unroll
  for (int i = 0; i < 4; ++i)
#pragma unroll
    for (int j = 0; j < 4; ++j) acc[i][j] = (f32x4v){0.f, 0.f, 0.f, 0.f};

  for (int k0 = 0; k0 < EMB; k0 += 32) {
    __syncthreads();
    {
      size_t ga = (size_t)(m0 + srow) * EMB + k0 + shalf;
      size_t gb = (size_t)(n0 + srow) * EMB + k0 + shalf;
      uint4 ah0 = *(const uint4*)(xhB + ga), ah1 = *(const uint4*)(xhB + ga + 8);
      uint4 al0 = *(const uint4*)(xlB + ga), al1 = *(const uint4*)(xlB + ga + 8);
      uint4 bh0 = *(const uint4*)(xhB + gb), bh1 = *(const uint4*)(xhB + gb + 8);
      uint4 bl0 = *(const uint4*)(xlB + gb), bl1 = *(const uint4*)(xlB + gb + 8);
      int o = srow * 40 + shalf;
      *(uint4*)&Ah[o] = ah0; *(uint4*)&Ah[o + 8] = ah1;
      *(uint4*)&Al[o] = al0; *(uint4*)&Al[o + 8] = al1;
      *(uint4*)&Bh[o] = bh0; *(uint4*)&Bh[o + 8] = bh1;
      *(uint4*)&Bl[o] = bl0; *(uint4*)&Bl[o + 8] = bl1;
    }
    __syncthreads();
    frag8 fbh[4], fbl[4];
#pragma unroll
    for (int nt = 0; nt < 4; ++nt) {
      int ob = (wn + nt * 16 + r16) * 40 + quad * 8;
      fbh[nt] = *(const frag8*)&Bh[ob];
      fbl[nt] = *(const frag8*)&Bl[ob];
    }
#pragma unroll
    for (int mt = 0; mt < 4; ++mt) {
      int oa = (wm + mt * 16 + r16) * 40 + quad * 8;
      frag8 fah = *(const frag8*)&Ah[oa];
      frag8 fal = *(const frag8*)&Al[oa];
#pragma unroll
      for (int nt = 0; nt < 4; ++nt) {
        acc[mt][nt] = __builtin_amdgcn_mfma_f32_16x16x32_bf16(fah, fbh[nt], acc[mt][nt], 0, 0, 0);
        acc[mt][nt] = __builtin_amdgcn_mfma_f32_16x16x32_bf16(fah, fbl[nt], acc[mt][nt], 0, 0, 0);
        acc[mt][nt] = __builtin_amdgcn_mfma_f32_16x16x32_bf16(fal, fbh[nt], acc[mt][nt], 0, 0, 0);
        acc[mt][nt] = __builtin_amdgcn_mfma_f32_16x16x32_bf16(fal, fbl[nt], acc[mt][nt], 0, 0, 0);
      }
    }
  }
#pragma unroll
  for (int mt = 0; mt < 4; ++mt)
#pragma unroll
    for (int nt = 0; nt < 4; ++nt) {
      int cg = n0 + wn + nt * 16 + r16;
      int rb = m0 + wm + mt * 16 + quad * 4;
#pragma unroll
      for (int r = 0; r < 4; ++r)
        Cb[(size_t)(rb + r) * SEQ + cg] = acc[mt][nt][r] * 0.0625f;
    }
}

// ---------------------------------------------------------------------------
// QKV projection via bf16 MFMA, 3-term split (hh+hl+lh), f16 output.
// grid (64, 2, 3): z selects W/bias/output.
// ---------------------------------------------------------------------------
__global__ __launch_bounds__(256) void qkv_mfma(
    const u16* __restrict__ xh, const u16* __restrict__ xl,
    const u16* __restrict__ wpk,
    const float* __restrict__ bq, const float* __restrict__ bk,
    const float* __restrict__ bv,
    u16* __restrict__ qo, u16* __restrict__ ko, u16* __restrict__ vo)
{
  const int z = blockIdx.z;
  const u16* Wh = wpk + (size_t)z * 2 * 65536;
  const u16* Wl = Wh + 65536;
  const float* bias = (z == 0) ? bq : (z == 1) ? bk : bv;
  u16* out = (z == 0) ? qo : (z == 1) ? ko : vo;

  __shared__ u16 Ah[128 * 40], Al[128 * 40], Bh[128 * 40], Bl[128 * 40];
  const int tid = threadIdx.x;
  const int m0 = blockIdx.x * 128, n0 = blockIdx.y * 128;
  const int wv = tid >> 6, ln = tid & 63;
  const int quad = ln >> 4, r16 = ln & 15;
  const int wm = (wv & 1) * 64, wn = (wv >> 1) * 64;
  const int srow = tid >> 1, shalf = (tid & 1) * 16;

  f32x4v acc[4][4];
#pragma unroll
  for (int i = 0; i < 4; ++i)
#pragma unroll
    for (int j = 0; j < 4; ++j) acc[i][j] = (f32x4v){0.f, 0.f, 0.f, 0.f};

  for (int k0 = 0; k0 < EMB; k0 += 32) {
    __syncthreads();
    {
      size_t ga = (size_t)(m0 + srow) * EMB + k0 + shalf;
      size_t gb = (size_t)(n0 + srow) * EMB + k0 + shalf;
      uint4 ah0 = *(const uint4*)(xh + ga), ah1 = *(const uint4*)(xh + ga + 8);
      uint4 al0 = *(const uint4*)(xl + ga), al1 = *(const uint4*)(xl + ga + 8);
      uint4 bh0 = *(const uint4*)(Wh + gb), bh1 = *(const uint4*)(Wh + gb + 8);
      uint4 bl0 = *(const uint4*)(Wl + gb), bl1 = *(const uint4*)(Wl + gb + 8);
      int o = srow * 40 + shalf;
      *(uint4*)&Ah[o] = ah0; *(uint4*)&Ah[o + 8] = ah1;
      *(uint4*)&Al[o] = al0; *(uint4*)&Al[o + 8] = al1;
      *(uint4*)&Bh[o] = bh0; *(uint4*)&Bh[o + 8] = bh1;
      *(uint4*)&Bl[o] = bl0; *(uint4*)&Bl[o + 8] = bl1;
    }
    __syncthreads();
    frag8 fbh[4], fbl[4];
#pragma unroll
    for (int nt = 0; nt < 4; ++nt) {
      int ob = (wn + nt * 16 + r16) * 40 + quad * 8;
      fbh[nt] = *(const frag8*)&Bh[ob];
      fbl[nt] = *(const frag8*)&Bl[ob];
    }
#pragma unroll
    for (int mt = 0; mt < 4; ++mt) {
      int oa = (wm + mt * 16 + r16) * 40 + quad * 8;
      frag8 fah = *(const frag8*)&Ah[oa];
      frag8 fal = *(const frag8*)&Al[oa];
#pragma unroll
      for (int nt = 0; nt < 4; ++nt) {
        acc[mt][nt] = __builtin_amdgcn_mfma_f32_16x16x32_bf16(fah, fbh[nt], acc[mt][nt], 0, 0, 0);
        acc[mt][nt] = __builtin_amdgcn_mfma_f32_16x16x32_bf16(fah, fbl[nt], acc[mt][nt], 0, 0, 0);
        acc[mt][nt] = __builtin_amdgcn_mfma_f32_16x16x32_bf16(fal, fbh[nt], acc[mt][nt], 0, 0, 0);
      }
    }
  }
#pragma unroll
  for (int nt = 0; nt < 4; ++nt) {
    int cg = n0 + wn + nt * 16 + r16;
    float bvv = bias[cg];
#pragma unroll
    for (int mt = 0; mt < 4; ++mt) {
      int rb = m0 + wm + mt * 16 + quad * 4;
#pragma unroll
      for (int r = 0; r < 4; ++r) {
        HU hu; hu.h = (f16)(acc[mt][nt][r] + bvv);
        out[(size_t)(rb + r) * EMB + cg] = hu.u;
      }
    }
  }
}

// ---------------------------------------------------------------------------
// Out projection via bf16 MFMA, 3-term split, fp32 output + bias.
// grid (64, 2). A = packed ctx, B = wpk matrix 3 (Wo).
// ---------------------------------------------------------------------------
__global__ __launch_bounds__(256) void out_mfma(
    const u16* __restrict__ ch, const u16* __restrict__ cl,
    const u16* __restrict__ wpk, const float* __restrict__ bias,
    float* __restrict__ out)
{
  const u16* Wh = wpk + (size_t)3 * 2 * 65536;
  const u16* Wl = Wh + 65536;
  __shared__ u16 Ah[128 * 40], Al[128 * 40], Bh[128 * 40], Bl[128 * 40];
  const int tid = threadIdx.x;
  const int m0 = blockIdx.x * 128, n0 = blockIdx.y * 128;
  const int wv = tid >> 6, ln = tid & 63;
  const int quad = ln >> 4, r16 = ln & 15;
  const int wm = (wv & 1) * 64, wn = (wv >> 1) * 64;
  const int srow = tid >> 1, shalf = (tid & 1) * 16;

  f32x4v acc[4][4];
#pragma unroll
  for (int i = 0; i < 4; ++i)
#pragma unroll
    for (int j = 0; j < 4; ++j) acc[i][j] = (f32x4v){0.f, 0.f, 0.f, 0.f};

  for (int k0 = 0; k0 < EMB; k0 += 32) {
    __syncthreads();
    {
      size_t ga = (size_t)(m0 + srow) * EMB + k0 + shalf;
      size_t gb = (size_t)(n0 + srow) * EMB + k0 + shalf;
      uint4 ah0 = *(const uint4*)(ch + ga), ah1 = *(const uint4*)(ch + ga + 8);
      uint4 al0 = *(const uint4*)(cl + ga), al1 = *(const uint4*)(cl + ga + 8);
      uint4 bh0 = *(const uint4*)(Wh + gb), bh1 = *(const uint4*)(Wh + gb + 8);
      uint4 bl0 = *(const uint4*)(Wl + gb), bl1 = *(const uint4*)(Wl + gb + 8);
      int o = srow * 40 + shalf;
      *(uint4*)&Ah[o] = ah0; *(uint4*)&Ah[o + 8] = ah1;
      *(uint4*)&Al[o] = al0; *(uint4*)&Al[o + 8] = al1;
      *(uint4*)&Bh[o] = bh0; *(uint4*)&Bh[o + 8] = bh1;
      *(uint4*)&Bl[o] = bl0; *(uint4*)&Bl[o + 8] = bl1;
    }
    __syncthreads();
    frag8 fbh[4], fbl[4];
#pragma unroll
    for (int nt = 0; nt < 4; ++nt) {
      int ob = (wn + nt * 16 + r16) * 40 + quad * 8;
      fbh[nt] = *(const frag8*)&Bh[ob];
      fbl[nt] = *(const frag8*)&Bl[ob];
    }
#pragma unroll
    for (int mt = 0; mt < 4; ++mt) {
      int oa = (wm + mt * 16 + r16) * 40 + quad * 8;
      frag8 fah = *(const frag8*)&Ah[oa];
      frag8 fal = *(const frag8*)&Al[oa];
#pragma unroll
      for (int nt = 0; nt < 4; ++nt) {
        acc[mt][nt] = __builtin_amdgcn_mfma_f32_16x16x32_bf16(fah, fbh[nt], acc[mt][nt], 0, 0, 0);
        acc[mt][nt] = __builtin_amdgcn_mfma_f32_16x16x32_bf16(fah, fbl[nt], acc[mt][nt], 0, 0, 0);
        acc[mt][nt] = __builtin_amdgcn_mfma_f32_16x16x32_bf16(fal, fbh[nt], acc[mt][nt], 0, 0, 0);
      }
    }
  }
#pragma unroll
  for (int nt = 0; nt < 4; ++nt) {
    int cg = n0 + wn + nt * 16 + r16;
    float bvv = bias[cg];
#pragma unroll
    for (int mt = 0; mt < 4; ++mt) {
      int rb = m0 + wm + mt * 16 + quad * 4;
#pragma unroll
      for (int r = 0; r < 4; ++r)
        out[(size_t)(rb + r) * EMB + cg] = acc[mt][nt][r] + bvv;
    }
  }
}

// ---------------------------------------------------------------------------
// Top-k per row on approx scores, with margin flagging into per-batch lists.
// ---------------------------------------------------------------------------
__global__ __launch_bounds__(256) void topk_idx(
    const float* __restrict__ scores, u16* __restrict__ idxl,
    int* __restrict__ flagcnt, int* __restrict__ flaglist)
{
  __shared__ TkS s;
  const int r = blockIdx.x;
  const int tid = threadIdx.x;
  const float* row = scores + (size_t)r * SEQ;
  unsigned key[8];
  {
    float4 f0 = *(const float4*)(row + tid * 8);
    float4 f1 = *(const float4*)(row + tid * 8 + 4);
    key[0]=f2ord(f0.x); key[1]=f2ord(f0.y); key[2]=f2ord(f0.z); key[3]=f2ord(f0.w);
    key[4]=f2ord(f1.x); key[5]=f2ord(f1.y); key[6]=f2ord(f1.z); key[7]=f2ord(f1.w);
  }
  const unsigned V = tk_kth(key, tid, s);

  int cgt = 0, ceq = 0;
#pragma unroll
  for (int j = 0; j < 8; ++j) {
    cgt += (key[j] > V) ? 1 : 0;
    ceq += (key[j] == V) ? 1 : 0;
  }
  const int GT = tk_blksum(cgt, tid, s);
  const int EQ = tk_blksum(ceq, tid, s);
  const int MEQ = KTOP - GT;

  {
    unsigned mk = 0;
#pragma unroll
    for (int j = 0; j < 8; ++j)
      if (key[j] < V && key[j] > mk) mk = key[j];
    for (int off = 32; off > 0; off >>= 1) {
      unsigned o = (unsigned)__shfl_down((int)mk, off, 64);
      if (o > mk) mk = o;
    }
    const int lane = tid & 63, wid = tid >> 6;
    if (lane == 0) s.wsum[wid] = (int)mk;
    __syncthreads();
    if (tid == 0) {
      unsigned m2 = (unsigned)s.wsum[0];
      for (int w = 1; w < 4; ++w)
        if ((unsigned)s.wsum[w] > m2) m2 = (unsigned)s.wsum[w];
      bool flag = (EQ > MEQ) || !(ord2f(V) - ord2f(m2) >= MBOUND);
      if (flag) {
        int bb = r >> 11;
        int p = atomicAdd(&flagcnt[bb], 1);
        flaglist[bb * SEQ + p] = r & (SEQ - 1);
      }
    }
    __syncthreads();
  }

  tk_write(key, V, MEQ, tid, idxl + (size_t)r * IDXP, s);
}

// ---------------------------------------------------------------------------
// Fixup A: exact fp32 scores for flagged rows (gathered-A 64x64 GEMM).
// ---------------------------------------------------------------------------
__global__ __launch_bounds__(256) void fixup_gemm(
    const float* __restrict__ x, const int* __restrict__ flagcnt,
    const int* __restrict__ flaglist, float* __restrict__ attn)
{
  const int b = blockIdx.z;
  const int n = flagcnt[b];
  const int g0 = blockIdx.y * 64;
  if (g0 >= n) return;
  __shared__ float As[16][68];
  __shared__ float Bs[16][68];
  __shared__ int rowsh[64];
  const int tid = threadIdx.x;
  const int n0 = blockIdx.x * 64;
  if (tid < 64) {
    int gi = g0 + tid;
    rowsh[tid] = (gi < n) ? flaglist[b * SEQ + gi] : -1;
  }
  __syncthreads();
  const float* xb = x + (size_t)b * SEQ * EMB;
  const int lm = tid >> 2;
  const int lk = (tid & 3) << 2;
  const int mt = tid >> 4;
  const int nt = tid & 15;
  const int arow = rowsh[lm];
  const int arowL = (arow < 0) ? 0 : arow;
  float acc[4][4] = {{0.f}};
  for (int k0 = 0; k0 < EMB; k0 += 16) {
    float4 av = *(const float4*)(xb + (size_t)arowL * EMB + k0 + lk);
    float4 bv = *(const float4*)(xb + (size_t)(n0 + lm) * EMB + k0 + lk);
    __syncthreads();
    As[lk+0][lm] = av.x; As[lk+1][lm] = av.y; As[lk+2][lm] = av.z; As[lk+3][lm] = av.w;
    Bs[lk+0][lm] = bv.x; Bs[lk+1][lm] = bv.y; Bs[lk+2][lm] = bv.z; Bs[lk+3][lm] = bv.w;
    __syncthreads();
#pragma unroll
    for (int kk = 0; kk < 16; ++kk) {
      float4 a4 = *(const float4*)&As[kk][mt << 2];
      float4 b4 = *(const float4*)&Bs[kk][nt << 2];
      acc[0][0] += a4.x*b4.x; acc[0][1] += a4.x*b4.y; acc[0][2] += a4.x*b4.z; acc[0][3] += a4.x*b4.w;
      acc[1][0] += a4.y*b4.x; acc[1][1] += a4.y*b4.y; acc[1][2] += a4.y*b4.z; acc[1][3] += a4.y*b4.w;
      acc[2][0] += a4.z*b4.x; acc[2][1] += a4.z*b4.y; acc[2][2] += a4.z*b4.z; acc[2][3] += a4.z*b4.w;
      acc[3][0] += a4.w*b4.x; acc[3][1] += a4.w*b4.y; acc[3][2] += a4.w*b4.z; acc[3][3] += a4.w*b4.w;
    }
  }
  float* attnB = attn + (size_t)b * SEQ * SEQ;
#pragma unroll
  for (int r = 0; r < 4; ++r) {
    int rr = rowsh[(mt << 2) + r];
    if (rr >= 0) {
      float4 o;
      o.x = acc[r][0] * 0.0625f; o.y = acc[r][1] * 0.0625f;
      o.z = acc[r][2] * 0.0625f; o.w = acc[r][3] * 0.0625f;
      *(float4*)(attnB + (size_t)rr * SEQ + n0 + (nt << 2)) = o;
    }
  }
}

// ---------------------------------------------------------------------------
// Fixup B: redo top-k on the (now exact) flagged rows.
// ---------------------------------------------------------------------------
__global__ __launch_bounds__(256) void topk_fixup(
    const float* __restrict__ attn, const int* __restrict__ flagcnt,
    const int* __restrict__ flaglist, u16* __restrict__ idxl)
{
  const int b = blockIdx.y;
  if ((int)blockIdx.x >= flagcnt[b]) return;
  const int r = b * SEQ + flaglist[b * SEQ + blockIdx.x];
  __shared__ TkS s;
  const int tid = threadIdx.x;
  const float* row = attn + (size_t)r * SEQ;
  unsigned key[8];
  {
    float4 f0 = *(const float4*)(row + tid * 8);
    float4 f1 = *(const float4*)(row + tid * 8 + 4);
    key[0]=f2ord(f0.x); key[1]=f2ord(f0.y); key[2]=f2ord(f0.z); key[3]=f2ord(f0.w);
    key[4]=f2ord(f1.x); key[5]=f2ord(f1.y); key[6]=f2ord(f1.z); key[7]=f2ord(f1.w);
  }
  const unsigned V = tk_kth(key, tid, s);
  int cgt = 0;
#pragma unroll
  for (int j = 0; j < 8; ++j) cgt += (key[j] > V) ? 1 : 0;
  const int GT = tk_blksum(cgt, tid, s);
  tk_write(key, V, KTOP - GT, tid, idxl + (size_t)r * IDXP, s);
}

// ---------------------------------------------------------------------------
// Sparse attention v5: f16 Q/K/V, v_dot2_f32_f16 dots, 16B/lane 2-keys-per-
// wave-load, 32-bit precomputed byte offsets, LDS-dense attn row.
// Lane ln: half = ln>>5 (which of 2 keys), sl = ln&31 (dims sl*8..+7, head sl>>2).
// ---------------------------------------------------------------------------
__global__ __launch_bounds__(256) void sparse_attn(
    const u16* __restrict__ qf, const u16* __restrict__ kf,
    const u16* __restrict__ vf, const u16* __restrict__ idxl,
    float* __restrict__ attn, float* __restrict__ ctxb)
{
  const int lin = blockIdx.x;
  const int b = lin & 3;                                  // XCD-stable batch
  const int q = (lin >> 3) + (((lin >> 2) & 1) << 10);
  const int tid = threadIdx.x;
  const int wv = tid >> 6, ln = tid & 63;
  const int half = ln >> 5, sl = ln & 31;
  const int h = sl >> 2, d0 = sl * 8;
  const int lb = sl * 16;                                 // lane byte offset in row
  __shared__ int   ish[IDXP];
  __shared__ int   koff[IDXP];          // byte offsets (idx * 512)
  __shared__ float psh[IDXP * 9 + 4];   // [j][h], stride 9
  __shared__ float idsh[NH];
  __shared__ float csh[8][264];         // 8 partials x 256 dims (+pad)
  __shared__ float rsh[SEQ];            // dense attn row

  const int row = b * SEQ + q;
  if (tid < KTOP) {
    int idx = (int)idxl[(size_t)row * IDXP + tid];
    ish[tid] = idx;
    koff[tid] = idx << 9;
  } else if (tid < IDXP) {
    ish[tid] = 0; koff[tid] = 0;
  }
  if (tid < 32) psh[(KTOP + (tid >> 3)) * 9 + (tid & 7)] = 0.f;  // pad probs

  float4 z4 = make_float4(0.f, 0.f, 0.f, 0.f);
  *(float4*)&rsh[tid * 4]        = z4;
  *(float4*)&rsh[1024 + tid * 4] = z4;

  // q fragment: 8 dims (4 f16x2) at byte sl*16 of this row
  U4 qv;
  qv.u = *(const uint4*)((const char*)(qf + (size_t)row * EMB) + lb);

  __syncthreads();

  const float scale = 0.17677669529663687f;  // 1/sqrt(32)
  const char* kbC = (const char*)(kf + (size_t)(b * SEQ) * EMB);
  const int jb = wv * KPW;
#pragma unroll 4
  for (int t = 0; t < KPW; t += 2) {
    const int j = jb + t + half;
    U4 kv;
    kv.u = *(const uint4*)(kbC + (koff[j] + lb));
    float s = FDOT2(qv.h[0], kv.h[0],
              FDOT2(qv.h[1], kv.h[1],
              FDOT2(qv.h[2], kv.h[2],
              FDOT2(qv.h[3], kv.h[3], 0.f))));
    s += __shfl_xor(s, 1, 64);
    s += __shfl_xor(s, 2, 64);
    if ((sl & 3) == 0 && j < KTOP) psh[j * 9 + h] = __expf(s * scale);
  }
  __syncthreads();

  // per-head denominators
  {
    int h2 = tid >> 5, l = tid & 31;
    float sden = 0.f;
    for (int j = l; j < KTOP; j += 32) sden += psh[j * 9 + h2];
#pragma unroll
    for (int off = 16; off > 0; off >>= 1) sden += __shfl_down(sden, off, 32);
    if (l == 0) idsh[h2] = 1.0f / sden;
  }
  __syncthreads();

  // normalize in place; head-mean scatter into LDS row
  if (tid < KTOP) {
    float ps = 0.f;
#pragma unroll
    for (int hh = 0; hh < 8; ++hh) {
      float pp = psh[tid * 9 + hh] * idsh[hh];
      psh[tid * 9 + hh] = pp;
      ps += pp;
    }
    rsh[ish[tid]] = ps * 0.125f;
  }
  __syncthreads();

  // stream dense row out (full-line, conflict-free)
  {
    float* arow = attn + (size_t)row * SEQ;
    *(float4*)(arow + tid * 4)        = *(const float4*)&rsh[tid * 4];
    *(float4*)(arow + 1024 + tid * 4) = *(const float4*)&rsh[1024 + tid * 4];
  }

  // ctx: each lane accumulates its 8 dims over its half's keys (pads p=0)
  {
    const char* vbC = (const char*)(vf + (size_t)(b * SEQ) * EMB);
    float a8[8] = {0.f,0.f,0.f,0.f,0.f,0.f,0.f,0.f};
#pragma unroll 4
    for (int t = 0; t < KPW; t += 2) {
      const int j = jb + t + half;
      float p = psh[j * 9 + h];
      U4 vv;
      vv.u = *(const uint4*)(vbC + (koff[j] + lb));
      a8[0] += p * (float)vv.h[0][0]; a8[1] += p * (float)vv.h[0][1];
      a8[2] += p * (float)vv.h[1][0]; a8[3] += p * (float)vv.h[1][1];
      a8[4] += p * (float)vv.h[2][0]; a8[5] += p * (float)vv.h[2][1];
      a8[6] += p * (float)vv.h[3][0]; a8[7] += p * (float)vv.h[3][1];
    }
    const int pi = wv * 2 + half;
    *(float4*)&csh[pi][d0]     = make_float4(a8[0], a8[1], a8[2], a8[3]);
    *(float4*)&csh[pi][d0 + 4] = make_float4(a8[4], a8[5], a8[6], a8[7]);
  }
  __syncthreads();
  if (tid < 64) {
    float4 o = z4;
#pragma unroll
    for (int g = 0; g < 8; ++g) {
      float4 v = *(const float4*)&csh[g][tid * 4];
      o.x += v.x; o.y += v.y; o.z += v.z; o.w += v.w;
    }
    *(float4*)(ctxb + (size_t)row * EMB + tid * 4) = o;
  }
}

// ---------------------------------------------------------------------------
extern "C" void kernel_launch(void* const* d_in, const int* in_sizes, int n_in,
                              void* d_out, int out_size, void* d_ws, size_t ws_size,
                              hipStream_t stream)
{
  const float* x  = (const float*)d_in[0];
  const float* Wq = (const float*)d_in[1];
  const float* bq = (const float*)d_in[2];
  const float* Wk = (const float*)d_in[3];
  const float* bk = (const float*)d_in[4];
  const float* Wv = (const float*)d_in[5];
  const float* bv = (const float*)d_in[6];
  const float* Wo = (const float*)d_in[7];
  const float* bo = (const float*)d_in[8];

  float* out  = (float*)d_out;
  float* attn = out + (size_t)NB * SEQ * EMB;   // [B,S,S] region of d_out

  const size_t NSE = (size_t)NB * SEQ * EMB;    // 2097152
  u16* xh  = (u16*)d_ws;            // bf16 hi of x (later: hi of ctx)
  u16* xl  = xh + NSE;              // bf16 lo
  u16* qf  = xl + NSE;              // f16 Q
  u16* kf  = qf + NSE;              // f16 K
  u16* vf  = kf + NSE;              // f16 V
  u16* wpk = vf + NSE;              // 4 x (hi,lo) 256x256 bf16
  float* ctxb = (float*)(wpk + 4 * 2 * 65536);
  u16* idxl = (u16*)(ctxb + NSE);
  int* flagcnt  = (int*)(idxl + (size_t)NB * SEQ * IDXP);
  int* flaglist = flagcnt + NB;

  const dim3 blk(256);

  // bf16 hi/lo splits (x + the 4 weight matrices); flag counters reset
  pack_x<<<dim3(1024), blk, 0, stream>>>(x, xh, xl, flagcnt);
  pack_w<<<dim3(32, 4), blk, 0, stream>>>(Wq, Wk, Wv, Wo, wpk);

  // Q/K/V projections via MFMA (3-term), f16 outputs
  qkv_mfma<<<dim3(64, 2, 3), blk, 0, stream>>>(xh, xl, wpk, bq, bk, bv, qf, kf, vf);

  // scores = x @ x^T / 16 via full split-bf16 MFMA (4-term)
  scores_mfma<<<dim3(16, 16, NB), blk, 0, stream>>>(xh, xl, attn);

  // top-k with margin flagging; exact fp32 fixup of low-margin rows
  topk_idx<<<dim3(NB * SEQ), blk, 0, stream>>>(attn, idxl, flagcnt, flaglist);
  fixup_gemm<<<dim3(32, 32, NB), blk, 0, stream>>>(x, flagcnt, flaglist, attn);
  topk_fixup<<<dim3(SEQ, NB), blk, 0, stream>>>(attn, flagcnt, flaglist, idxl);

  // fused sparse attention (f16 gathers + fdot2)
  sparse_attn<<<dim3(SEQ * NB), blk, 0, stream>>>(qf, kf, vf, idxl, attn, ctxb);

  // out = ctx @ Wo^T + bo via MFMA (pack ctx into xh/xl, now free)
  pack_x<<<dim3(1024), blk, 0, stream>>>(ctxb, xh, xl, nullptr);
  out_mfma<<<dim3(64, 2), blk, 0, stream>>>(xh, xl, wpk, bo, out);
}

// Round 9
// 347.624 us; speedup vs baseline: 1.4981x; 1.1907x over previous
//
#include <hip/hip_runtime.h>

#define SEQ  2048
#define EMB  256
#define NH   8
#define HD   32
#define NB   4
#define KTOP 204
#define IDXP 208
#define KPW  52       // keys per wave (4*52 = 208, padded)
#define MBOUND 4e-4f  // top-k margin for fp32 re-verify

typedef unsigned long long ull;
typedef unsigned short u16;

using frag8  = __attribute__((ext_vector_type(8))) short;  // 8 bf16
using f32x4v = __attribute__((ext_vector_type(4))) float;
typedef _Float16 f16;
typedef _Float16 f16x2 __attribute__((ext_vector_type(2)));

union U4 { uint4 u; f16x2 h[4]; };
union HU { f16 h; u16 u; };

#if defined(__has_builtin)
#if __has_builtin(__builtin_amdgcn_fdot2)
#define FDOT2(a,b,c) __builtin_amdgcn_fdot2(a, b, c, false)
#endif
#endif
#ifndef FDOT2
__device__ __forceinline__ float fdot2_sw(f16x2 a, f16x2 b, float c) {
  return c + (float)a[0]*(float)b[0] + (float)a[1]*(float)b[1];
}
#define FDOT2(a,b,c) fdot2_sw(a,b,c)
#endif

__device__ __forceinline__ unsigned f2ord(float f) {
  unsigned u = __float_as_uint(f);
  return (u & 0x80000000u) ? ~u : (u | 0x80000000u);
}
__device__ __forceinline__ float ord2f(unsigned o) {
  unsigned u = (o & 0x80000000u) ? (o ^ 0x80000000u) : ~o;
  return __uint_as_float(u);
}
__device__ __forceinline__ u16 f2bf(float f) {
  unsigned u = __float_as_uint(f);
  u += 0x7FFF + ((u >> 16) & 1);     // RTNE
  return (u16)(u >> 16);
}
__device__ __forceinline__ float bf2f(u16 h) {
  return __uint_as_float((unsigned)h << 16);
}

// ---------------------------------------------------------------------------
// Radix-256 top-k: 4 byte-passes with per-wave LDS histograms + wave-0
// shuffle suffix-scan over bins. ~4 barriers/pass vs 3/step x 32 steps for
// binary search. Returns V (k-th largest ordinal) and MEQ (# equals to take).
// ---------------------------------------------------------------------------
__device__ __forceinline__ void tk_radix(
    const unsigned key[8], int tid, int (*hist)[256], int* sel,
    unsigned& V, int& MEQ)
{
  const int lane = tid & 63, wid = tid >> 6;
  unsigned prefix = 0;
  int k = KTOP;
#pragma unroll
  for (int p = 0; p < 4; ++p) {
    const int shift = 24 - 8 * p;
    hist[0][tid] = 0; hist[1][tid] = 0; hist[2][tid] = 0; hist[3][tid] = 0;
    __syncthreads();
#pragma unroll
    for (int j = 0; j < 8; ++j) {
      unsigned kj = key[j];
      bool ok = (p == 0) || ((kj >> (shift + 8)) == prefix);
      if (ok) atomicAdd(&hist[wid][(kj >> shift) & 255], 1);
    }
    __syncthreads();
    {
      int c = hist[0][tid] + hist[1][tid] + hist[2][tid] + hist[3][tid];
      hist[0][tid] = c;
    }
    __syncthreads();
    if (wid == 0) {
      int m0 = hist[0][lane * 4 + 0], m1 = hist[0][lane * 4 + 1];
      int m2 = hist[0][lane * 4 + 2], m3 = hist[0][lane * 4 + 3];
      int sl = m0 + m1 + m2 + m3;
      int suf = sl;                      // inclusive suffix sum over lanes
#pragma unroll
      for (int off = 1; off < 64; off <<= 1) {
        int y = __shfl_down(suf, off, 64);
        if (lane + off < 64) suf += y;
      }
      int above = suf - sl;              // total count in higher bins
      if (above < k && k <= suf) {       // exactly one lane matches
        int bin, nk;
        if (k <= above + m3)                { bin = lane*4+3; nk = k - above; }
        else if (k <= above + m3 + m2)      { bin = lane*4+2; nk = k - above - m3; }
        else if (k <= above + m3 + m2 + m1) { bin = lane*4+1; nk = k - above - m3 - m2; }
        else                                { bin = lane*4+0; nk = k - above - m3 - m2 - m1; }
        sel[0] = bin; sel[1] = nk;
      }
    }
    __syncthreads();
    prefix = (prefix << 8) | (unsigned)sel[0];
    k = sel[1];
    __syncthreads();
  }
  V = prefix;
  MEQ = k;
}

// exclusive block scan via wave shuffle prefix + 1 barrier
__device__ __forceinline__ int tk_scan_excl(int v, int tid, int* wsum) {
  const int lane = tid & 63, wid = tid >> 6;
  int x = v;
#pragma unroll
  for (int off = 1; off < 64; off <<= 1) {
    int y = __shfl_up(x, off, 64);
    if (lane >= off) x += y;
  }
  if (lane == 63) wsum[wid] = x;
  __syncthreads();
  int base = 0;
  for (int w = 0; w < wid; ++w) base += wsum[w];
  return base + x - v;
}

__device__ __forceinline__ void tk_write(const unsigned key[8], unsigned V, int MEQ,
                                         int tid, u16* orow, int* wsum) {
  int ceq = 0;
#pragma unroll
  for (int j = 0; j < 8; ++j) ceq += (key[j] == V) ? 1 : 0;
  int run = tk_scan_excl(ceq, tid, wsum);
  unsigned bits = 0;
#pragma unroll
  for (int j = 0; j < 8; ++j) {
    bool e = (key[j] == V);
    bool s = (key[j] > V) || (e && (run < MEQ));
    if (e) run++;
    if (s) bits |= (1u << j);
  }
  int csel = __popc(bits);
  __syncthreads();                       // wsum reuse guard
  int base = tk_scan_excl(csel, tid, wsum);
#pragma unroll
  for (int j = 0; j < 8; ++j)
    if ((bits >> j) & 1u) orow[base++] = (u16)(tid * 8 + j);
}

// ---------------------------------------------------------------------------
// Split fp32 -> bf16 hi/lo pair. flagcnt (nullable) zeroed by block 0.
// ---------------------------------------------------------------------------
__global__ __launch_bounds__(256) void pack_x(
    const float* __restrict__ x, u16* __restrict__ xh, u16* __restrict__ xl,
    int* __restrict__ flagcnt)
{
  if (flagcnt && blockIdx.x == 0 && threadIdx.x < NB) flagcnt[threadIdx.x] = 0;
  const int i = (blockIdx.x * 256 + threadIdx.x) * 8;
  float4 a = *(const float4*)(x + i);
  float4 b = *(const float4*)(x + i + 4);
  float v[8] = {a.x,a.y,a.z,a.w,b.x,b.y,b.z,b.w};
  u16 h[8], l[8];
#pragma unroll
  for (int j = 0; j < 8; ++j) {
    h[j] = f2bf(v[j]);
    l[j] = f2bf(v[j] - bf2f(h[j]));
  }
  uint4 ph, pl;
  ph.x = h[0] | ((unsigned)h[1] << 16); ph.y = h[2] | ((unsigned)h[3] << 16);
  ph.z = h[4] | ((unsigned)h[5] << 16); ph.w = h[6] | ((unsigned)h[7] << 16);
  pl.x = l[0] | ((unsigned)l[1] << 16); pl.y = l[2] | ((unsigned)l[3] << 16);
  pl.z = l[4] | ((unsigned)l[5] << 16); pl.w = l[6] | ((unsigned)l[7] << 16);
  *(uint4*)(xh + i) = ph;
  *(uint4*)(xl + i) = pl;
}

// ---------------------------------------------------------------------------
// Pack the 4 weight matrices into bf16 hi/lo pairs: wpk[m*2]=hi, [m*2+1]=lo.
// ---------------------------------------------------------------------------
__global__ __launch_bounds__(256) void pack_w(
    const float* __restrict__ W0, const float* __restrict__ W1,
    const float* __restrict__ W2, const float* __restrict__ W3,
    u16* __restrict__ wpk)
{
  const int m = blockIdx.y;
  const float* W = (m == 0) ? W0 : (m == 1) ? W1 : (m == 2) ? W2 : W3;
  const int i = (blockIdx.x * 256 + threadIdx.x) * 8;
  float4 a = *(const float4*)(W + i);
  float4 b = *(const float4*)(W + i + 4);
  float v[8] = {a.x,a.y,a.z,a.w,b.x,b.y,b.z,b.w};
  u16 h[8], l[8];
#pragma unroll
  for (int j = 0; j < 8; ++j) {
    h[j] = f2bf(v[j]);
    l[j] = f2bf(v[j] - bf2f(h[j]));
  }
  uint4 ph, pl;
  ph.x = h[0] | ((unsigned)h[1] << 16); ph.y = h[2] | ((unsigned)h[3] << 16);
  ph.z = h[4] | ((unsigned)h[5] << 16); ph.w = h[6] | ((unsigned)h[7] << 16);
  pl.x = l[0] | ((unsigned)l[1] << 16); pl.y = l[2] | ((unsigned)l[3] << 16);
  pl.z = l[4] | ((unsigned)l[5] << 16); pl.w = l[6] | ((unsigned)l[7] << 16);
  u16* dh = wpk + (size_t)m * 2 * 65536;
  *(uint4*)(dh + i) = ph;
  *(uint4*)(dh + 65536 + i) = pl;
}

// ---------------------------------------------------------------------------
// scores = x @ x^T / 16 via bf16 MFMA, FULL 2x2 split (hh+hl+lh+ll).
// ---------------------------------------------------------------------------
__global__ __launch_bounds__(256) void scores_mfma(
    const u16* __restrict__ xh, const u16* __restrict__ xl,
    float* __restrict__ C)
{
  __shared__ u16 Ah[128 * 40], Al[128 * 40], Bh[128 * 40], Bl[128 * 40];
  const int tid = threadIdx.x;
  const int m0 = blockIdx.x * 128, n0 = blockIdx.y * 128;
  const u16* xhB = xh + (size_t)blockIdx.z * SEQ * EMB;
  const u16* xlB = xl + (size_t)blockIdx.z * SEQ * EMB;
  float* Cb = C + (size_t)blockIdx.z * SEQ * SEQ;
  const int wv = tid >> 6, ln = tid & 63;
  const int quad = ln >> 4, r16 = ln & 15;
  const int wm = (wv & 1) * 64, wn = (wv >> 1) * 64;
  const int srow = tid >> 1, shalf = (tid & 1) * 16;

  f32x4v acc[4][4];
#pragma unroll
  for (int i = 0; i < 4; ++i)
#pragma unroll
    for (int j = 0; j < 4; ++j) acc[i][j] = (f32x4v){0.f, 0.f, 0.f, 0.f};

  for (int k0 = 0; k0 < EMB; k0 += 32) {
    __syncthreads();
    {
      size_t ga = (size_t)(m0 + srow) * EMB + k0 + shalf;
      size_t gb = (size_t)(n0 + srow) * EMB + k0 + shalf;
      uint4 ah0 = *(const uint4*)(xhB + ga), ah1 = *(const uint4*)(xhB + ga + 8);
      uint4 al0 = *(const uint4*)(xlB + ga), al1 = *(const uint4*)(xlB + ga + 8);
      uint4 bh0 = *(const uint4*)(xhB + gb), bh1 = *(const uint4*)(xhB + gb + 8);
      uint4 bl0 = *(const uint4*)(xlB + gb), bl1 = *(const uint4*)(xlB + gb + 8);
      int o = srow * 40 + shalf;
      *(uint4*)&Ah[o] = ah0; *(uint4*)&Ah[o + 8] = ah1;
      *(uint4*)&Al[o] = al0; *(uint4*)&Al[o + 8] = al1;
      *(uint4*)&Bh[o] = bh0; *(uint4*)&Bh[o + 8] = bh1;
      *(uint4*)&Bl[o] = bl0; *(uint4*)&Bl[o + 8] = bl1;
    }
    __syncthreads();
    frag8 fbh[4], fbl[4];
#pragma unroll
    for (int nt = 0; nt < 4; ++nt) {
      int ob = (wn + nt * 16 + r16) * 40 + quad * 8;
      fbh[nt] = *(const frag8*)&Bh[ob];
      fbl[nt] = *(const frag8*)&Bl[ob];
    }
#pragma unroll
    for (int mt = 0; mt < 4; ++mt) {
      int oa = (wm + mt * 16 + r16) * 40 + quad * 8;
      frag8 fah = *(const frag8*)&Ah[oa];
      frag8 fal = *(const frag8*)&Al[oa];
#pragma unroll
      for (int nt = 0; nt < 4; ++nt) {
        acc[mt][nt] = __builtin_amdgcn_mfma_f32_16x16x32_bf16(fah, fbh[nt], acc[mt][nt], 0, 0, 0);
        acc[mt][nt] = __builtin_amdgcn_mfma_f32_16x16x32_bf16(fah, fbl[nt], acc[mt][nt], 0, 0, 0);
        acc[mt][nt] = __builtin_amdgcn_mfma_f32_16x16x32_bf16(fal, fbh[nt], acc[mt][nt], 0, 0, 0);
        acc[mt][nt] = __builtin_amdgcn_mfma_f32_16x16x32_bf16(fal, fbl[nt], acc[mt][nt], 0, 0, 0);
      }
    }
  }
#pragma unroll
  for (int mt = 0; mt < 4; ++mt)
#pragma unroll
    for (int nt = 0; nt < 4; ++nt) {
      int cg = n0 + wn + nt * 16 + r16;
      int rb = m0 + wm + mt * 16 + quad * 4;
#pragma unroll
      for (int r = 0; r < 4; ++r)
        Cb[(size_t)(rb + r) * SEQ + cg] = acc[mt][nt][r] * 0.0625f;
    }
}

// ---------------------------------------------------------------------------
// QKV projection via bf16 MFMA, 3-term split (hh+hl+lh), f16 output.
// ---------------------------------------------------------------------------
__global__ __launch_bounds__(256) void qkv_mfma(
    const u16* __restrict__ xh, const u16* __restrict__ xl,
    const u16* __restrict__ wpk,
    const float* __restrict__ bq, const float* __restrict__ bk,
    const float* __restrict__ bv,
    u16* __restrict__ qo, u16* __restrict__ ko, u16* __restrict__ vo)
{
  const int z = blockIdx.z;
  const u16* Wh = wpk + (size_t)z * 2 * 65536;
  const u16* Wl = Wh + 65536;
  const float* bias = (z == 0) ? bq : (z == 1) ? bk : bv;
  u16* out = (z == 0) ? qo : (z == 1) ? ko : vo;

  __shared__ u16 Ah[128 * 40], Al[128 * 40], Bh[128 * 40], Bl[128 * 40];
  const int tid = threadIdx.x;
  const int m0 = blockIdx.x * 128, n0 = blockIdx.y * 128;
  const int wv = tid >> 6, ln = tid & 63;
  const int quad = ln >> 4, r16 = ln & 15;
  const int wm = (wv & 1) * 64, wn = (wv >> 1) * 64;
  const int srow = tid >> 1, shalf = (tid & 1) * 16;

  f32x4v acc[4][4];
#pragma unroll
  for (int i = 0; i < 4; ++i)
#pragma unroll
    for (int j = 0; j < 4; ++j) acc[i][j] = (f32x4v){0.f, 0.f, 0.f, 0.f};

  for (int k0 = 0; k0 < EMB; k0 += 32) {
    __syncthreads();
    {
      size_t ga = (size_t)(m0 + srow) * EMB + k0 + shalf;
      size_t gb = (size_t)(n0 + srow) * EMB + k0 + shalf;
      uint4 ah0 = *(const uint4*)(xh + ga), ah1 = *(const uint4*)(xh + ga + 8);
      uint4 al0 = *(const uint4*)(xl + ga), al1 = *(const uint4*)(xl + ga + 8);
      uint4 bh0 = *(const uint4*)(Wh + gb), bh1 = *(const uint4*)(Wh + gb + 8);
      uint4 bl0 = *(const uint4*)(Wl + gb), bl1 = *(const uint4*)(Wl + gb + 8);
      int o = srow * 40 + shalf;
      *(uint4*)&Ah[o] = ah0; *(uint4*)&Ah[o + 8] = ah1;
      *(uint4*)&Al[o] = al0; *(uint4*)&Al[o + 8] = al1;
      *(uint4*)&Bh[o] = bh0; *(uint4*)&Bh[o + 8] = bh1;
      *(uint4*)&Bl[o] = bl0; *(uint4*)&Bl[o + 8] = bl1;
    }
    __syncthreads();
    frag8 fbh[4], fbl[4];
#pragma unroll
    for (int nt = 0; nt < 4; ++nt) {
      int ob = (wn + nt * 16 + r16) * 40 + quad * 8;
      fbh[nt] = *(const frag8*)&Bh[ob];
      fbl[nt] = *(const frag8*)&Bl[ob];
    }
#pragma unroll
    for (int mt = 0; mt < 4; ++mt) {
      int oa = (wm + mt * 16 + r16) * 40 + quad * 8;
      frag8 fah = *(const frag8*)&Ah[oa];
      frag8 fal = *(const frag8*)&Al[oa];
#pragma unroll
      for (int nt = 0; nt < 4; ++nt) {
        acc[mt][nt] = __builtin_amdgcn_mfma_f32_16x16x32_bf16(fah, fbh[nt], acc[mt][nt], 0, 0, 0);
        acc[mt][nt] = __builtin_amdgcn_mfma_f32_16x16x32_bf16(fah, fbl[nt], acc[mt][nt], 0, 0, 0);
        acc[mt][nt] = __builtin_amdgcn_mfma_f32_16x16x32_bf16(fal, fbh[nt], acc[mt][nt], 0, 0, 0);
      }
    }
  }
#pragma unroll
  for (int nt = 0; nt < 4; ++nt) {
    int cg = n0 + wn + nt * 16 + r16;
    float bvv = bias[cg];
#pragma unroll
    for (int mt = 0; mt < 4; ++mt) {
      int rb = m0 + wm + mt * 16 + quad * 4;
#pragma unroll
      for (int r = 0; r < 4; ++r) {
        HU hu; hu.h = (f16)(acc[mt][nt][r] + bvv);
        out[(size_t)(rb + r) * EMB + cg] = hu.u;
      }
    }
  }
}

// ---------------------------------------------------------------------------
// Out projection via bf16 MFMA, 3-term split, fp32 output + bias.
// ---------------------------------------------------------------------------
__global__ __launch_bounds__(256) void out_mfma(
    const u16* __restrict__ ch, const u16* __restrict__ cl,
    const u16* __restrict__ wpk, const float* __restrict__ bias,
    float* __restrict__ out)
{
  const u16* Wh = wpk + (size_t)3 * 2 * 65536;
  const u16* Wl = Wh + 65536;
  __shared__ u16 Ah[128 * 40], Al[128 * 40], Bh[128 * 40], Bl[128 * 40];
  const int tid = threadIdx.x;
  const int m0 = blockIdx.x * 128, n0 = blockIdx.y * 128;
  const int wv = tid >> 6, ln = tid & 63;
  const int quad = ln >> 4, r16 = ln & 15;
  const int wm = (wv & 1) * 64, wn = (wv >> 1) * 64;
  const int srow = tid >> 1, shalf = (tid & 1) * 16;

  f32x4v acc[4][4];
#pragma unroll
  for (int i = 0; i < 4; ++i)
#pragma unroll
    for (int j = 0; j < 4; ++j) acc[i][j] = (f32x4v){0.f, 0.f, 0.f, 0.f};

  for (int k0 = 0; k0 < EMB; k0 += 32) {
    __syncthreads();
    {
      size_t ga = (size_t)(m0 + srow) * EMB + k0 + shalf;
      size_t gb = (size_t)(n0 + srow) * EMB + k0 + shalf;
      uint4 ah0 = *(const uint4*)(ch + ga), ah1 = *(const uint4*)(ch + ga + 8);
      uint4 al0 = *(const uint4*)(cl + ga), al1 = *(const uint4*)(cl + ga + 8);
      uint4 bh0 = *(const uint4*)(Wh + gb), bh1 = *(const uint4*)(Wh + gb + 8);
      uint4 bl0 = *(const uint4*)(Wl + gb), bl1 = *(const uint4*)(Wl + gb + 8);
      int o = srow * 40 + shalf;
      *(uint4*)&Ah[o] = ah0; *(uint4*)&Ah[o + 8] = ah1;
      *(uint4*)&Al[o] = al0; *(uint4*)&Al[o + 8] = al1;
      *(uint4*)&Bh[o] = bh0; *(uint4*)&Bh[o + 8] = bh1;
      *(uint4*)&Bl[o] = bl0; *(uint4*)&Bl[o + 8] = bl1;
    }
    __syncthreads();
    frag8 fbh[4], fbl[4];
#pragma unroll
    for (int nt = 0; nt < 4; ++nt) {
      int ob = (wn + nt * 16 + r16) * 40 + quad * 8;
      fbh[nt] = *(const frag8*)&Bh[ob];
      fbl[nt] = *(const frag8*)&Bl[ob];
    }
#pragma unroll
    for (int mt = 0; mt < 4; ++mt) {
      int oa = (wm + mt * 16 + r16) * 40 + quad * 8;
      frag8 fah = *(const frag8*)&Ah[oa];
      frag8 fal = *(const frag8*)&Al[oa];
#pragma unroll
      for (int nt = 0; nt < 4; ++nt) {
        acc[mt][nt] = __builtin_amdgcn_mfma_f32_16x16x32_bf16(fah, fbh[nt], acc[mt][nt], 0, 0, 0);
        acc[mt][nt] = __builtin_amdgcn_mfma_f32_16x16x32_bf16(fah, fbl[nt], acc[mt][nt], 0, 0, 0);
        acc[mt][nt] = __builtin_amdgcn_mfma_f32_16x16x32_bf16(fal, fbh[nt], acc[mt][nt], 0, 0, 0);
      }
    }
  }
#pragma unroll
  for (int nt = 0; nt < 4; ++nt) {
    int cg = n0 + wn + nt * 16 + r16;
    float bvv = bias[cg];
#pragma unroll
    for (int mt = 0; mt < 4; ++mt) {
      int rb = m0 + wm + mt * 16 + quad * 4;
#pragma unroll
      for (int r = 0; r < 4; ++r)
        out[(size_t)(rb + r) * EMB + cg] = acc[mt][nt][r] + bvv;
    }
  }
}

// ---------------------------------------------------------------------------
// Top-k per row (radix-256), with margin flagging into per-batch lists.
// ---------------------------------------------------------------------------
__global__ __launch_bounds__(256) void topk_idx(
    const float* __restrict__ scores, u16* __restrict__ idxl,
    int* __restrict__ flagcnt, int* __restrict__ flaglist)
{
  __shared__ int hist[4][256];
  __shared__ int sel[2];
  __shared__ int wsum[4];
  __shared__ unsigned wmax[4];
  const int r = blockIdx.x;
  const int tid = threadIdx.x;
  const int lane = tid & 63, wid = tid >> 6;
  const float* row = scores + (size_t)r * SEQ;
  unsigned key[8];
  {
    float4 f0 = *(const float4*)(row + tid * 8);
    float4 f1 = *(const float4*)(row + tid * 8 + 4);
    key[0]=f2ord(f0.x); key[1]=f2ord(f0.y); key[2]=f2ord(f0.z); key[3]=f2ord(f0.w);
    key[4]=f2ord(f1.x); key[5]=f2ord(f1.y); key[6]=f2ord(f1.z); key[7]=f2ord(f1.w);
  }
  unsigned V; int MEQ;
  tk_radix(key, tid, hist, sel, V, MEQ);

  // EQ count + margin (next value below V), then flag decision
  {
    int ceq = 0; unsigned mk = 0;
#pragma unroll
    for (int j = 0; j < 8; ++j) {
      ceq += (key[j] == V) ? 1 : 0;
      if (key[j] < V && key[j] > mk) mk = key[j];
    }
#pragma unroll
    for (int off = 32; off > 0; off >>= 1) {
      ceq += __shfl_down(ceq, off, 64);
      unsigned o = (unsigned)__shfl_down((int)mk, off, 64);
      if (o > mk) mk = o;
    }
    if (lane == 0) { wsum[wid] = ceq; wmax[wid] = mk; }
    __syncthreads();
    if (tid == 0) {
      int EQ = wsum[0] + wsum[1] + wsum[2] + wsum[3];
      unsigned m2 = wmax[0];
      for (int w = 1; w < 4; ++w) if (wmax[w] > m2) m2 = wmax[w];
      bool flag = (EQ > MEQ) || !(ord2f(V) - ord2f(m2) >= MBOUND);
      if (flag) {
        int bb = r >> 11;
        int p = atomicAdd(&flagcnt[bb], 1);
        flaglist[bb * SEQ + p] = r & (SEQ - 1);
      }
    }
    __syncthreads();   // wsum reuse in tk_write
  }

  tk_write(key, V, MEQ, tid, idxl + (size_t)r * IDXP, wsum);
}

// ---------------------------------------------------------------------------
// Fixup A: exact fp32 scores for flagged rows (gathered-A 64x64 GEMM).
// ---------------------------------------------------------------------------
__global__ __launch_bounds__(256) void fixup_gemm(
    const float* __restrict__ x, const int* __restrict__ flagcnt,
    const int* __restrict__ flaglist, float* __restrict__ attn)
{
  const int b = blockIdx.z;
  const int n = flagcnt[b];
  const int g0 = blockIdx.y * 64;
  if (g0 >= n) return;
  __shared__ float As[16][68];
  __shared__ float Bs[16][68];
  __shared__ int rowsh[64];
  const int tid = threadIdx.x;
  const int n0 = blockIdx.x * 64;
  if (tid < 64) {
    int gi = g0 + tid;
    rowsh[tid] = (gi < n) ? flaglist[b * SEQ + gi] : -1;
  }
  __syncthreads();
  const float* xb = x + (size_t)b * SEQ * EMB;
  const int lm = tid >> 2;
  const int lk = (tid & 3) << 2;
  const int mt = tid >> 4;
  const int nt = tid & 15;
  const int arow = rowsh[lm];
  const int arowL = (arow < 0) ? 0 : arow;
  float acc[4][4] = {{0.f}};
  for (int k0 = 0; k0 < EMB; k0 += 16) {
    float4 av = *(const float4*)(xb + (size_t)arowL * EMB + k0 + lk);
    float4 bv = *(const float4*)(xb + (size_t)(n0 + lm) * EMB + k0 + lk);
    __syncthreads();
    As[lk+0][lm] = av.x; As[lk+1][lm] = av.y; As[lk+2][lm] = av.z; As[lk+3][lm] = av.w;
    Bs[lk+0][lm] = bv.x; Bs[lk+1][lm] = bv.y; Bs[lk+2][lm] = bv.z; Bs[lk+3][lm] = bv.w;
    __syncthreads();
#pragma unroll
    for (int kk = 0; kk < 16; ++kk) {
      float4 a4 = *(const float4*)&As[kk][mt << 2];
      float4 b4 = *(const float4*)&Bs[kk][nt << 2];
      acc[0][0] += a4.x*b4.x; acc[0][1] += a4.x*b4.y; acc[0][2] += a4.x*b4.z; acc[0][3] += a4.x*b4.w;
      acc[1][0] += a4.y*b4.x; acc[1][1] += a4.y*b4.y; acc[1][2] += a4.y*b4.z; acc[1][3] += a4.y*b4.w;
      acc[2][0] += a4.z*b4.x; acc[2][1] += a4.z*b4.y; acc[2][2] += a4.z*b4.z; acc[2][3] += a4.z*b4.w;
      acc[3][0] += a4.w*b4.x; acc[3][1] += a4.w*b4.y; acc[3][2] += a4.w*b4.z; acc[3][3] += a4.w*b4.w;
    }
  }
  float* attnB = attn + (size_t)b * SEQ * SEQ;
#pragma unroll
  for (int r = 0; r < 4; ++r) {
    int rr = rowsh[(mt << 2) + r];
    if (rr >= 0) {
      float4 o;
      o.x = acc[r][0] * 0.0625f; o.y = acc[r][1] * 0.0625f;
      o.z = acc[r][2] * 0.0625f; o.w = acc[r][3] * 0.0625f;
      *(float4*)(attnB + (size_t)rr * SEQ + n0 + (nt << 2)) = o;
    }
  }
}

// ---------------------------------------------------------------------------
// Fixup B: redo top-k (radix) on the now-exact flagged rows.
// ---------------------------------------------------------------------------
__global__ __launch_bounds__(256) void topk_fixup(
    const float* __restrict__ attn, const int* __restrict__ flagcnt,
    const int* __restrict__ flaglist, u16* __restrict__ idxl)
{
  const int b = blockIdx.y;
  if ((int)blockIdx.x >= flagcnt[b]) return;
  const int r = b * SEQ + flaglist[b * SEQ + blockIdx.x];
  __shared__ int hist[4][256];
  __shared__ int sel[2];
  __shared__ int wsum[4];
  const int tid = threadIdx.x;
  const float* row = attn + (size_t)r * SEQ;
  unsigned key[8];
  {
    float4 f0 = *(const float4*)(row + tid * 8);
    float4 f1 = *(const float4*)(row + tid * 8 + 4);
    key[0]=f2ord(f0.x); key[1]=f2ord(f0.y); key[2]=f2ord(f0.z); key[3]=f2ord(f0.w);
    key[4]=f2ord(f1.x); key[5]=f2ord(f1.y); key[6]=f2ord(f1.z); key[7]=f2ord(f1.w);
  }
  unsigned V; int MEQ;
  tk_radix(key, tid, hist, sel, V, MEQ);
  tk_write(key, V, MEQ, tid, idxl + (size_t)r * IDXP, wsum);
}

// ---------------------------------------------------------------------------
// Sparse attention v5: f16 Q/K/V, fdot2 dots, 16B/lane 2-keys-per-wave-load,
// 32-bit byte offsets, LDS-dense attn row, XCD batch swizzle.
// ---------------------------------------------------------------------------
__global__ __launch_bounds__(256) void sparse_attn(
    const u16* __restrict__ qf, const u16* __restrict__ kf,
    const u16* __restrict__ vf, const u16* __restrict__ idxl,
    float* __restrict__ attn, float* __restrict__ ctxb)
{
  const int lin = blockIdx.x;
  const int b = lin & 3;                                  // XCD-stable batch
  const int q = (lin >> 3) + (((lin >> 2) & 1) << 10);
  const int tid = threadIdx.x;
  const int wv = tid >> 6, ln = tid & 63;
  const int half = ln >> 5, sl = ln & 31;
  const int h = sl >> 2, d0 = sl * 8;
  const int lb = sl * 16;
  __shared__ int   ish[IDXP];
  __shared__ int   koff[IDXP];
  __shared__ float psh[IDXP * 9 + 4];   // [j][h], stride 9
  __shared__ float idsh[NH];
  __shared__ float csh[8][264];
  __shared__ float rsh[SEQ];

  const int row = b * SEQ + q;
  if (tid < KTOP) {
    int idx = (int)idxl[(size_t)row * IDXP + tid];
    ish[tid] = idx;
    koff[tid] = idx << 9;
  } else if (tid < IDXP) {
    ish[tid] = 0; koff[tid] = 0;
  }
  if (tid < 32) psh[(KTOP + (tid >> 3)) * 9 + (tid & 7)] = 0.f;

  float4 z4 = make_float4(0.f, 0.f, 0.f, 0.f);
  *(float4*)&rsh[tid * 4]        = z4;
  *(float4*)&rsh[1024 + tid * 4] = z4;

  U4 qv;
  qv.u = *(const uint4*)((const char*)(qf + (size_t)row * EMB) + lb);

  __syncthreads();

  const float scale = 0.17677669529663687f;  // 1/sqrt(32)
  const char* kbC = (const char*)(kf + (size_t)(b * SEQ) * EMB);
  const int jb = wv * KPW;
#pragma unroll 4
  for (int t = 0; t < KPW; t += 2) {
    const int j = jb + t + half;
    U4 kv;
    kv.u = *(const uint4*)(kbC + (koff[j] + lb));
    float s = FDOT2(qv.h[0], kv.h[0],
              FDOT2(qv.h[1], kv.h[1],
              FDOT2(qv.h[2], kv.h[2],
              FDOT2(qv.h[3], kv.h[3], 0.f))));
    s += __shfl_xor(s, 1, 64);
    s += __shfl_xor(s, 2, 64);
    if ((sl & 3) == 0 && j < KTOP) psh[j * 9 + h] = __expf(s * scale);
  }
  __syncthreads();

  {
    int h2 = tid >> 5, l = tid & 31;
    float sden = 0.f;
    for (int j = l; j < KTOP; j += 32) sden += psh[j * 9 + h2];
#pragma unroll
    for (int off = 16; off > 0; off >>= 1) sden += __shfl_down(sden, off, 32);
    if (l == 0) idsh[h2] = 1.0f / sden;
  }
  __syncthreads();

  if (tid < KTOP) {
    float ps = 0.f;
#pragma unroll
    for (int hh = 0; hh < 8; ++hh) {
      float pp = psh[tid * 9 + hh] * idsh[hh];
      psh[tid * 9 + hh] = pp;
      ps += pp;
    }
    rsh[ish[tid]] = ps * 0.125f;
  }
  __syncthreads();

  {
    float* arow = attn + (size_t)row * SEQ;
    *(float4*)(arow + tid * 4)        = *(const float4*)&rsh[tid * 4];
    *(float4*)(arow + 1024 + tid * 4) = *(const float4*)&rsh[1024 + tid * 4];
  }

  {
    const char* vbC = (const char*)(vf + (size_t)(b * SEQ) * EMB);
    float a8[8] = {0.f,0.f,0.f,0.f,0.f,0.f,0.f,0.f};
#pragma unroll 4
    for (int t = 0; t < KPW; t += 2) {
      const int j = jb + t + half;
      float p = psh[j * 9 + h];
      U4 vv;
      vv.u = *(const uint4*)(vbC + (koff[j] + lb));
      a8[0] += p * (float)vv.h[0][0]; a8[1] += p * (float)vv.h[0][1];
      a8[2] += p * (float)vv.h[1][0]; a8[3] += p * (float)vv.h[1][1];
      a8[4] += p * (float)vv.h[2][0]; a8[5] += p * (float)vv.h[2][1];
      a8[6] += p * (float)vv.h[3][0]; a8[7] += p * (float)vv.h[3][1];
    }
    const int pi = wv * 2 + half;
    *(float4*)&csh[pi][d0]     = make_float4(a8[0], a8[1], a8[2], a8[3]);
    *(float4*)&csh[pi][d0 + 4] = make_float4(a8[4], a8[5], a8[6], a8[7]);
  }
  __syncthreads();
  if (tid < 64) {
    float4 o = z4;
#pragma unroll
    for (int g = 0; g < 8; ++g) {
      float4 v = *(const float4*)&csh[g][tid * 4];
      o.x += v.x; o.y += v.y; o.z += v.z; o.w += v.w;
    }
    *(float4*)(ctxb + (size_t)row * EMB + tid * 4) = o;
  }
}

// ---------------------------------------------------------------------------
extern "C" void kernel_launch(void* const* d_in, const int* in_sizes, int n_in,
                              void* d_out, int out_size, void* d_ws, size_t ws_size,
                              hipStream_t stream)
{
  const float* x  = (const float*)d_in[0];
  const float* Wq = (const float*)d_in[1];
  const float* bq = (const float*)d_in[2];
  const float* Wk = (const float*)d_in[3];
  const float* bk = (const float*)d_in[4];
  const float* Wv = (const float*)d_in[5];
  const float* bv = (const float*)d_in[6];
  const float* Wo = (const float*)d_in[7];
  const float* bo = (const float*)d_in[8];

  float* out  = (float*)d_out;
  float* attn = out + (size_t)NB * SEQ * EMB;   // [B,S,S] region of d_out

  const size_t NSE = (size_t)NB * SEQ * EMB;    // 2097152
  u16* xh  = (u16*)d_ws;            // bf16 hi of x (later: hi of ctx)
  u16* xl  = xh + NSE;              // bf16 lo
  u16* qf  = xl + NSE;              // f16 Q
  u16* kf  = qf + NSE;              // f16 K
  u16* vf  = kf + NSE;              // f16 V
  u16* wpk = vf + NSE;              // 4 x (hi,lo) 256x256 bf16
  float* ctxb = (float*)(wpk + 4 * 2 * 65536);
  u16* idxl = (u16*)(ctxb + NSE);
  int* flagcnt  = (int*)(idxl + (size_t)NB * SEQ * IDXP);
  int* flaglist = flagcnt + NB;

  const dim3 blk(256);

  // bf16 hi/lo splits (x + the 4 weight matrices); flag counters reset
  pack_x<<<dim3(1024), blk, 0, stream>>>(x, xh, xl, flagcnt);
  pack_w<<<dim3(32, 4), blk, 0, stream>>>(Wq, Wk, Wv, Wo, wpk);

  // Q/K/V projections via MFMA (3-term), f16 outputs
  qkv_mfma<<<dim3(64, 2, 3), blk, 0, stream>>>(xh, xl, wpk, bq, bk, bv, qf, kf, vf);

  // scores = x @ x^T / 16 via full split-bf16 MFMA (4-term)
  scores_mfma<<<dim3(16, 16, NB), blk, 0, stream>>>(xh, xl, attn);

  // radix top-k with margin flagging; exact fp32 fixup of low-margin rows
  topk_idx<<<dim3(NB * SEQ), blk, 0, stream>>>(attn, idxl, flagcnt, flaglist);
  fixup_gemm<<<dim3(32, 32, NB), blk, 0, stream>>>(x, flagcnt, flaglist, attn);
  topk_fixup<<<dim3(SEQ, NB), blk, 0, stream>>>(attn, flagcnt, flaglist, idxl);

  // fused sparse attention (f16 gathers + fdot2)
  sparse_attn<<<dim3(SEQ * NB), blk, 0, stream>>>(qf, kf, vf, idxl, attn, ctxb);

  // out = ctx @ Wo^T + bo via MFMA (pack ctx into xh/xl, now free)
  pack_x<<<dim3(1024), blk, 0, stream>>>(ctxb, xh, xl, nullptr);
  out_mfma<<<dim3(64, 2), blk, 0, stream>>>(xh, xl, wpk, bo, out);
}

// Round 10
// 323.297 us; speedup vs baseline: 1.6108x; 1.0752x over previous
//
#include <hip/hip_runtime.h>

#define SEQ  2048
#define EMB  256
#define NH   8
#define HD   32
#define NB   4
#define KTOP 204
#define IDXP 208
#define KPW  52       // keys per wave (4*52 = 208, padded)
#define MBOUND 4e-4f  // top-k margin for fp32 re-verify

typedef unsigned long long ull;
typedef unsigned short u16;

using frag8  = __attribute__((ext_vector_type(8))) short;  // 8 bf16
using f32x4v = __attribute__((ext_vector_type(4))) float;
typedef _Float16 f16;
typedef _Float16 f16x2 __attribute__((ext_vector_type(2)));

union U4 { uint4 u; f16x2 h[4]; };
union HU { f16 h; u16 u; };

#if defined(__has_builtin)
#if __has_builtin(__builtin_amdgcn_fdot2)
#define FDOT2(a,b,c) __builtin_amdgcn_fdot2(a, b, c, false)
#endif
#endif
#ifndef FDOT2
__device__ __forceinline__ float fdot2_sw(f16x2 a, f16x2 b, float c) {
  return c + (float)a[0]*(float)b[0] + (float)a[1]*(float)b[1];
}
#define FDOT2(a,b,c) fdot2_sw(a,b,c)
#endif

__device__ __forceinline__ unsigned f2ord(float f) {
  unsigned u = __float_as_uint(f);
  return (u & 0x80000000u) ? ~u : (u | 0x80000000u);
}
__device__ __forceinline__ float ord2f(unsigned o) {
  unsigned u = (o & 0x80000000u) ? (o ^ 0x80000000u) : ~o;
  return __uint_as_float(u);
}
__device__ __forceinline__ u16 f2bf(float f) {
  unsigned u = __float_as_uint(f);
  u += 0x7FFF + ((u >> 16) & 1);     // RTNE
  return (u16)(u >> 16);
}
__device__ __forceinline__ float bf2f(u16 h) {
  return __uint_as_float((unsigned)h << 16);
}

// ---------------------------------------------------------------------------
// Radix-256 top-k (4 byte passes, per-wave histograms, wave-0 suffix scan).
// ---------------------------------------------------------------------------
__device__ __forceinline__ void tk_radix(
    const unsigned key[8], int tid, int (*hist)[256], int* sel,
    unsigned& V, int& MEQ)
{
  const int lane = tid & 63, wid = tid >> 6;
  unsigned prefix = 0;
  int k = KTOP;
#pragma unroll
  for (int p = 0; p < 4; ++p) {
    const int shift = 24 - 8 * p;
    hist[0][tid] = 0; hist[1][tid] = 0; hist[2][tid] = 0; hist[3][tid] = 0;
    __syncthreads();
#pragma unroll
    for (int j = 0; j < 8; ++j) {
      unsigned kj = key[j];
      bool ok = (p == 0) || ((kj >> (shift + 8)) == prefix);
      if (ok) atomicAdd(&hist[wid][(kj >> shift) & 255], 1);
    }
    __syncthreads();
    {
      int c = hist[0][tid] + hist[1][tid] + hist[2][tid] + hist[3][tid];
      hist[0][tid] = c;
    }
    __syncthreads();
    if (wid == 0) {
      int m0 = hist[0][lane * 4 + 0], m1 = hist[0][lane * 4 + 1];
      int m2 = hist[0][lane * 4 + 2], m3 = hist[0][lane * 4 + 3];
      int sl = m0 + m1 + m2 + m3;
      int suf = sl;
#pragma unroll
      for (int off = 1; off < 64; off <<= 1) {
        int y = __shfl_down(suf, off, 64);
        if (lane + off < 64) suf += y;
      }
      int above = suf - sl;
      if (above < k && k <= suf) {
        int bin, nk;
        if (k <= above + m3)                { bin = lane*4+3; nk = k - above; }
        else if (k <= above + m3 + m2)      { bin = lane*4+2; nk = k - above - m3; }
        else if (k <= above + m3 + m2 + m1) { bin = lane*4+1; nk = k - above - m3 - m2; }
        else                                { bin = lane*4+0; nk = k - above - m3 - m2 - m1; }
        sel[0] = bin; sel[1] = nk;
      }
    }
    __syncthreads();
    prefix = (prefix << 8) | (unsigned)sel[0];
    k = sel[1];
    __syncthreads();
  }
  V = prefix;
  MEQ = k;
}

__device__ __forceinline__ int tk_scan_excl(int v, int tid, int* wsum) {
  const int lane = tid & 63, wid = tid >> 6;
  int x = v;
#pragma unroll
  for (int off = 1; off < 64; off <<= 1) {
    int y = __shfl_up(x, off, 64);
    if (lane >= off) x += y;
  }
  if (lane == 63) wsum[wid] = x;
  __syncthreads();
  int base = 0;
  for (int w = 0; w < wid; ++w) base += wsum[w];
  return base + x - v;
}

__device__ __forceinline__ void tk_write(const unsigned key[8], unsigned V, int MEQ,
                                         int tid, u16* orow, int* wsum) {
  int ceq = 0;
#pragma unroll
  for (int j = 0; j < 8; ++j) ceq += (key[j] == V) ? 1 : 0;
  int run = tk_scan_excl(ceq, tid, wsum);
  unsigned bits = 0;
#pragma unroll
  for (int j = 0; j < 8; ++j) {
    bool e = (key[j] == V);
    bool s = (key[j] > V) || (e && (run < MEQ));
    if (e) run++;
    if (s) bits |= (1u << j);
  }
  int csel = __popc(bits);
  __syncthreads();
  int base = tk_scan_excl(csel, tid, wsum);
#pragma unroll
  for (int j = 0; j < 8; ++j)
    if ((bits >> j) & 1u) orow[base++] = (u16)(tid * 8 + j);
}

// ---------------------------------------------------------------------------
// pack_all: bf16 hi/lo split of x (blocks 0..1023) and the 4 weight matrices
// (blocks 1024..1151); block 0 also zeroes the per-batch flag counters.
// ---------------------------------------------------------------------------
__global__ __launch_bounds__(256) void pack_all(
    const float* __restrict__ x,
    const float* __restrict__ W0, const float* __restrict__ W1,
    const float* __restrict__ W2, const float* __restrict__ W3,
    u16* __restrict__ xh, u16* __restrict__ xl, u16* __restrict__ wpk,
    int* __restrict__ flagcnt)
{
  const int lin = blockIdx.x;
  if (lin == 0 && threadIdx.x < NB) flagcnt[threadIdx.x] = 0;
  const float* src; u16 *dh, *dl; int i;
  if (lin < 1024) {
    src = x;
    i = (lin * 256 + threadIdx.x) * 8;
    dh = xh; dl = xl;
  } else {
    int j = lin - 1024;             // 0..127
    int m = j >> 5, bx = j & 31;
    src = (m == 0) ? W0 : (m == 1) ? W1 : (m == 2) ? W2 : W3;
    i = (bx * 256 + threadIdx.x) * 8;
    dh = wpk + (size_t)m * 2 * 65536;
    dl = dh + 65536;
  }
  float4 a = *(const float4*)(src + i);
  float4 b = *(const float4*)(src + i + 4);
  float v[8] = {a.x,a.y,a.z,a.w,b.x,b.y,b.z,b.w};
  u16 h[8], l[8];
#pragma unroll
  for (int j = 0; j < 8; ++j) {
    h[j] = f2bf(v[j]);
    l[j] = f2bf(v[j] - bf2f(h[j]));
  }
  uint4 ph, pl;
  ph.x = h[0] | ((unsigned)h[1] << 16); ph.y = h[2] | ((unsigned)h[3] << 16);
  ph.z = h[4] | ((unsigned)h[5] << 16); ph.w = h[6] | ((unsigned)h[7] << 16);
  pl.x = l[0] | ((unsigned)l[1] << 16); pl.y = l[2] | ((unsigned)l[3] << 16);
  pl.z = l[4] | ((unsigned)l[5] << 16); pl.w = l[6] | ((unsigned)l[7] << 16);
  *(uint4*)(dh + i) = ph;
  *(uint4*)(dl + i) = pl;
}

// ---------------------------------------------------------------------------
// fused_gemms: one launch for scores (blocks 0..1023, 4-term split, fp32 out)
// and QKV projections (blocks 1024..1407, 3-term split, f16 out).
// ---------------------------------------------------------------------------
__global__ __launch_bounds__(256) void fused_gemms(
    const u16* __restrict__ xh, const u16* __restrict__ xl,
    const u16* __restrict__ wpk,
    const float* __restrict__ bq, const float* __restrict__ bk,
    const float* __restrict__ bv,
    u16* __restrict__ qo, u16* __restrict__ ko, u16* __restrict__ vo,
    float* __restrict__ attnC)
{
  __shared__ u16 Ah[128 * 40], Al[128 * 40], Bh[128 * 40], Bl[128 * 40];
  const int lin = blockIdx.x;
  const int tid = threadIdx.x;
  const int wv = tid >> 6, ln = tid & 63;
  const int quad = ln >> 4, r16 = ln & 15;
  const int wm = (wv & 1) * 64, wn = (wv >> 1) * 64;
  const int srow = tid >> 1, shalf = (tid & 1) * 16;

  f32x4v acc[4][4];
#pragma unroll
  for (int i = 0; i < 4; ++i)
#pragma unroll
    for (int j = 0; j < 4; ++j) acc[i][j] = (f32x4v){0.f, 0.f, 0.f, 0.f};

  if (lin < 1024) {
    // ----- scores path -----
    const int m0 = (lin & 15) * 128, n0 = ((lin >> 4) & 15) * 128;
    const int b = lin >> 8;
    const u16* xhB = xh + (size_t)b * SEQ * EMB;
    const u16* xlB = xl + (size_t)b * SEQ * EMB;
    float* Cb = attnC + (size_t)b * SEQ * SEQ;
    for (int k0 = 0; k0 < EMB; k0 += 32) {
      __syncthreads();
      {
        size_t ga = (size_t)(m0 + srow) * EMB + k0 + shalf;
        size_t gb = (size_t)(n0 + srow) * EMB + k0 + shalf;
        uint4 ah0 = *(const uint4*)(xhB + ga), ah1 = *(const uint4*)(xhB + ga + 8);
        uint4 al0 = *(const uint4*)(xlB + ga), al1 = *(const uint4*)(xlB + ga + 8);
        uint4 bh0 = *(const uint4*)(xhB + gb), bh1 = *(const uint4*)(xhB + gb + 8);
        uint4 bl0 = *(const uint4*)(xlB + gb), bl1 = *(const uint4*)(xlB + gb + 8);
        int o = srow * 40 + shalf;
        *(uint4*)&Ah[o] = ah0; *(uint4*)&Ah[o + 8] = ah1;
        *(uint4*)&Al[o] = al0; *(uint4*)&Al[o + 8] = al1;
        *(uint4*)&Bh[o] = bh0; *(uint4*)&Bh[o + 8] = bh1;
        *(uint4*)&Bl[o] = bl0; *(uint4*)&Bl[o + 8] = bl1;
      }
      __syncthreads();
      frag8 fbh[4], fbl[4];
#pragma unroll
      for (int nt = 0; nt < 4; ++nt) {
        int ob = (wn + nt * 16 + r16) * 40 + quad * 8;
        fbh[nt] = *(const frag8*)&Bh[ob];
        fbl[nt] = *(const frag8*)&Bl[ob];
      }
#pragma unroll
      for (int mt = 0; mt < 4; ++mt) {
        int oa = (wm + mt * 16 + r16) * 40 + quad * 8;
        frag8 fah = *(const frag8*)&Ah[oa];
        frag8 fal = *(const frag8*)&Al[oa];
#pragma unroll
        for (int nt = 0; nt < 4; ++nt) {
          acc[mt][nt] = __builtin_amdgcn_mfma_f32_16x16x32_bf16(fah, fbh[nt], acc[mt][nt], 0, 0, 0);
          acc[mt][nt] = __builtin_amdgcn_mfma_f32_16x16x32_bf16(fah, fbl[nt], acc[mt][nt], 0, 0, 0);
          acc[mt][nt] = __builtin_amdgcn_mfma_f32_16x16x32_bf16(fal, fbh[nt], acc[mt][nt], 0, 0, 0);
          acc[mt][nt] = __builtin_amdgcn_mfma_f32_16x16x32_bf16(fal, fbl[nt], acc[mt][nt], 0, 0, 0);
        }
      }
    }
#pragma unroll
    for (int mt = 0; mt < 4; ++mt)
#pragma unroll
      for (int nt = 0; nt < 4; ++nt) {
        int cg = n0 + wn + nt * 16 + r16;
        int rb = m0 + wm + mt * 16 + quad * 4;
#pragma unroll
        for (int r = 0; r < 4; ++r)
          Cb[(size_t)(rb + r) * SEQ + cg] = acc[mt][nt][r] * 0.0625f;
      }
  } else {
    // ----- qkv path -----
    const int j = lin - 1024;
    const int m0 = (j & 63) * 128, n0 = ((j >> 6) & 1) * 128;
    const int z = j >> 7;
    const u16* Wh = wpk + (size_t)z * 2 * 65536;
    const u16* Wl = Wh + 65536;
    const float* bias = (z == 0) ? bq : (z == 1) ? bk : bv;
    u16* out = (z == 0) ? qo : (z == 1) ? ko : vo;
    for (int k0 = 0; k0 < EMB; k0 += 32) {
      __syncthreads();
      {
        size_t ga = (size_t)(m0 + srow) * EMB + k0 + shalf;
        size_t gb = (size_t)(n0 + srow) * EMB + k0 + shalf;
        uint4 ah0 = *(const uint4*)(xh + ga), ah1 = *(const uint4*)(xh + ga + 8);
        uint4 al0 = *(const uint4*)(xl + ga), al1 = *(const uint4*)(xl + ga + 8);
        uint4 bh0 = *(const uint4*)(Wh + gb), bh1 = *(const uint4*)(Wh + gb + 8);
        uint4 bl0 = *(const uint4*)(Wl + gb), bl1 = *(const uint4*)(Wl + gb + 8);
        int o = srow * 40 + shalf;
        *(uint4*)&Ah[o] = ah0; *(uint4*)&Ah[o + 8] = ah1;
        *(uint4*)&Al[o] = al0; *(uint4*)&Al[o + 8] = al1;
        *(uint4*)&Bh[o] = bh0; *(uint4*)&Bh[o + 8] = bh1;
        *(uint4*)&Bl[o] = bl0; *(uint4*)&Bl[o + 8] = bl1;
      }
      __syncthreads();
      frag8 fbh[4], fbl[4];
#pragma unroll
      for (int nt = 0; nt < 4; ++nt) {
        int ob = (wn + nt * 16 + r16) * 40 + quad * 8;
        fbh[nt] = *(const frag8*)&Bh[ob];
        fbl[nt] = *(const frag8*)&Bl[ob];
      }
#pragma unroll
      for (int mt = 0; mt < 4; ++mt) {
        int oa = (wm + mt * 16 + r16) * 40 + quad * 8;
        frag8 fah = *(const frag8*)&Ah[oa];
        frag8 fal = *(const frag8*)&Al[oa];
#pragma unroll
        for (int nt = 0; nt < 4; ++nt) {
          acc[mt][nt] = __builtin_amdgcn_mfma_f32_16x16x32_bf16(fah, fbh[nt], acc[mt][nt], 0, 0, 0);
          acc[mt][nt] = __builtin_amdgcn_mfma_f32_16x16x32_bf16(fah, fbl[nt], acc[mt][nt], 0, 0, 0);
          acc[mt][nt] = __builtin_amdgcn_mfma_f32_16x16x32_bf16(fal, fbh[nt], acc[mt][nt], 0, 0, 0);
        }
      }
    }
#pragma unroll
    for (int nt = 0; nt < 4; ++nt) {
      int cg = n0 + wn + nt * 16 + r16;
      float bvv = bias[cg];
#pragma unroll
      for (int mt = 0; mt < 4; ++mt) {
        int rb = m0 + wm + mt * 16 + quad * 4;
#pragma unroll
        for (int r = 0; r < 4; ++r) {
          HU hu; hu.h = (f16)(acc[mt][nt][r] + bvv);
          out[(size_t)(rb + r) * EMB + cg] = hu.u;
        }
      }
    }
  }
}

// ---------------------------------------------------------------------------
// Out projection: stages fp32 ctx, splits hi/lo in-kernel (3-term MFMA).
// ---------------------------------------------------------------------------
__global__ __launch_bounds__(256) void out_mfma(
    const float* __restrict__ ctx, const u16* __restrict__ wpk,
    const float* __restrict__ bias, float* __restrict__ out)
{
  const u16* Wh = wpk + (size_t)3 * 2 * 65536;
  const u16* Wl = Wh + 65536;
  __shared__ u16 Ah[128 * 40], Al[128 * 40], Bh[128 * 40], Bl[128 * 40];
  const int tid = threadIdx.x;
  const int m0 = blockIdx.x * 128, n0 = blockIdx.y * 128;
  const int wv = tid >> 6, ln = tid & 63;
  const int quad = ln >> 4, r16 = ln & 15;
  const int wm = (wv & 1) * 64, wn = (wv >> 1) * 64;
  const int srow = tid >> 1, shalf = (tid & 1) * 16;

  f32x4v acc[4][4];
#pragma unroll
  for (int i = 0; i < 4; ++i)
#pragma unroll
    for (int j = 0; j < 4; ++j) acc[i][j] = (f32x4v){0.f, 0.f, 0.f, 0.f};

  for (int k0 = 0; k0 < EMB; k0 += 32) {
    __syncthreads();
    {
      size_t ga = (size_t)(m0 + srow) * EMB + k0 + shalf;
      float4 c0 = *(const float4*)(ctx + ga);
      float4 c1 = *(const float4*)(ctx + ga + 4);
      float4 c2 = *(const float4*)(ctx + ga + 8);
      float4 c3 = *(const float4*)(ctx + ga + 12);
      float v[16] = {c0.x,c0.y,c0.z,c0.w, c1.x,c1.y,c1.z,c1.w,
                     c2.x,c2.y,c2.z,c2.w, c3.x,c3.y,c3.z,c3.w};
      u16 hh[16], ll[16];
#pragma unroll
      for (int jj = 0; jj < 16; ++jj) {
        hh[jj] = f2bf(v[jj]);
        ll[jj] = f2bf(v[jj] - bf2f(hh[jj]));
      }
      int o = srow * 40 + shalf;
#pragma unroll
      for (int g = 0; g < 2; ++g) {
        uint4 ph, pl;
        ph.x = hh[g*8+0] | ((unsigned)hh[g*8+1] << 16);
        ph.y = hh[g*8+2] | ((unsigned)hh[g*8+3] << 16);
        ph.z = hh[g*8+4] | ((unsigned)hh[g*8+5] << 16);
        ph.w = hh[g*8+6] | ((unsigned)hh[g*8+7] << 16);
        pl.x = ll[g*8+0] | ((unsigned)ll[g*8+1] << 16);
        pl.y = ll[g*8+2] | ((unsigned)ll[g*8+3] << 16);
        pl.z = ll[g*8+4] | ((unsigned)ll[g*8+5] << 16);
        pl.w = ll[g*8+6] | ((unsigned)ll[g*8+7] << 16);
        *(uint4*)&Ah[o + g*8] = ph;
        *(uint4*)&Al[o + g*8] = pl;
      }
      size_t gb = (size_t)(n0 + srow) * EMB + k0 + shalf;
      uint4 bh0 = *(const uint4*)(Wh + gb), bh1 = *(const uint4*)(Wh + gb + 8);
      uint4 bl0 = *(const uint4*)(Wl + gb), bl1 = *(const uint4*)(Wl + gb + 8);
      *(uint4*)&Bh[o] = bh0; *(uint4*)&Bh[o + 8] = bh1;
      *(uint4*)&Bl[o] = bl0; *(uint4*)&Bl[o + 8] = bl1;
    }
    __syncthreads();
    frag8 fbh[4], fbl[4];
#pragma unroll
    for (int nt = 0; nt < 4; ++nt) {
      int ob = (wn + nt * 16 + r16) * 40 + quad * 8;
      fbh[nt] = *(const frag8*)&Bh[ob];
      fbl[nt] = *(const frag8*)&Bl[ob];
    }
#pragma unroll
    for (int mt = 0; mt < 4; ++mt) {
      int oa = (wm + mt * 16 + r16) * 40 + quad * 8;
      frag8 fah = *(const frag8*)&Ah[oa];
      frag8 fal = *(const frag8*)&Al[oa];
#pragma unroll
      for (int nt = 0; nt < 4; ++nt) {
        acc[mt][nt] = __builtin_amdgcn_mfma_f32_16x16x32_bf16(fah, fbh[nt], acc[mt][nt], 0, 0, 0);
        acc[mt][nt] = __builtin_amdgcn_mfma_f32_16x16x32_bf16(fah, fbl[nt], acc[mt][nt], 0, 0, 0);
        acc[mt][nt] = __builtin_amdgcn_mfma_f32_16x16x32_bf16(fal, fbh[nt], acc[mt][nt], 0, 0, 0);
      }
    }
  }
#pragma unroll
  for (int nt = 0; nt < 4; ++nt) {
    int cg = n0 + wn + nt * 16 + r16;
    float bvv = bias[cg];
#pragma unroll
    for (int mt = 0; mt < 4; ++mt) {
      int rb = m0 + wm + mt * 16 + quad * 4;
#pragma unroll
      for (int r = 0; r < 4; ++r)
        out[(size_t)(rb + r) * EMB + cg] = acc[mt][nt][r] + bvv;
    }
  }
}

// ---------------------------------------------------------------------------
// Top-k per row (radix-256), with margin flagging into per-batch lists.
// ---------------------------------------------------------------------------
__global__ __launch_bounds__(256) void topk_idx(
    const float* __restrict__ scores, u16* __restrict__ idxl,
    int* __restrict__ flagcnt, int* __restrict__ flaglist)
{
  __shared__ int hist[4][256];
  __shared__ int sel[2];
  __shared__ int wsum[4];
  __shared__ unsigned wmax[4];
  const int r = blockIdx.x;
  const int tid = threadIdx.x;
  const int lane = tid & 63, wid = tid >> 6;
  const float* row = scores + (size_t)r * SEQ;
  unsigned key[8];
  {
    float4 f0 = *(const float4*)(row + tid * 8);
    float4 f1 = *(const float4*)(row + tid * 8 + 4);
    key[0]=f2ord(f0.x); key[1]=f2ord(f0.y); key[2]=f2ord(f0.z); key[3]=f2ord(f0.w);
    key[4]=f2ord(f1.x); key[5]=f2ord(f1.y); key[6]=f2ord(f1.z); key[7]=f2ord(f1.w);
  }
  unsigned V; int MEQ;
  tk_radix(key, tid, hist, sel, V, MEQ);

  {
    int ceq = 0; unsigned mk = 0;
#pragma unroll
    for (int j = 0; j < 8; ++j) {
      ceq += (key[j] == V) ? 1 : 0;
      if (key[j] < V && key[j] > mk) mk = key[j];
    }
#pragma unroll
    for (int off = 32; off > 0; off >>= 1) {
      ceq += __shfl_down(ceq, off, 64);
      unsigned o = (unsigned)__shfl_down((int)mk, off, 64);
      if (o > mk) mk = o;
    }
    if (lane == 0) { wsum[wid] = ceq; wmax[wid] = mk; }
    __syncthreads();
    if (tid == 0) {
      int EQ = wsum[0] + wsum[1] + wsum[2] + wsum[3];
      unsigned m2 = wmax[0];
      for (int w = 1; w < 4; ++w) if (wmax[w] > m2) m2 = wmax[w];
      bool flag = (EQ > MEQ) || !(ord2f(V) - ord2f(m2) >= MBOUND);
      if (flag) {
        int bb = r >> 11;
        int p = atomicAdd(&flagcnt[bb], 1);
        flaglist[bb * SEQ + p] = r & (SEQ - 1);
      }
    }
    __syncthreads();
  }

  tk_write(key, V, MEQ, tid, idxl + (size_t)r * IDXP, wsum);
}

// ---------------------------------------------------------------------------
// Fixup A: exact fp32 scores for flagged rows (gathered-A 64x64 GEMM).
// ---------------------------------------------------------------------------
__global__ __launch_bounds__(256) void fixup_gemm(
    const float* __restrict__ x, const int* __restrict__ flagcnt,
    const int* __restrict__ flaglist, float* __restrict__ attn)
{
  const int b = blockIdx.z;
  const int n = flagcnt[b];
  const int g0 = blockIdx.y * 64;
  if (g0 >= n) return;
  __shared__ float As[16][68];
  __shared__ float Bs[16][68];
  __shared__ int rowsh[64];
  const int tid = threadIdx.x;
  const int n0 = blockIdx.x * 64;
  if (tid < 64) {
    int gi = g0 + tid;
    rowsh[tid] = (gi < n) ? flaglist[b * SEQ + gi] : -1;
  }
  __syncthreads();
  const float* xb = x + (size_t)b * SEQ * EMB;
  const int lm = tid >> 2;
  const int lk = (tid & 3) << 2;
  const int mt = tid >> 4;
  const int nt = tid & 15;
  const int arow = rowsh[lm];
  const int arowL = (arow < 0) ? 0 : arow;
  float acc[4][4] = {{0.f}};
  for (int k0 = 0; k0 < EMB; k0 += 16) {
    float4 av = *(const float4*)(xb + (size_t)arowL * EMB + k0 + lk);
    float4 bv = *(const float4*)(xb + (size_t)(n0 + lm) * EMB + k0 + lk);
    __syncthreads();
    As[lk+0][lm] = av.x; As[lk+1][lm] = av.y; As[lk+2][lm] = av.z; As[lk+3][lm] = av.w;
    Bs[lk+0][lm] = bv.x; Bs[lk+1][lm] = bv.y; Bs[lk+2][lm] = bv.z; Bs[lk+3][lm] = bv.w;
    __syncthreads();
#pragma unroll
    for (int kk = 0; kk < 16; ++kk) {
      float4 a4 = *(const float4*)&As[kk][mt << 2];
      float4 b4 = *(const float4*)&Bs[kk][nt << 2];
      acc[0][0] += a4.x*b4.x; acc[0][1] += a4.x*b4.y; acc[0][2] += a4.x*b4.z; acc[0][3] += a4.x*b4.w;
      acc[1][0] += a4.y*b4.x; acc[1][1] += a4.y*b4.y; acc[1][2] += a4.y*b4.z; acc[1][3] += a4.y*b4.w;
      acc[2][0] += a4.z*b4.x; acc[2][1] += a4.z*b4.y; acc[2][2] += a4.z*b4.z; acc[2][3] += a4.z*b4.w;
      acc[3][0] += a4.w*b4.x; acc[3][1] += a4.w*b4.y; acc[3][2] += a4.w*b4.z; acc[3][3] += a4.w*b4.w;
    }
  }
  float* attnB = attn + (size_t)b * SEQ * SEQ;
#pragma unroll
  for (int r = 0; r < 4; ++r) {
    int rr = rowsh[(mt << 2) + r];
    if (rr >= 0) {
      float4 o;
      o.x = acc[r][0] * 0.0625f; o.y = acc[r][1] * 0.0625f;
      o.z = acc[r][2] * 0.0625f; o.w = acc[r][3] * 0.0625f;
      *(float4*)(attnB + (size_t)rr * SEQ + n0 + (nt << 2)) = o;
    }
  }
}

// ---------------------------------------------------------------------------
// Fixup B: redo top-k (radix) on the now-exact flagged rows.
// ---------------------------------------------------------------------------
__global__ __launch_bounds__(256) void topk_fixup(
    const float* __restrict__ attn, const int* __restrict__ flagcnt,
    const int* __restrict__ flaglist, u16* __restrict__ idxl)
{
  const int b = blockIdx.y;
  if ((int)blockIdx.x >= flagcnt[b]) return;
  const int r = b * SEQ + flaglist[b * SEQ + blockIdx.x];
  __shared__ int hist[4][256];
  __shared__ int sel[2];
  __shared__ int wsum[4];
  const int tid = threadIdx.x;
  const float* row = attn + (size_t)r * SEQ;
  unsigned key[8];
  {
    float4 f0 = *(const float4*)(row + tid * 8);
    float4 f1 = *(const float4*)(row + tid * 8 + 4);
    key[0]=f2ord(f0.x); key[1]=f2ord(f0.y); key[2]=f2ord(f0.z); key[3]=f2ord(f0.w);
    key[4]=f2ord(f1.x); key[5]=f2ord(f1.y); key[6]=f2ord(f1.z); key[7]=f2ord(f1.w);
  }
  unsigned V; int MEQ;
  tk_radix(key, tid, hist, sel, V, MEQ);
  tk_write(key, V, MEQ, tid, idxl + (size_t)r * IDXP, wsum);
}

// ---------------------------------------------------------------------------
// Sparse attention v6: f16 Q/K/V, fdot2 dots, 2-keys-per-wave-load, 32-bit
// byte offsets; rsh (dense attn row) and csh (ctx partials) share one LDS
// region (rsh dead after stream-out) -> ~17.7 KB LDS -> 8 blocks/CU.
// ---------------------------------------------------------------------------
__global__ __launch_bounds__(256) void sparse_attn(
    const u16* __restrict__ qf, const u16* __restrict__ kf,
    const u16* __restrict__ vf, const u16* __restrict__ idxl,
    float* __restrict__ attn, float* __restrict__ ctxb)
{
  const int lin = blockIdx.x;
  const int b = lin & 3;                                  // XCD-stable batch
  const int q = (lin >> 3) + (((lin >> 2) & 1) << 10);
  const int tid = threadIdx.x;
  const int wv = tid >> 6, ln = tid & 63;
  const int half = ln >> 5, sl = ln & 31;
  const int h = sl >> 2, d0 = sl * 8;
  const int lb = sl * 16;
  __shared__ int   ish[IDXP];
  __shared__ int   koff[IDXP];
  __shared__ float psh[IDXP * 9 + 4];   // [j][h], stride 9
  __shared__ float idsh[NH];
  __shared__ float rcsh[2112];          // union: rsh[2048] | csh[8][264]
#define CSH(i, j) rcsh[(i) * 264 + (j)]

  const int row = b * SEQ + q;
  if (tid < KTOP) {
    int idx = (int)idxl[(size_t)row * IDXP + tid];
    ish[tid] = idx;
    koff[tid] = idx << 9;
  } else if (tid < IDXP) {
    ish[tid] = 0; koff[tid] = 0;
  }
  if (tid < 32) psh[(KTOP + (tid >> 3)) * 9 + (tid & 7)] = 0.f;

  float4 z4 = make_float4(0.f, 0.f, 0.f, 0.f);
  *(float4*)&rcsh[tid * 4]        = z4;
  *(float4*)&rcsh[1024 + tid * 4] = z4;

  U4 qv;
  qv.u = *(const uint4*)((const char*)(qf + (size_t)row * EMB) + lb);

  __syncthreads();

  const float scale = 0.17677669529663687f;  // 1/sqrt(32)
  const char* kbC = (const char*)(kf + (size_t)(b * SEQ) * EMB);
  const int jb = wv * KPW;
#pragma unroll 4
  for (int t = 0; t < KPW; t += 2) {
    const int j = jb + t + half;
    U4 kv;
    kv.u = *(const uint4*)(kbC + (koff[j] + lb));
    float s = FDOT2(qv.h[0], kv.h[0],
              FDOT2(qv.h[1], kv.h[1],
              FDOT2(qv.h[2], kv.h[2],
              FDOT2(qv.h[3], kv.h[3], 0.f))));
    s += __shfl_xor(s, 1, 64);
    s += __shfl_xor(s, 2, 64);
    if ((sl & 3) == 0 && j < KTOP) psh[j * 9 + h] = __expf(s * scale);
  }
  __syncthreads();

  {
    int h2 = tid >> 5, l = tid & 31;
    float sden = 0.f;
    for (int j = l; j < KTOP; j += 32) sden += psh[j * 9 + h2];
#pragma unroll
    for (int off = 16; off > 0; off >>= 1) sden += __shfl_down(sden, off, 32);
    if (l == 0) idsh[h2] = 1.0f / sden;
  }
  __syncthreads();

  if (tid < KTOP) {
    float ps = 0.f;
#pragma unroll
    for (int hh = 0; hh < 8; ++hh) {
      float pp = psh[tid * 9 + hh] * idsh[hh];
      psh[tid * 9 + hh] = pp;
      ps += pp;
    }
    rcsh[ish[tid]] = ps * 0.125f;
  }
  __syncthreads();

  // stream dense row out (full-line, conflict-free)
  {
    float* arow = attn + (size_t)row * SEQ;
    *(float4*)(arow + tid * 4)        = *(const float4*)&rcsh[tid * 4];
    *(float4*)(arow + 1024 + tid * 4) = *(const float4*)&rcsh[1024 + tid * 4];
  }
  __syncthreads();   // rsh dead; csh may now overwrite the region

  {
    const char* vbC = (const char*)(vf + (size_t)(b * SEQ) * EMB);
    float a8[8] = {0.f,0.f,0.f,0.f,0.f,0.f,0.f,0.f};
#pragma unroll 4
    for (int t = 0; t < KPW; t += 2) {
      const int j = jb + t + half;
      float p = psh[j * 9 + h];
      U4 vv;
      vv.u = *(const uint4*)(vbC + (koff[j] + lb));
      a8[0] += p * (float)vv.h[0][0]; a8[1] += p * (float)vv.h[0][1];
      a8[2] += p * (float)vv.h[1][0]; a8[3] += p * (float)vv.h[1][1];
      a8[4] += p * (float)vv.h[2][0]; a8[5] += p * (float)vv.h[2][1];
      a8[6] += p * (float)vv.h[3][0]; a8[7] += p * (float)vv.h[3][1];
    }
    const int pi = wv * 2 + half;
    *(float4*)&CSH(pi, d0)     = make_float4(a8[0], a8[1], a8[2], a8[3]);
    *(float4*)&CSH(pi, d0 + 4) = make_float4(a8[4], a8[5], a8[6], a8[7]);
  }
  __syncthreads();
  if (tid < 64) {
    float4 o = z4;
#pragma unroll
    for (int g = 0; g < 8; ++g) {
      float4 v = *(const float4*)&CSH(g, tid * 4);
      o.x += v.x; o.y += v.y; o.z += v.z; o.w += v.w;
    }
    *(float4*)(ctxb + (size_t)row * EMB + tid * 4) = o;
  }
#undef CSH
}

// ---------------------------------------------------------------------------
extern "C" void kernel_launch(void* const* d_in, const int* in_sizes, int n_in,
                              void* d_out, int out_size, void* d_ws, size_t ws_size,
                              hipStream_t stream)
{
  const float* x  = (const float*)d_in[0];
  const float* Wq = (const float*)d_in[1];
  const float* bq = (const float*)d_in[2];
  const float* Wk = (const float*)d_in[3];
  const float* bk = (const float*)d_in[4];
  const float* Wv = (const float*)d_in[5];
  const float* bv = (const float*)d_in[6];
  const float* Wo = (const float*)d_in[7];
  const float* bo = (const float*)d_in[8];

  float* out  = (float*)d_out;
  float* attn = out + (size_t)NB * SEQ * EMB;   // [B,S,S] region of d_out

  const size_t NSE = (size_t)NB * SEQ * EMB;    // 2097152
  u16* xh  = (u16*)d_ws;            // bf16 hi of x
  u16* xl  = xh + NSE;              // bf16 lo
  u16* qf  = xl + NSE;              // f16 Q
  u16* kf  = qf + NSE;              // f16 K
  u16* vf  = kf + NSE;              // f16 V
  u16* wpk = vf + NSE;              // 4 x (hi,lo) 256x256 bf16
  float* ctxb = (float*)(wpk + 4 * 2 * 65536);
  u16* idxl = (u16*)(ctxb + NSE);
  int* flagcnt  = (int*)(idxl + (size_t)NB * SEQ * IDXP);
  int* flaglist = flagcnt + NB;

  const dim3 blk(256);

  // hi/lo splits of x + weights (one launch); flag counters reset
  pack_all<<<dim3(1152), blk, 0, stream>>>(x, Wq, Wk, Wv, Wo, xh, xl, wpk, flagcnt);

  // scores (4-term) + QKV projections (3-term, f16 out) in one launch
  fused_gemms<<<dim3(1408), blk, 0, stream>>>(xh, xl, wpk, bq, bk, bv,
                                              qf, kf, vf, attn);

  // radix top-k with margin flagging; exact fp32 fixup of low-margin rows
  topk_idx<<<dim3(NB * SEQ), blk, 0, stream>>>(attn, idxl, flagcnt, flaglist);
  fixup_gemm<<<dim3(32, 32, NB), blk, 0, stream>>>(x, flagcnt, flaglist, attn);
  topk_fixup<<<dim3(SEQ, NB), blk, 0, stream>>>(attn, flagcnt, flaglist, idxl);

  // fused sparse attention (f16 gathers + fdot2, shared rsh/csh LDS)
  sparse_attn<<<dim3(SEQ * NB), blk, 0, stream>>>(qf, kf, vf, idxl, attn, ctxb);

  // out = ctx @ Wo^T + bo (in-kernel hi/lo split of ctx)
  out_mfma<<<dim3(64, 2), blk, 0, stream>>>(ctxb, wpk, bo, out);
}

// Round 11
// 317.852 us; speedup vs baseline: 1.6384x; 1.0171x over previous
//
#include <hip/hip_runtime.h>

#define SEQ  2048
#define EMB  256
#define NH   8
#define HD   32
#define NB   4
#define KTOP 204
#define IDXP 208
#define KPW  52       // keys per wave (4*52 = 208, padded)
#define MBOUND 4e-4f  // top-k margin for fp32 re-verify

typedef unsigned long long ull;
typedef unsigned short u16;

using frag8  = __attribute__((ext_vector_type(8))) short;  // 8 bf16
using f32x4v = __attribute__((ext_vector_type(4))) float;
typedef _Float16 f16;
typedef _Float16 f16x2 __attribute__((ext_vector_type(2)));

union U4 { uint4 u; f16x2 h[4]; };
union HU { f16 h; u16 u; };

#if defined(__has_builtin)
#if __has_builtin(__builtin_amdgcn_fdot2)
#define FDOT2(a,b,c) __builtin_amdgcn_fdot2(a, b, c, false)
#endif
#endif
#ifndef FDOT2
__device__ __forceinline__ float fdot2_sw(f16x2 a, f16x2 b, float c) {
  return c + (float)a[0]*(float)b[0] + (float)a[1]*(float)b[1];
}
#define FDOT2(a,b,c) fdot2_sw(a,b,c)
#endif

__device__ __forceinline__ unsigned f2ord(float f) {
  unsigned u = __float_as_uint(f);
  return (u & 0x80000000u) ? ~u : (u | 0x80000000u);
}
__device__ __forceinline__ float ord2f(unsigned o) {
  unsigned u = (o & 0x80000000u) ? (o ^ 0x80000000u) : ~o;
  return __uint_as_float(u);
}
__device__ __forceinline__ u16 f2bf(float f) {
  unsigned u = __float_as_uint(f);
  u += 0x7FFF + ((u >> 16) & 1);     // RTNE
  return (u16)(u >> 16);
}
__device__ __forceinline__ float bf2f(u16 h) {
  return __uint_as_float((unsigned)h << 16);
}

// ---------------------------------------------------------------------------
// Radix-256 top-k (4 byte passes, per-wave histograms, wave-0 suffix scan).
// ---------------------------------------------------------------------------
__device__ __forceinline__ void tk_radix(
    const unsigned key[8], int tid, int (*hist)[256], int* sel,
    unsigned& V, int& MEQ)
{
  const int lane = tid & 63, wid = tid >> 6;
  unsigned prefix = 0;
  int k = KTOP;
#pragma unroll
  for (int p = 0; p < 4; ++p) {
    const int shift = 24 - 8 * p;
    hist[0][tid] = 0; hist[1][tid] = 0; hist[2][tid] = 0; hist[3][tid] = 0;
    __syncthreads();
#pragma unroll
    for (int j = 0; j < 8; ++j) {
      unsigned kj = key[j];
      bool ok = (p == 0) || ((kj >> (shift + 8)) == prefix);
      if (ok) atomicAdd(&hist[wid][(kj >> shift) & 255], 1);
    }
    __syncthreads();
    {
      int c = hist[0][tid] + hist[1][tid] + hist[2][tid] + hist[3][tid];
      hist[0][tid] = c;
    }
    __syncthreads();
    if (wid == 0) {
      int m0 = hist[0][lane * 4 + 0], m1 = hist[0][lane * 4 + 1];
      int m2 = hist[0][lane * 4 + 2], m3 = hist[0][lane * 4 + 3];
      int sl = m0 + m1 + m2 + m3;
      int suf = sl;
#pragma unroll
      for (int off = 1; off < 64; off <<= 1) {
        int y = __shfl_down(suf, off, 64);
        if (lane + off < 64) suf += y;
      }
      int above = suf - sl;
      if (above < k && k <= suf) {
        int bin, nk;
        if (k <= above + m3)                { bin = lane*4+3; nk = k - above; }
        else if (k <= above + m3 + m2)      { bin = lane*4+2; nk = k - above - m3; }
        else if (k <= above + m3 + m2 + m1) { bin = lane*4+1; nk = k - above - m3 - m2; }
        else                                { bin = lane*4+0; nk = k - above - m3 - m2 - m1; }
        sel[0] = bin; sel[1] = nk;
      }
    }
    __syncthreads();
    prefix = (prefix << 8) | (unsigned)sel[0];
    k = sel[1];
    __syncthreads();
  }
  V = prefix;
  MEQ = k;
}

__device__ __forceinline__ int tk_scan_excl(int v, int tid, int* wsum) {
  const int lane = tid & 63, wid = tid >> 6;
  int x = v;
#pragma unroll
  for (int off = 1; off < 64; off <<= 1) {
    int y = __shfl_up(x, off, 64);
    if (lane >= off) x += y;
  }
  if (lane == 63) wsum[wid] = x;
  __syncthreads();
  int base = 0;
  for (int w = 0; w < wid; ++w) base += wsum[w];
  return base + x - v;
}

__device__ __forceinline__ void tk_write(const unsigned key[8], unsigned V, int MEQ,
                                         int tid, u16* orow, int* wsum) {
  int ceq = 0;
#pragma unroll
  for (int j = 0; j < 8; ++j) ceq += (key[j] == V) ? 1 : 0;
  int run = tk_scan_excl(ceq, tid, wsum);
  unsigned bits = 0;
#pragma unroll
  for (int j = 0; j < 8; ++j) {
    bool e = (key[j] == V);
    bool s = (key[j] > V) || (e && (run < MEQ));
    if (e) run++;
    if (s) bits |= (1u << j);
  }
  int csel = __popc(bits);
  __syncthreads();
  int base = tk_scan_excl(csel, tid, wsum);
#pragma unroll
  for (int j = 0; j < 8; ++j)
    if ((bits >> j) & 1u) orow[base++] = (u16)(tid * 8 + j);
}

// ---------------------------------------------------------------------------
// pack_all: bf16 hi/lo split of x (blocks 0..1023) and the 4 weight matrices
// (blocks 1024..1151); block 0 also zeroes the per-batch flag counters.
// ---------------------------------------------------------------------------
__global__ __launch_bounds__(256) void pack_all(
    const float* __restrict__ x,
    const float* __restrict__ W0, const float* __restrict__ W1,
    const float* __restrict__ W2, const float* __restrict__ W3,
    u16* __restrict__ xh, u16* __restrict__ xl, u16* __restrict__ wpk,
    int* __restrict__ flagcnt)
{
  const int lin = blockIdx.x;
  if (lin == 0 && threadIdx.x < NB) flagcnt[threadIdx.x] = 0;
  const float* src; u16 *dh, *dl; int i;
  if (lin < 1024) {
    src = x;
    i = (lin * 256 + threadIdx.x) * 8;
    dh = xh; dl = xl;
  } else {
    int j = lin - 1024;             // 0..127
    int m = j >> 5, bx = j & 31;
    src = (m == 0) ? W0 : (m == 1) ? W1 : (m == 2) ? W2 : W3;
    i = (bx * 256 + threadIdx.x) * 8;
    dh = wpk + (size_t)m * 2 * 65536;
    dl = dh + 65536;
  }
  float4 a = *(const float4*)(src + i);
  float4 b = *(const float4*)(src + i + 4);
  float v[8] = {a.x,a.y,a.z,a.w,b.x,b.y,b.z,b.w};
  u16 h[8], l[8];
#pragma unroll
  for (int j = 0; j < 8; ++j) {
    h[j] = f2bf(v[j]);
    l[j] = f2bf(v[j] - bf2f(h[j]));
  }
  uint4 ph, pl;
  ph.x = h[0] | ((unsigned)h[1] << 16); ph.y = h[2] | ((unsigned)h[3] << 16);
  ph.z = h[4] | ((unsigned)h[5] << 16); ph.w = h[6] | ((unsigned)h[7] << 16);
  pl.x = l[0] | ((unsigned)l[1] << 16); pl.y = l[2] | ((unsigned)l[3] << 16);
  pl.z = l[4] | ((unsigned)l[5] << 16); pl.w = l[6] | ((unsigned)l[7] << 16);
  *(uint4*)(dh + i) = ph;
  *(uint4*)(dl + i) = pl;
}

// ---------------------------------------------------------------------------
// fused_gemms: scores (SYMMETRIC — upper-triangle blocks only, mirror written
// from registers; blocks 0..543) + QKV projections (blocks 544..927).
// ---------------------------------------------------------------------------
__global__ __launch_bounds__(256) void fused_gemms(
    const u16* __restrict__ xh, const u16* __restrict__ xl,
    const u16* __restrict__ wpk,
    const float* __restrict__ bq, const float* __restrict__ bk,
    const float* __restrict__ bv,
    u16* __restrict__ qo, u16* __restrict__ ko, u16* __restrict__ vo,
    float* __restrict__ attnC)
{
  __shared__ u16 Ah[128 * 40], Al[128 * 40], Bh[128 * 40], Bl[128 * 40];
  const int lin = blockIdx.x;
  const int tid = threadIdx.x;
  const int wv = tid >> 6, ln = tid & 63;
  const int quad = ln >> 4, r16 = ln & 15;
  const int wm = (wv & 1) * 64, wn = (wv >> 1) * 64;
  const int srow = tid >> 1, shalf = (tid & 1) * 16;

  f32x4v acc[4][4];
#pragma unroll
  for (int i = 0; i < 4; ++i)
#pragma unroll
    for (int j = 0; j < 4; ++j) acc[i][j] = (f32x4v){0.f, 0.f, 0.f, 0.f};

  if (lin < 544) {
    // ----- scores path (symmetric, bi <= bj) -----
    const int b = lin / 136;
    int p = lin - b * 136;
    int bi = 0;
    while (p >= 16 - bi) { p -= 16 - bi; ++bi; }
    const int bj = bi + p;
    const int m0 = bi * 128, n0 = bj * 128;
    const u16* xhB = xh + (size_t)b * SEQ * EMB;
    const u16* xlB = xl + (size_t)b * SEQ * EMB;
    float* Cb = attnC + (size_t)b * SEQ * SEQ;
    for (int k0 = 0; k0 < EMB; k0 += 32) {
      __syncthreads();
      {
        size_t ga = (size_t)(m0 + srow) * EMB + k0 + shalf;
        size_t gb = (size_t)(n0 + srow) * EMB + k0 + shalf;
        uint4 ah0 = *(const uint4*)(xhB + ga), ah1 = *(const uint4*)(xhB + ga + 8);
        uint4 al0 = *(const uint4*)(xlB + ga), al1 = *(const uint4*)(xlB + ga + 8);
        uint4 bh0 = *(const uint4*)(xhB + gb), bh1 = *(const uint4*)(xhB + gb + 8);
        uint4 bl0 = *(const uint4*)(xlB + gb), bl1 = *(const uint4*)(xlB + gb + 8);
        int o = srow * 40 + shalf;
        *(uint4*)&Ah[o] = ah0; *(uint4*)&Ah[o + 8] = ah1;
        *(uint4*)&Al[o] = al0; *(uint4*)&Al[o + 8] = al1;
        *(uint4*)&Bh[o] = bh0; *(uint4*)&Bh[o + 8] = bh1;
        *(uint4*)&Bl[o] = bl0; *(uint4*)&Bl[o + 8] = bl1;
      }
      __syncthreads();
      frag8 fbh[4], fbl[4];
#pragma unroll
      for (int nt = 0; nt < 4; ++nt) {
        int ob = (wn + nt * 16 + r16) * 40 + quad * 8;
        fbh[nt] = *(const frag8*)&Bh[ob];
        fbl[nt] = *(const frag8*)&Bl[ob];
      }
#pragma unroll
      for (int mt = 0; mt < 4; ++mt) {
        int oa = (wm + mt * 16 + r16) * 40 + quad * 8;
        frag8 fah = *(const frag8*)&Ah[oa];
        frag8 fal = *(const frag8*)&Al[oa];
#pragma unroll
        for (int nt = 0; nt < 4; ++nt) {
          acc[mt][nt] = __builtin_amdgcn_mfma_f32_16x16x32_bf16(fah, fbh[nt], acc[mt][nt], 0, 0, 0);
          acc[mt][nt] = __builtin_amdgcn_mfma_f32_16x16x32_bf16(fah, fbl[nt], acc[mt][nt], 0, 0, 0);
          acc[mt][nt] = __builtin_amdgcn_mfma_f32_16x16x32_bf16(fal, fbh[nt], acc[mt][nt], 0, 0, 0);
          acc[mt][nt] = __builtin_amdgcn_mfma_f32_16x16x32_bf16(fal, fbl[nt], acc[mt][nt], 0, 0, 0);
        }
      }
    }
    // normal write (upper block)
#pragma unroll
    for (int mt = 0; mt < 4; ++mt)
#pragma unroll
      for (int nt = 0; nt < 4; ++nt) {
        int cg = n0 + wn + nt * 16 + r16;
        int rb = m0 + wm + mt * 16 + quad * 4;
#pragma unroll
        for (int r = 0; r < 4; ++r)
          Cb[(size_t)(rb + r) * SEQ + cg] = acc[mt][nt][r] * 0.0625f;
      }
    // mirror write (lower block): element (rb+r, cg) -> (cg, rb+r).
    // reg index r spans 4 consecutive COLUMNS of the mirror -> float4/lane.
    if (bi != bj) {
#pragma unroll
      for (int mt = 0; mt < 4; ++mt)
#pragma unroll
        for (int nt = 0; nt < 4; ++nt) {
          int cg = n0 + wn + nt * 16 + r16;
          int rb = m0 + wm + mt * 16 + quad * 4;
          float4 o;
          o.x = acc[mt][nt][0] * 0.0625f;
          o.y = acc[mt][nt][1] * 0.0625f;
          o.z = acc[mt][nt][2] * 0.0625f;
          o.w = acc[mt][nt][3] * 0.0625f;
          *(float4*)&Cb[(size_t)cg * SEQ + rb] = o;
        }
    }
  } else {
    // ----- qkv path -----
    const int j = lin - 544;
    const int m0 = (j & 63) * 128, n0 = ((j >> 6) & 1) * 128;
    const int z = j >> 7;
    const u16* Wh = wpk + (size_t)z * 2 * 65536;
    const u16* Wl = Wh + 65536;
    const float* bias = (z == 0) ? bq : (z == 1) ? bk : bv;
    u16* out = (z == 0) ? qo : (z == 1) ? ko : vo;
    for (int k0 = 0; k0 < EMB; k0 += 32) {
      __syncthreads();
      {
        size_t ga = (size_t)(m0 + srow) * EMB + k0 + shalf;
        size_t gb = (size_t)(n0 + srow) * EMB + k0 + shalf;
        uint4 ah0 = *(const uint4*)(xh + ga), ah1 = *(const uint4*)(xh + ga + 8);
        uint4 al0 = *(const uint4*)(xl + ga), al1 = *(const uint4*)(xl + ga + 8);
        uint4 bh0 = *(const uint4*)(Wh + gb), bh1 = *(const uint4*)(Wh + gb + 8);
        uint4 bl0 = *(const uint4*)(Wl + gb), bl1 = *(const uint4*)(Wl + gb + 8);
        int o = srow * 40 + shalf;
        *(uint4*)&Ah[o] = ah0; *(uint4*)&Ah[o + 8] = ah1;
        *(uint4*)&Al[o] = al0; *(uint4*)&Al[o + 8] = al1;
        *(uint4*)&Bh[o] = bh0; *(uint4*)&Bh[o + 8] = bh1;
        *(uint4*)&Bl[o] = bl0; *(uint4*)&Bl[o + 8] = bl1;
      }
      __syncthreads();
      frag8 fbh[4], fbl[4];
#pragma unroll
      for (int nt = 0; nt < 4; ++nt) {
        int ob = (wn + nt * 16 + r16) * 40 + quad * 8;
        fbh[nt] = *(const frag8*)&Bh[ob];
        fbl[nt] = *(const frag8*)&Bl[ob];
      }
#pragma unroll
      for (int mt = 0; mt < 4; ++mt) {
        int oa = (wm + mt * 16 + r16) * 40 + quad * 8;
        frag8 fah = *(const frag8*)&Ah[oa];
        frag8 fal = *(const frag8*)&Al[oa];
#pragma unroll
        for (int nt = 0; nt < 4; ++nt) {
          acc[mt][nt] = __builtin_amdgcn_mfma_f32_16x16x32_bf16(fah, fbh[nt], acc[mt][nt], 0, 0, 0);
          acc[mt][nt] = __builtin_amdgcn_mfma_f32_16x16x32_bf16(fah, fbl[nt], acc[mt][nt], 0, 0, 0);
          acc[mt][nt] = __builtin_amdgcn_mfma_f32_16x16x32_bf16(fal, fbh[nt], acc[mt][nt], 0, 0, 0);
        }
      }
    }
#pragma unroll
    for (int nt = 0; nt < 4; ++nt) {
      int cg = n0 + wn + nt * 16 + r16;
      float bvv = bias[cg];
#pragma unroll
      for (int mt = 0; mt < 4; ++mt) {
        int rb = m0 + wm + mt * 16 + quad * 4;
#pragma unroll
        for (int r = 0; r < 4; ++r) {
          HU hu; hu.h = (f16)(acc[mt][nt][r] + bvv);
          out[(size_t)(rb + r) * EMB + cg] = hu.u;
        }
      }
    }
  }
}

// ---------------------------------------------------------------------------
// Out projection: stages fp32 ctx, splits hi/lo in-kernel (3-term MFMA).
// ---------------------------------------------------------------------------
__global__ __launch_bounds__(256) void out_mfma(
    const float* __restrict__ ctx, const u16* __restrict__ wpk,
    const float* __restrict__ bias, float* __restrict__ out)
{
  const u16* Wh = wpk + (size_t)3 * 2 * 65536;
  const u16* Wl = Wh + 65536;
  __shared__ u16 Ah[128 * 40], Al[128 * 40], Bh[128 * 40], Bl[128 * 40];
  const int tid = threadIdx.x;
  const int m0 = blockIdx.x * 128, n0 = blockIdx.y * 128;
  const int wv = tid >> 6, ln = tid & 63;
  const int quad = ln >> 4, r16 = ln & 15;
  const int wm = (wv & 1) * 64, wn = (wv >> 1) * 64;
  const int srow = tid >> 1, shalf = (tid & 1) * 16;

  f32x4v acc[4][4];
#pragma unroll
  for (int i = 0; i < 4; ++i)
#pragma unroll
    for (int j = 0; j < 4; ++j) acc[i][j] = (f32x4v){0.f, 0.f, 0.f, 0.f};

  for (int k0 = 0; k0 < EMB; k0 += 32) {
    __syncthreads();
    {
      size_t ga = (size_t)(m0 + srow) * EMB + k0 + shalf;
      float4 c0 = *(const float4*)(ctx + ga);
      float4 c1 = *(const float4*)(ctx + ga + 4);
      float4 c2 = *(const float4*)(ctx + ga + 8);
      float4 c3 = *(const float4*)(ctx + ga + 12);
      float v[16] = {c0.x,c0.y,c0.z,c0.w, c1.x,c1.y,c1.z,c1.w,
                     c2.x,c2.y,c2.z,c2.w, c3.x,c3.y,c3.z,c3.w};
      u16 hh[16], ll[16];
#pragma unroll
      for (int jj = 0; jj < 16; ++jj) {
        hh[jj] = f2bf(v[jj]);
        ll[jj] = f2bf(v[jj] - bf2f(hh[jj]));
      }
      int o = srow * 40 + shalf;
#pragma unroll
      for (int g = 0; g < 2; ++g) {
        uint4 ph, pl;
        ph.x = hh[g*8+0] | ((unsigned)hh[g*8+1] << 16);
        ph.y = hh[g*8+2] | ((unsigned)hh[g*8+3] << 16);
        ph.z = hh[g*8+4] | ((unsigned)hh[g*8+5] << 16);
        ph.w = hh[g*8+6] | ((unsigned)hh[g*8+7] << 16);
        pl.x = ll[g*8+0] | ((unsigned)ll[g*8+1] << 16);
        pl.y = ll[g*8+2] | ((unsigned)ll[g*8+3] << 16);
        pl.z = ll[g*8+4] | ((unsigned)ll[g*8+5] << 16);
        pl.w = ll[g*8+6] | ((unsigned)ll[g*8+7] << 16);
        *(uint4*)&Ah[o + g*8] = ph;
        *(uint4*)&Al[o + g*8] = pl;
      }
      size_t gb = (size_t)(n0 + srow) * EMB + k0 + shalf;
      uint4 bh0 = *(const uint4*)(Wh + gb), bh1 = *(const uint4*)(Wh + gb + 8);
      uint4 bl0 = *(const uint4*)(Wl + gb), bl1 = *(const uint4*)(Wl + gb + 8);
      *(uint4*)&Bh[o] = bh0; *(uint4*)&Bh[o + 8] = bh1;
      *(uint4*)&Bl[o] = bl0; *(uint4*)&Bl[o + 8] = bl1;
    }
    __syncthreads();
    frag8 fbh[4], fbl[4];
#pragma unroll
    for (int nt = 0; nt < 4; ++nt) {
      int ob = (wn + nt * 16 + r16) * 40 + quad * 8;
      fbh[nt] = *(const frag8*)&Bh[ob];
      fbl[nt] = *(const frag8*)&Bl[ob];
    }
#pragma unroll
    for (int mt = 0; mt < 4; ++mt) {
      int oa = (wm + mt * 16 + r16) * 40 + quad * 8;
      frag8 fah = *(const frag8*)&Ah[oa];
      frag8 fal = *(const frag8*)&Al[oa];
#pragma unroll
      for (int nt = 0; nt < 4; ++nt) {
        acc[mt][nt] = __builtin_amdgcn_mfma_f32_16x16x32_bf16(fah, fbh[nt], acc[mt][nt], 0, 0, 0);
        acc[mt][nt] = __builtin_amdgcn_mfma_f32_16x16x32_bf16(fah, fbl[nt], acc[mt][nt], 0, 0, 0);
        acc[mt][nt] = __builtin_amdgcn_mfma_f32_16x16x32_bf16(fal, fbh[nt], acc[mt][nt], 0, 0, 0);
      }
    }
  }
#pragma unroll
  for (int nt = 0; nt < 4; ++nt) {
    int cg = n0 + wn + nt * 16 + r16;
    float bvv = bias[cg];
#pragma unroll
    for (int mt = 0; mt < 4; ++mt) {
      int rb = m0 + wm + mt * 16 + quad * 4;
#pragma unroll
      for (int r = 0; r < 4; ++r)
        out[(size_t)(rb + r) * EMB + cg] = acc[mt][nt][r] + bvv;
    }
  }
}

// ---------------------------------------------------------------------------
// Top-k per row (radix-256), with margin flagging into per-batch lists.
// ---------------------------------------------------------------------------
__global__ __launch_bounds__(256) void topk_idx(
    const float* __restrict__ scores, u16* __restrict__ idxl,
    int* __restrict__ flagcnt, int* __restrict__ flaglist)
{
  __shared__ int hist[4][256];
  __shared__ int sel[2];
  __shared__ int wsum[4];
  __shared__ unsigned wmax[4];
  const int r = blockIdx.x;
  const int tid = threadIdx.x;
  const int lane = tid & 63, wid = tid >> 6;
  const float* row = scores + (size_t)r * SEQ;
  unsigned key[8];
  {
    float4 f0 = *(const float4*)(row + tid * 8);
    float4 f1 = *(const float4*)(row + tid * 8 + 4);
    key[0]=f2ord(f0.x); key[1]=f2ord(f0.y); key[2]=f2ord(f0.z); key[3]=f2ord(f0.w);
    key[4]=f2ord(f1.x); key[5]=f2ord(f1.y); key[6]=f2ord(f1.z); key[7]=f2ord(f1.w);
  }
  unsigned V; int MEQ;
  tk_radix(key, tid, hist, sel, V, MEQ);

  {
    int ceq = 0; unsigned mk = 0;
#pragma unroll
    for (int j = 0; j < 8; ++j) {
      ceq += (key[j] == V) ? 1 : 0;
      if (key[j] < V && key[j] > mk) mk = key[j];
    }
#pragma unroll
    for (int off = 32; off > 0; off >>= 1) {
      ceq += __shfl_down(ceq, off, 64);
      unsigned o = (unsigned)__shfl_down((int)mk, off, 64);
      if (o > mk) mk = o;
    }
    if (lane == 0) { wsum[wid] = ceq; wmax[wid] = mk; }
    __syncthreads();
    if (tid == 0) {
      int EQ = wsum[0] + wsum[1] + wsum[2] + wsum[3];
      unsigned m2 = wmax[0];
      for (int w = 1; w < 4; ++w) if (wmax[w] > m2) m2 = wmax[w];
      bool flag = (EQ > MEQ) || !(ord2f(V) - ord2f(m2) >= MBOUND);
      if (flag) {
        int bb = r >> 11;
        int p = atomicAdd(&flagcnt[bb], 1);
        flaglist[bb * SEQ + p] = r & (SEQ - 1);
      }
    }
    __syncthreads();
  }

  tk_write(key, V, MEQ, tid, idxl + (size_t)r * IDXP, wsum);
}

// ---------------------------------------------------------------------------
// Fixup A: exact fp32 scores for flagged rows (gathered-A 64x64 GEMM).
// ---------------------------------------------------------------------------
__global__ __launch_bounds__(256) void fixup_gemm(
    const float* __restrict__ x, const int* __restrict__ flagcnt,
    const int* __restrict__ flaglist, float* __restrict__ attn)
{
  const int b = blockIdx.z;
  const int n = flagcnt[b];
  const int g0 = blockIdx.y * 64;
  if (g0 >= n) return;
  __shared__ float As[16][68];
  __shared__ float Bs[16][68];
  __shared__ int rowsh[64];
  const int tid = threadIdx.x;
  const int n0 = blockIdx.x * 64;
  if (tid < 64) {
    int gi = g0 + tid;
    rowsh[tid] = (gi < n) ? flaglist[b * SEQ + gi] : -1;
  }
  __syncthreads();
  const float* xb = x + (size_t)b * SEQ * EMB;
  const int lm = tid >> 2;
  const int lk = (tid & 3) << 2;
  const int mt = tid >> 4;
  const int nt = tid & 15;
  const int arow = rowsh[lm];
  const int arowL = (arow < 0) ? 0 : arow;
  float acc[4][4] = {{0.f}};
  for (int k0 = 0; k0 < EMB; k0 += 16) {
    float4 av = *(const float4*)(xb + (size_t)arowL * EMB + k0 + lk);
    float4 bv = *(const float4*)(xb + (size_t)(n0 + lm) * EMB + k0 + lk);
    __syncthreads();
    As[lk+0][lm] = av.x; As[lk+1][lm] = av.y; As[lk+2][lm] = av.z; As[lk+3][lm] = av.w;
    Bs[lk+0][lm] = bv.x; Bs[lk+1][lm] = bv.y; Bs[lk+2][lm] = bv.z; Bs[lk+3][lm] = bv.w;
    __syncthreads();
#pragma unroll
    for (int kk = 0; kk < 16; ++kk) {
      float4 a4 = *(const float4*)&As[kk][mt << 2];
      float4 b4 = *(const float4*)&Bs[kk][nt << 2];
      acc[0][0] += a4.x*b4.x; acc[0][1] += a4.x*b4.y; acc[0][2] += a4.x*b4.z; acc[0][3] += a4.x*b4.w;
      acc[1][0] += a4.y*b4.x; acc[1][1] += a4.y*b4.y; acc[1][2] += a4.y*b4.z; acc[1][3] += a4.y*b4.w;
      acc[2][0] += a4.z*b4.x; acc[2][1] += a4.z*b4.y; acc[2][2] += a4.z*b4.z; acc[2][3] += a4.z*b4.w;
      acc[3][0] += a4.w*b4.x; acc[3][1] += a4.w*b4.y; acc[3][2] += a4.w*b4.z; acc[3][3] += a4.w*b4.w;
    }
  }
  float* attnB = attn + (size_t)b * SEQ * SEQ;
#pragma unroll
  for (int r = 0; r < 4; ++r) {
    int rr = rowsh[(mt << 2) + r];
    if (rr >= 0) {
      float4 o;
      o.x = acc[r][0] * 0.0625f; o.y = acc[r][1] * 0.0625f;
      o.z = acc[r][2] * 0.0625f; o.w = acc[r][3] * 0.0625f;
      *(float4*)(attnB + (size_t)rr * SEQ + n0 + (nt << 2)) = o;
    }
  }
}

// ---------------------------------------------------------------------------
// Fixup B: redo top-k (radix) on the now-exact flagged rows.
// ---------------------------------------------------------------------------
__global__ __launch_bounds__(256) void topk_fixup(
    const float* __restrict__ attn, const int* __restrict__ flagcnt,
    const int* __restrict__ flaglist, u16* __restrict__ idxl)
{
  const int b = blockIdx.y;
  if ((int)blockIdx.x >= flagcnt[b]) return;
  const int r = b * SEQ + flaglist[b * SEQ + blockIdx.x];
  __shared__ int hist[4][256];
  __shared__ int sel[2];
  __shared__ int wsum[4];
  const int tid = threadIdx.x;
  const float* row = attn + (size_t)r * SEQ;
  unsigned key[8];
  {
    float4 f0 = *(const float4*)(row + tid * 8);
    float4 f1 = *(const float4*)(row + tid * 8 + 4);
    key[0]=f2ord(f0.x); key[1]=f2ord(f0.y); key[2]=f2ord(f0.z); key[3]=f2ord(f0.w);
    key[4]=f2ord(f1.x); key[5]=f2ord(f1.y); key[6]=f2ord(f1.z); key[7]=f2ord(f1.w);
  }
  unsigned V; int MEQ;
  tk_radix(key, tid, hist, sel, V, MEQ);
  tk_write(key, V, MEQ, tid, idxl + (size_t)r * IDXP, wsum);
}

// ---------------------------------------------------------------------------
// Sparse attention v6: f16 Q/K/V, fdot2 dots, 2-keys-per-wave-load, 32-bit
// byte offsets; rsh/csh share one LDS region -> 8 blocks/CU.
// ---------------------------------------------------------------------------
__global__ __launch_bounds__(256) void sparse_attn(
    const u16* __restrict__ qf, const u16* __restrict__ kf,
    const u16* __restrict__ vf, const u16* __restrict__ idxl,
    float* __restrict__ attn, float* __restrict__ ctxb)
{
  const int lin = blockIdx.x;
  const int b = lin & 3;                                  // XCD-stable batch
  const int q = (lin >> 3) + (((lin >> 2) & 1) << 10);
  const int tid = threadIdx.x;
  const int wv = tid >> 6, ln = tid & 63;
  const int half = ln >> 5, sl = ln & 31;
  const int h = sl >> 2, d0 = sl * 8;
  const int lb = sl * 16;
  __shared__ int   ish[IDXP];
  __shared__ int   koff[IDXP];
  __shared__ float psh[IDXP * 9 + 4];   // [j][h], stride 9
  __shared__ float idsh[NH];
  __shared__ float rcsh[2112];          // union: rsh[2048] | csh[8][264]
#define CSH(i, j) rcsh[(i) * 264 + (j)]

  const int row = b * SEQ + q;
  if (tid < KTOP) {
    int idx = (int)idxl[(size_t)row * IDXP + tid];
    ish[tid] = idx;
    koff[tid] = idx << 9;
  } else if (tid < IDXP) {
    ish[tid] = 0; koff[tid] = 0;
  }
  if (tid < 32) psh[(KTOP + (tid >> 3)) * 9 + (tid & 7)] = 0.f;

  float4 z4 = make_float4(0.f, 0.f, 0.f, 0.f);
  *(float4*)&rcsh[tid * 4]        = z4;
  *(float4*)&rcsh[1024 + tid * 4] = z4;

  U4 qv;
  qv.u = *(const uint4*)((const char*)(qf + (size_t)row * EMB) + lb);

  __syncthreads();

  const float scale = 0.17677669529663687f;  // 1/sqrt(32)
  const char* kbC = (const char*)(kf + (size_t)(b * SEQ) * EMB);
  const int jb = wv * KPW;
#pragma unroll 4
  for (int t = 0; t < KPW; t += 2) {
    const int j = jb + t + half;
    U4 kv;
    kv.u = *(const uint4*)(kbC + (koff[j] + lb));
    float s = FDOT2(qv.h[0], kv.h[0],
              FDOT2(qv.h[1], kv.h[1],
              FDOT2(qv.h[2], kv.h[2],
              FDOT2(qv.h[3], kv.h[3], 0.f))));
    s += __shfl_xor(s, 1, 64);
    s += __shfl_xor(s, 2, 64);
    if ((sl & 3) == 0 && j < KTOP) psh[j * 9 + h] = __expf(s * scale);
  }
  __syncthreads();

  {
    int h2 = tid >> 5, l = tid & 31;
    float sden = 0.f;
    for (int j = l; j < KTOP; j += 32) sden += psh[j * 9 + h2];
#pragma unroll
    for (int off = 16; off > 0; off >>= 1) sden += __shfl_down(sden, off, 32);
    if (l == 0) idsh[h2] = 1.0f / sden;
  }
  __syncthreads();

  if (tid < KTOP) {
    float ps = 0.f;
#pragma unroll
    for (int hh = 0; hh < 8; ++hh) {
      float pp = psh[tid * 9 + hh] * idsh[hh];
      psh[tid * 9 + hh] = pp;
      ps += pp;
    }
    rcsh[ish[tid]] = ps * 0.125f;
  }
  __syncthreads();

  // stream dense row out (full-line, conflict-free)
  {
    float* arow = attn + (size_t)row * SEQ;
    *(float4*)(arow + tid * 4)        = *(const float4*)&rcsh[tid * 4];
    *(float4*)(arow + 1024 + tid * 4) = *(const float4*)&rcsh[1024 + tid * 4];
  }
  __syncthreads();   // rsh dead; csh may now overwrite the region

  {
    const char* vbC = (const char*)(vf + (size_t)(b * SEQ) * EMB);
    float a8[8] = {0.f,0.f,0.f,0.f,0.f,0.f,0.f,0.f};
#pragma unroll 4
    for (int t = 0; t < KPW; t += 2) {
      const int j = jb + t + half;
      float p = psh[j * 9 + h];
      U4 vv;
      vv.u = *(const uint4*)(vbC + (koff[j] + lb));
      a8[0] += p * (float)vv.h[0][0]; a8[1] += p * (float)vv.h[0][1];
      a8[2] += p * (float)vv.h[1][0]; a8[3] += p * (float)vv.h[1][1];
      a8[4] += p * (float)vv.h[2][0]; a8[5] += p * (float)vv.h[2][1];
      a8[6] += p * (float)vv.h[3][0]; a8[7] += p * (float)vv.h[3][1];
    }
    const int pi = wv * 2 + half;
    *(float4*)&CSH(pi, d0)     = make_float4(a8[0], a8[1], a8[2], a8[3]);
    *(float4*)&CSH(pi, d0 + 4) = make_float4(a8[4], a8[5], a8[6], a8[7]);
  }
  __syncthreads();
  if (tid < 64) {
    float4 o = z4;
#pragma unroll
    for (int g = 0; g < 8; ++g) {
      float4 v = *(const float4*)&CSH(g, tid * 4);
      o.x += v.x; o.y += v.y; o.z += v.z; o.w += v.w;
    }
    *(float4*)(ctxb + (size_t)row * EMB + tid * 4) = o;
  }
#undef CSH
}

// ---------------------------------------------------------------------------
extern "C" void kernel_launch(void* const* d_in, const int* in_sizes, int n_in,
                              void* d_out, int out_size, void* d_ws, size_t ws_size,
                              hipStream_t stream)
{
  const float* x  = (const float*)d_in[0];
  const float* Wq = (const float*)d_in[1];
  const float* bq = (const float*)d_in[2];
  const float* Wk = (const float*)d_in[3];
  const float* bk = (const float*)d_in[4];
  const float* Wv = (const float*)d_in[5];
  const float* bv = (const float*)d_in[6];
  const float* Wo = (const float*)d_in[7];
  const float* bo = (const float*)d_in[8];

  float* out  = (float*)d_out;
  float* attn = out + (size_t)NB * SEQ * EMB;   // [B,S,S] region of d_out

  const size_t NSE = (size_t)NB * SEQ * EMB;    // 2097152
  u16* xh  = (u16*)d_ws;            // bf16 hi of x
  u16* xl  = xh + NSE;              // bf16 lo
  u16* qf  = xl + NSE;              // f16 Q
  u16* kf  = qf + NSE;              // f16 K
  u16* vf  = kf + NSE;              // f16 V
  u16* wpk = vf + NSE;              // 4 x (hi,lo) 256x256 bf16
  float* ctxb = (float*)(wpk + 4 * 2 * 65536);
  u16* idxl = (u16*)(ctxb + NSE);
  int* flagcnt  = (int*)(idxl + (size_t)NB * SEQ * IDXP);
  int* flaglist = flagcnt + NB;

  const dim3 blk(256);

  // hi/lo splits of x + weights (one launch); flag counters reset
  pack_all<<<dim3(1152), blk, 0, stream>>>(x, Wq, Wk, Wv, Wo, xh, xl, wpk, flagcnt);

  // symmetric scores (544 upper-triangle blocks) + QKV (384) in one launch
  fused_gemms<<<dim3(928), blk, 0, stream>>>(xh, xl, wpk, bq, bk, bv,
                                             qf, kf, vf, attn);

  // radix top-k with margin flagging; exact fp32 fixup of low-margin rows
  topk_idx<<<dim3(NB * SEQ), blk, 0, stream>>>(attn, idxl, flagcnt, flaglist);
  fixup_gemm<<<dim3(32, 32, NB), blk, 0, stream>>>(x, flagcnt, flaglist, attn);
  topk_fixup<<<dim3(SEQ, NB), blk, 0, stream>>>(attn, flagcnt, flaglist, idxl);

  // fused sparse attention (f16 gathers + fdot2, shared rsh/csh LDS)
  sparse_attn<<<dim3(SEQ * NB), blk, 0, stream>>>(qf, kf, vf, idxl, attn, ctxb);

  // out = ctx @ Wo^T + bo (in-kernel hi/lo split of ctx)
  out_mfma<<<dim3(64, 2), blk, 0, stream>>>(ctxb, wpk, bo, out);
}